// Round 1
// baseline (1982.228 us; speedup 1.0000x reference)
//
#include <hip/hip_runtime.h>
#include <math.h>

#define NN   4096
#define MM   1024
#define NNZC 65536
#define DD   512
#define HH   8
#define DHH  64
#define DFFC 2048

// ---------------- utility ----------------
__device__ inline void atomicMaxF(float* addr, float val) {
  // sign-split trick: int compare matches float order for >=0,
  // reversed uint compare matches for <0. Works mixed-sign.
  if (val >= 0.f) atomicMax((int*)addr, __float_as_int(val));
  else            atomicMin((unsigned int*)addr, __float_as_uint(val));
}

// ---------------- init ----------------
__global__ void init_kernel(float* amax, float* den, int* DnCnt, int* BnCnt,
                            int* node_cur, int* edge_cur) {
  int i = blockIdx.x * 256 + threadIdx.x;
  if (i < NN) { amax[i] = -INFINITY; den[i] = 0.f; DnCnt[i] = 0; node_cur[i] = 0; }
  if (i < MM) { BnCnt[i] = 0; edge_cur[i] = 0; }
}

// ---------------- generic fp32 NT GEMM: C[M,N] = A[M,K] @ B[N,K]^T (+bias, +relu) ----------------
// 64x64 tile, 256 threads, 4x4 per thread, K-step 16.
__global__ __launch_bounds__(256) void gemm_nt(const float* __restrict__ A,
    const float* __restrict__ B, const float* __restrict__ bias,
    float* __restrict__ C, int Ndim, int K, int relu) {
  __shared__ float As[64][17];
  __shared__ float Bs[64][17];
  const int t  = threadIdx.x;
  const int tx = t & 15, ty = t >> 4;
  const int bm = blockIdx.x * 64, bn = blockIdx.y * 64;
  float acc[4][4] = {};
  for (int k0 = 0; k0 < K; k0 += 16) {
    const int r = t >> 2, c4 = (t & 3) << 2;
    float4 av = *(const float4*)&A[(size_t)(bm + r) * K + k0 + c4];
    float4 bv = *(const float4*)&B[(size_t)(bn + r) * K + k0 + c4];
    As[r][c4+0] = av.x; As[r][c4+1] = av.y; As[r][c4+2] = av.z; As[r][c4+3] = av.w;
    Bs[r][c4+0] = bv.x; Bs[r][c4+1] = bv.y; Bs[r][c4+2] = bv.z; Bs[r][c4+3] = bv.w;
    __syncthreads();
    #pragma unroll
    for (int kk = 0; kk < 16; ++kk) {
      float a[4], b[4];
      #pragma unroll
      for (int i = 0; i < 4; ++i) a[i] = As[ty*4+i][kk];
      #pragma unroll
      for (int j = 0; j < 4; ++j) b[j] = Bs[tx*4+j][kk];
      #pragma unroll
      for (int i = 0; i < 4; ++i)
        #pragma unroll
        for (int j = 0; j < 4; ++j)
          acc[i][j] += a[i] * b[j];
    }
    __syncthreads();
  }
  #pragma unroll
  for (int i = 0; i < 4; ++i) {
    int row = bm + ty*4 + i;
    #pragma unroll
    for (int j = 0; j < 4; ++j) {
      int col = bn + tx*4 + j;
      float v = acc[i][j];
      if (bias) v += bias[col];
      if (relu) v = fmaxf(v, 0.f);
      C[(size_t)row * Ndim + col] = v;
    }
  }
}

// ---------------- per-row dot with a vector of length 512 (one wave per row) ----------------
__global__ __launch_bounds__(256) void rowdot(const float* __restrict__ X,
    const float* __restrict__ vec, float* __restrict__ out, int rows) {
  int w = (blockIdx.x * 256 + threadIdx.x) >> 6;
  int lane = threadIdx.x & 63;
  if (w >= rows) return;
  const float* xr = &X[(size_t)w * DD];
  float s = 0.f;
  #pragma unroll
  for (int j = 0; j < 8; ++j) s += xr[lane + 64*j] * vec[lane + 64*j];
  #pragma unroll
  for (int off = 1; off < 64; off <<= 1) s += __shfl_xor(s, off, 64);
  if (lane == 0) out[w] = s;
}

// ---------------- incidence pass 1: score + leaky + per-node max + degree counts ----------------
__global__ void incidence_pass1(const int* __restrict__ node_idx, const int* __restrict__ edge_idx,
    const float* __restrict__ s_node, const float* __restrict__ s_edge,
    float* __restrict__ a_buf, float* amax, int* DnCnt, int* BnCnt) {
  int i = blockIdx.x * 256 + threadIdx.x;
  if (i >= NNZC) return;
  int n = node_idx[i], m = edge_idx[i];
  float a = s_node[n] + s_edge[m];
  a = (a >= 0.f) ? a : 0.2f * a;   // leaky_relu(0.2)
  a_buf[i] = a;
  atomicMaxF(&amax[n], a);
  atomicAdd(&DnCnt[n], 1);
  atomicAdd(&BnCnt[m], 1);
}

// ---------------- single-block exclusive scan (n <= 1024*chunk) ----------------
__global__ __launch_bounds__(1024) void exscan_kernel(const int* __restrict__ in,
                                                      int* __restrict__ out, int n) {
  __shared__ int sums[1024];
  const int t = threadIdx.x;
  const int chunk = (n + 1023) >> 10;
  const int start = t * chunk;
  const int stop  = min(start + chunk, n);
  int local = 0;
  for (int i = start; i < stop; ++i) local += in[i];
  sums[t] = local;
  __syncthreads();
  for (int o = 1; o < 1024; o <<= 1) {
    int v = (t >= o) ? sums[t - o] : 0;
    __syncthreads();
    sums[t] += v;
    __syncthreads();
  }
  int run = (t == 0) ? 0 : sums[t - 1];
  for (int i = start; i < stop; ++i) { out[i] = run; run += in[i]; }
  if (t == 1023) out[n] = sums[1023];
}

// ---------------- incidence pass 2: exp, denom, build CSR lists ----------------
__global__ void incidence_pass2(const int* __restrict__ node_idx, const int* __restrict__ edge_idx,
    float* __restrict__ a_buf, const float* __restrict__ amax, float* den,
    const int* __restrict__ node_off, const int* __restrict__ edge_off,
    int* node_cur, int* edge_cur, int* node_list, int* edge_list) {
  int i = blockIdx.x * 256 + threadIdx.x;
  if (i >= NNZC) return;
  int n = node_idx[i], m = edge_idx[i];
  float e = __expf(a_buf[i] - amax[n]);
  a_buf[i] = e;
  atomicAdd(&den[n], e);
  int pn = atomicAdd(&node_cur[n], 1);
  node_list[node_off[n] + pn] = i;
  int pm = atomicAdd(&edge_cur[m], 1);
  edge_list[edge_off[m] + pm] = i;
}

// ---------------- edge gather: ef[m] = sum_i Binv*alpha_i*xl[node_i] ----------------
__global__ __launch_bounds__(256) void gather_edge(const int* __restrict__ edge_off,
    const int* __restrict__ edge_list, const int* __restrict__ node_idx,
    const float* __restrict__ a_buf, const float* __restrict__ den,
    const float* __restrict__ xl, float* __restrict__ ef) {
  int m = blockIdx.x;
  int t = threadIdx.x;
  int beg = edge_off[m], end = edge_off[m+1];
  int cnt = end - beg;
  float Binv = (cnt > 0) ? (1.0f / (float)cnt) : 0.f;
  __shared__ int   ln_[128];
  __shared__ float lw_[128];
  float acc0 = 0.f, acc1 = 0.f;
  for (int c = beg; c < end; c += 128) {
    int nchunk = min(128, end - c);
    if (t < nchunk) {
      int i = edge_list[c + t];
      int n = node_idx[i];
      ln_[t] = n;
      lw_[t] = a_buf[i] / (den[n] + 1e-16f) * Binv;
    }
    __syncthreads();
    for (int j = 0; j < nchunk; ++j) {
      const float w = lw_[j];
      const float* xr = &xl[(size_t)ln_[j] * DD];
      acc0 += w * xr[t];
      acc1 += w * xr[t + 256];
    }
    __syncthreads();
  }
  ef[(size_t)m * DD + t]       = acc0;
  ef[(size_t)m * DD + t + 256] = acc1;
}

// ---------------- node gather: conv[n] = sum_i Dinv*alpha_i*ef[edge_i] + bias ----------------
__global__ __launch_bounds__(256) void gather_node(const int* __restrict__ node_off,
    const int* __restrict__ node_list, const int* __restrict__ edge_idx,
    const float* __restrict__ a_buf, const float* __restrict__ den,
    const float* __restrict__ ef, const float* __restrict__ bias_h, float* __restrict__ conv) {
  int n = blockIdx.x;
  int t = threadIdx.x;
  int beg = node_off[n], end = node_off[n+1];
  int cnt = end - beg;
  float Dinv = (cnt > 0) ? (1.0f / (float)cnt) : 0.f;
  float wscale = Dinv / (den[n] + 1e-16f);
  __shared__ int   le_[128];
  __shared__ float lw_[128];
  float acc0 = 0.f, acc1 = 0.f;
  for (int c = beg; c < end; c += 128) {
    int nchunk = min(128, end - c);
    if (t < nchunk) {
      int i = node_list[c + t];
      le_[t] = edge_idx[i];
      lw_[t] = a_buf[i] * wscale;
    }
    __syncthreads();
    for (int j = 0; j < nchunk; ++j) {
      const float w = lw_[j];
      const float* er = &ef[(size_t)le_[j] * DD];
      acc0 += w * er[t];
      acc1 += w * er[t + 256];
    }
    __syncthreads();
  }
  conv[(size_t)n * DD + t]       = acc0 + bias_h[t];
  conv[(size_t)n * DD + t + 256] = acc1 + bias_h[t + 256];
}

// ---------------- LayerNorm(a + b) row-wise, D=512, block=256 ----------------
__global__ __launch_bounds__(256) void ln_residual(const float* __restrict__ a,
    const float* __restrict__ b, const float* __restrict__ g, const float* __restrict__ be,
    float* __restrict__ out) {
  int r = blockIdx.x;
  int t = threadIdx.x;
  float v0 = a[(size_t)r*DD + t]       + b[(size_t)r*DD + t];
  float v1 = a[(size_t)r*DD + t + 256] + b[(size_t)r*DD + t + 256];
  __shared__ float red[4];
  __shared__ float mu_s, rstd_s;
  float s = v0 + v1;
  #pragma unroll
  for (int off = 1; off < 64; off <<= 1) s += __shfl_xor(s, off, 64);
  int wid = t >> 6;
  if ((t & 63) == 0) red[wid] = s;
  __syncthreads();
  if (t == 0) mu_s = (red[0] + red[1] + red[2] + red[3]) / 512.f;
  __syncthreads();
  float mu = mu_s;
  float d0 = v0 - mu, d1 = v1 - mu;
  float vs = d0*d0 + d1*d1;
  #pragma unroll
  for (int off = 1; off < 64; off <<= 1) vs += __shfl_xor(vs, off, 64);
  if ((t & 63) == 0) red[wid] = vs;
  __syncthreads();
  if (t == 0) rstd_s = rsqrtf((red[0] + red[1] + red[2] + red[3]) / 512.f + 1e-5f);
  __syncthreads();
  float rs = rstd_s;
  out[(size_t)r*DD + t]       = d0 * rs * g[t]       + be[t];
  out[(size_t)r*DD + t + 256] = d1 * rs * g[t + 256] + be[t + 256];
}

// ---------------- flash attention fp32: H=8, DH=64, 32 queries/block ----------------
__global__ __launch_bounds__(256) void attn_kernel(const float* __restrict__ qkv,
                                                   float* __restrict__ ctx) {
  const int h  = blockIdx.y;
  const int q0 = blockIdx.x * 32;
  const int t  = threadIdx.x;
  const int qi = t >> 3, sub = t & 7;
  const int qrow = q0 + qi;
  __shared__ float Ks[64][64];
  __shared__ float Vs[64][64];
  float qr[8];
  const float scale = 0.125f;  // 1/sqrt(64)
  #pragma unroll
  for (int j = 0; j < 8; ++j)
    qr[j] = qkv[(size_t)qrow*1536 + h*64 + sub*8 + j] * scale;
  float m = -1e30f, l = 0.f, o[8] = {};
  for (int kt = 0; kt < NN; kt += 64) {
    #pragma unroll
    for (int it = 0; it < 4; ++it) {
      int idx = it * 256 + t;        // 0..1023
      int row = idx >> 4;
      int c4  = (idx & 15) << 2;
      *(float4*)&Ks[row][c4] = *(const float4*)&qkv[(size_t)(kt+row)*1536 + 512  + h*64 + c4];
      *(float4*)&Vs[row][c4] = *(const float4*)&qkv[(size_t)(kt+row)*1536 + 1024 + h*64 + c4];
    }
    __syncthreads();
    for (int k = 0; k < 64; ++k) {
      float s = 0.f;
      #pragma unroll
      for (int j = 0; j < 8; ++j) s += qr[j] * Ks[k][sub*8 + j];
      s += __shfl_xor(s, 1, 64); s += __shfl_xor(s, 2, 64); s += __shfl_xor(s, 4, 64);
      if (s <= m) {
        float p = __expf(s - m);
        l += p;
        #pragma unroll
        for (int j = 0; j < 8; ++j) o[j] += p * Vs[k][sub*8 + j];
      } else {
        float c = __expf(m - s);
        m = s;
        l = l * c + 1.f;
        #pragma unroll
        for (int j = 0; j < 8; ++j) o[j] = o[j] * c + Vs[k][sub*8 + j];
      }
    }
    __syncthreads();
  }
  float inv = 1.f / l;
  #pragma unroll
  for (int j = 0; j < 8; ++j)
    ctx[(size_t)qrow*DD + h*64 + sub*8 + j] = o[j] * inv;
}

// ---------------- host ----------------
extern "C" void kernel_launch(void* const* d_in, const int* in_sizes, int n_in,
                              void* d_out, int out_size, void* d_ws, size_t ws_size,
                              hipStream_t stream) {
  const float* x       = (const float*)d_in[0];
  const int*   hidx    = (const int*)d_in[1];
  const float* hattr   = (const float*)d_in[2];
  const float* Wh      = (const float*)d_in[3];
  const float* att     = (const float*)d_in[4];
  const float* bias_h  = (const float*)d_in[5];
  const float* ln1_g   = (const float*)d_in[6];
  const float* ln1_b   = (const float*)d_in[7];
  const float* ln2_g   = (const float*)d_in[8];
  const float* ln2_b   = (const float*)d_in[9];
  const float* in_proj_w  = (const float*)d_in[10];
  const float* in_proj_b  = (const float*)d_in[11];
  const float* out_proj_w = (const float*)d_in[12];
  const float* out_proj_b = (const float*)d_in[13];
  const float* ff1_w   = (const float*)d_in[14];
  const float* ff1_b   = (const float*)d_in[15];
  const float* ff2_w   = (const float*)d_in[16];
  const float* ff2_b   = (const float*)d_in[17];
  const float* tln1_g  = (const float*)d_in[18];
  const float* tln1_b  = (const float*)d_in[19];
  const float* tln2_g  = (const float*)d_in[20];
  const float* tln2_b  = (const float*)d_in[21];
  const int* node_idx = hidx;          // hyperedge_index[0]
  const int* edge_idx = hidx + NNZC;   // hyperedge_index[1]

  char* ws = (char*)d_ws;
  size_t off = 0;
  auto alloc = [&](size_t bytes) -> void* {
    void* p = ws + off;
    off = (off + bytes + 63) & ~(size_t)63;
    return p;
  };
  float* xl       = (float*)alloc(sizeof(float)*NN*DD);
  float* el       = (float*)alloc(sizeof(float)*MM*DD);
  float* s_node   = (float*)alloc(sizeof(float)*NN);
  float* s_edge   = (float*)alloc(sizeof(float)*MM);
  float* a_buf    = (float*)alloc(sizeof(float)*NNZC);
  float* amax     = (float*)alloc(sizeof(float)*NN);
  float* den      = (float*)alloc(sizeof(float)*NN);
  int*   DnCnt    = (int*)alloc(sizeof(int)*NN);
  int*   BnCnt    = (int*)alloc(sizeof(int)*MM);
  int*   node_off = (int*)alloc(sizeof(int)*(NN+1));
  int*   edge_off = (int*)alloc(sizeof(int)*(MM+1));
  int*   node_cur = (int*)alloc(sizeof(int)*NN);
  int*   edge_cur = (int*)alloc(sizeof(int)*MM);
  int*   node_list= (int*)alloc(sizeof(int)*NNZC);
  int*   edge_list= (int*)alloc(sizeof(int)*NNZC);
  float* ef       = (float*)alloc(sizeof(float)*MM*DD);
  float* conv     = (float*)alloc(sizeof(float)*NN*DD);
  float* x1       = (float*)alloc(sizeof(float)*NN*DD);
  float* qkvb     = (float*)alloc(sizeof(float)*NN*3*DD);
  float* ctx      = (float*)alloc(sizeof(float)*NN*DD);
  float* attn_out = (float*)alloc(sizeof(float)*NN*DD);
  float* x2       = (float*)alloc(sizeof(float)*NN*DD);
  float* ffh      = (float*)alloc(sizeof(float)*NN*DFFC);
  float* ffo      = (float*)alloc(sizeof(float)*NN*DD);
  float* x3       = (float*)alloc(sizeof(float)*NN*DD);
  (void)ws_size; (void)in_sizes; (void)n_in; (void)out_size;

  dim3 b256(256);
  // xl = x @ Wh^T ; el = hattr @ Wh^T
  gemm_nt<<<dim3(NN/64, DD/64), b256, 0, stream>>>(x,     Wh, nullptr, xl, DD, DD, 0);
  gemm_nt<<<dim3(MM/64, DD/64), b256, 0, stream>>>(hattr, Wh, nullptr, el, DD, DD, 0);
  // scalar attention pieces
  rowdot<<<NN/4, b256, 0, stream>>>(xl, att,      s_node, NN);
  rowdot<<<MM/4, b256, 0, stream>>>(el, att + DD, s_edge, MM);
  init_kernel<<<NN/256, b256, 0, stream>>>(amax, den, DnCnt, BnCnt, node_cur, edge_cur);
  incidence_pass1<<<NNZC/256, b256, 0, stream>>>(node_idx, edge_idx, s_node, s_edge,
                                                 a_buf, amax, DnCnt, BnCnt);
  exscan_kernel<<<1, 1024, 0, stream>>>(DnCnt, node_off, NN);
  exscan_kernel<<<1, 1024, 0, stream>>>(BnCnt, edge_off, MM);
  incidence_pass2<<<NNZC/256, b256, 0, stream>>>(node_idx, edge_idx, a_buf, amax, den,
                                                 node_off, edge_off, node_cur, edge_cur,
                                                 node_list, edge_list);
  gather_edge<<<MM, b256, 0, stream>>>(edge_off, edge_list, node_idx, a_buf, den, xl, ef);
  gather_node<<<NN, b256, 0, stream>>>(node_off, node_list, edge_idx, a_buf, den, ef, bias_h, conv);
  // x1 = LN(x + conv)
  ln_residual<<<NN, b256, 0, stream>>>(x, conv, ln1_g, ln1_b, x1);
  // qkv
  gemm_nt<<<dim3(NN/64, (3*DD)/64), b256, 0, stream>>>(x1, in_proj_w, in_proj_b, qkvb, 3*DD, DD, 0);
  // attention
  attn_kernel<<<dim3(NN/32, HH), b256, 0, stream>>>(qkvb, ctx);
  // out_proj
  gemm_nt<<<dim3(NN/64, DD/64), b256, 0, stream>>>(ctx, out_proj_w, out_proj_b, attn_out, DD, DD, 0);
  // x2 = LN(x1 + attn_out)
  ln_residual<<<NN, b256, 0, stream>>>(x1, attn_out, tln1_g, tln1_b, x2);
  // ffn
  gemm_nt<<<dim3(NN/64, DFFC/64), b256, 0, stream>>>(x2, ff1_w, ff1_b, ffh, DFFC, DD, 1);
  gemm_nt<<<dim3(NN/64, DD/64),   b256, 0, stream>>>(ffh, ff2_w, ff2_b, ffo, DD, DFFC, 0);
  // x3 = LN(x2 + ff)
  ln_residual<<<NN, b256, 0, stream>>>(x2, ffo, tln2_g, tln2_b, x3);
  // out = LN(x1 + x3)
  ln_residual<<<NN, b256, 0, stream>>>(x1, x3, ln2_g, ln2_b, (float*)d_out);
}

// Round 4
// 940.315 us; speedup vs baseline: 2.1080x; 2.1080x over previous
//
#include <hip/hip_runtime.h>
#include <math.h>

#define NN   4096
#define MM   1024
#define NNZC 65536
#define DD   512
#define HH   8
#define DHH  64
#define DFFC 2048

typedef short bf16x8 __attribute__((ext_vector_type(8)));
typedef float f32x4  __attribute__((ext_vector_type(4)));

static __device__ inline unsigned short f2bf(float f) {
  union { float f; unsigned int u; } v; v.f = f;
  unsigned int r = v.u + 0x7fff + ((v.u >> 16) & 1);   // RNE
  return (unsigned short)(r >> 16);
}

// ---------------- utility ----------------
__device__ inline void atomicMaxF(float* addr, float val) {
  if (val >= 0.f) atomicMax((int*)addr, __float_as_int(val));
  else            atomicMin((unsigned int*)addr, __float_as_uint(val));
}

// ---------------- init ----------------
__global__ void init_kernel(float* amax, float* den, int* DnCnt, int* BnCnt,
                            int* node_cur, int* edge_cur) {
  int i = blockIdx.x * 256 + threadIdx.x;
  if (i < NN) { amax[i] = -INFINITY; den[i] = 0.f; DnCnt[i] = 0; node_cur[i] = 0; }
  if (i < MM) { BnCnt[i] = 0; edge_cur[i] = 0; }
}

// ---------------- generic fp32 NT GEMM: C[M,N] = A[M,K] @ B[N,K]^T (+bias, +relu) ----------------
__global__ __launch_bounds__(256) void gemm_nt(const float* __restrict__ A,
    const float* __restrict__ B, const float* __restrict__ bias,
    float* __restrict__ C, int Ndim, int K, int relu) {
  __shared__ float As[64][17];
  __shared__ float Bs[64][17];
  const int t  = threadIdx.x;
  const int tx = t & 15, ty = t >> 4;
  const int bm = blockIdx.x * 64, bn = blockIdx.y * 64;
  float acc[4][4] = {};
  for (int k0 = 0; k0 < K; k0 += 16) {
    const int r = t >> 2, c4 = (t & 3) << 2;
    float4 av = *(const float4*)&A[(size_t)(bm + r) * K + k0 + c4];
    float4 bv = *(const float4*)&B[(size_t)(bn + r) * K + k0 + c4];
    As[r][c4+0] = av.x; As[r][c4+1] = av.y; As[r][c4+2] = av.z; As[r][c4+3] = av.w;
    Bs[r][c4+0] = bv.x; Bs[r][c4+1] = bv.y; Bs[r][c4+2] = bv.z; Bs[r][c4+3] = bv.w;
    __syncthreads();
    #pragma unroll
    for (int kk = 0; kk < 16; ++kk) {
      float a[4], b[4];
      #pragma unroll
      for (int i = 0; i < 4; ++i) a[i] = As[ty*4+i][kk];
      #pragma unroll
      for (int j = 0; j < 4; ++j) b[j] = Bs[tx*4+j][kk];
      #pragma unroll
      for (int i = 0; i < 4; ++i)
        #pragma unroll
        for (int j = 0; j < 4; ++j)
          acc[i][j] += a[i] * b[j];
    }
    __syncthreads();
  }
  #pragma unroll
  for (int i = 0; i < 4; ++i) {
    int row = bm + ty*4 + i;
    #pragma unroll
    for (int j = 0; j < 4; ++j) {
      int col = bn + tx*4 + j;
      float v = acc[i][j];
      if (bias) v += bias[col];
      if (relu) v = fmaxf(v, 0.f);
      C[(size_t)row * Ndim + col] = v;
    }
  }
}

// ---------------- per-row dot ----------------
__global__ __launch_bounds__(256) void rowdot(const float* __restrict__ X,
    const float* __restrict__ vec, float* __restrict__ out, int rows) {
  int w = (blockIdx.x * 256 + threadIdx.x) >> 6;
  int lane = threadIdx.x & 63;
  if (w >= rows) return;
  const float* xr = &X[(size_t)w * DD];
  float s = 0.f;
  #pragma unroll
  for (int j = 0; j < 8; ++j) s += xr[lane + 64*j] * vec[lane + 64*j];
  #pragma unroll
  for (int off = 1; off < 64; off <<= 1) s += __shfl_xor(s, off, 64);
  if (lane == 0) out[w] = s;
}

// ---------------- incidence pass 1 ----------------
__global__ void incidence_pass1(const int* __restrict__ node_idx, const int* __restrict__ edge_idx,
    const float* __restrict__ s_node, const float* __restrict__ s_edge,
    float* __restrict__ a_buf, float* amax, int* DnCnt, int* BnCnt) {
  int i = blockIdx.x * 256 + threadIdx.x;
  if (i >= NNZC) return;
  int n = node_idx[i], m = edge_idx[i];
  float a = s_node[n] + s_edge[m];
  a = (a >= 0.f) ? a : 0.2f * a;
  a_buf[i] = a;
  atomicMaxF(&amax[n], a);
  atomicAdd(&DnCnt[n], 1);
  atomicAdd(&BnCnt[m], 1);
}

// ---------------- single-block exclusive scan ----------------
__global__ __launch_bounds__(1024) void exscan_kernel(const int* __restrict__ in,
                                                      int* __restrict__ out, int n) {
  __shared__ int sums[1024];
  const int t = threadIdx.x;
  const int chunk = (n + 1023) >> 10;
  const int start = t * chunk;
  const int stop  = min(start + chunk, n);
  int local = 0;
  for (int i = start; i < stop; ++i) local += in[i];
  sums[t] = local;
  __syncthreads();
  for (int o = 1; o < 1024; o <<= 1) {
    int v = (t >= o) ? sums[t - o] : 0;
    __syncthreads();
    sums[t] += v;
    __syncthreads();
  }
  int run = (t == 0) ? 0 : sums[t - 1];
  for (int i = start; i < stop; ++i) { out[i] = run; run += in[i]; }
  if (t == 1023) out[n] = sums[1023];
}

// ---------------- incidence pass 2 ----------------
__global__ void incidence_pass2(const int* __restrict__ node_idx, const int* __restrict__ edge_idx,
    float* __restrict__ a_buf, const float* __restrict__ amax, float* den,
    const int* __restrict__ node_off, const int* __restrict__ edge_off,
    int* node_cur, int* edge_cur, int* node_list, int* edge_list) {
  int i = blockIdx.x * 256 + threadIdx.x;
  if (i >= NNZC) return;
  int n = node_idx[i], m = edge_idx[i];
  float e = __expf(a_buf[i] - amax[n]);
  a_buf[i] = e;
  atomicAdd(&den[n], e);
  int pn = atomicAdd(&node_cur[n], 1);
  node_list[node_off[n] + pn] = i;
  int pm = atomicAdd(&edge_cur[m], 1);
  edge_list[edge_off[m] + pm] = i;
}

// ---------------- edge gather ----------------
__global__ __launch_bounds__(256) void gather_edge(const int* __restrict__ edge_off,
    const int* __restrict__ edge_list, const int* __restrict__ node_idx,
    const float* __restrict__ a_buf, const float* __restrict__ den,
    const float* __restrict__ xl, float* __restrict__ ef) {
  int m = blockIdx.x;
  int t = threadIdx.x;
  int beg = edge_off[m], end = edge_off[m+1];
  int cnt = end - beg;
  float Binv = (cnt > 0) ? (1.0f / (float)cnt) : 0.f;
  __shared__ int   ln_[128];
  __shared__ float lw_[128];
  float acc0 = 0.f, acc1 = 0.f;
  for (int c = beg; c < end; c += 128) {
    int nchunk = min(128, end - c);
    if (t < nchunk) {
      int i = edge_list[c + t];
      int n = node_idx[i];
      ln_[t] = n;
      lw_[t] = a_buf[i] / (den[n] + 1e-16f) * Binv;
    }
    __syncthreads();
    for (int j = 0; j < nchunk; ++j) {
      const float w = lw_[j];
      const float* xr = &xl[(size_t)ln_[j] * DD];
      acc0 += w * xr[t];
      acc1 += w * xr[t + 256];
    }
    __syncthreads();
  }
  ef[(size_t)m * DD + t]       = acc0;
  ef[(size_t)m * DD + t + 256] = acc1;
}

// ---------------- node gather ----------------
__global__ __launch_bounds__(256) void gather_node(const int* __restrict__ node_off,
    const int* __restrict__ node_list, const int* __restrict__ edge_idx,
    const float* __restrict__ a_buf, const float* __restrict__ den,
    const float* __restrict__ ef, const float* __restrict__ bias_h, float* __restrict__ conv) {
  int n = blockIdx.x;
  int t = threadIdx.x;
  int beg = node_off[n], end = node_off[n+1];
  int cnt = end - beg;
  float Dinv = (cnt > 0) ? (1.0f / (float)cnt) : 0.f;
  float wscale = Dinv / (den[n] + 1e-16f);
  __shared__ int   le_[128];
  __shared__ float lw_[128];
  float acc0 = 0.f, acc1 = 0.f;
  for (int c = beg; c < end; c += 128) {
    int nchunk = min(128, end - c);
    if (t < nchunk) {
      int i = node_list[c + t];
      le_[t] = edge_idx[i];
      lw_[t] = a_buf[i] * wscale;
    }
    __syncthreads();
    for (int j = 0; j < nchunk; ++j) {
      const float w = lw_[j];
      const float* er = &ef[(size_t)le_[j] * DD];
      acc0 += w * er[t];
      acc1 += w * er[t + 256];
    }
    __syncthreads();
  }
  conv[(size_t)n * DD + t]       = acc0 + bias_h[t];
  conv[(size_t)n * DD + t + 256] = acc1 + bias_h[t + 256];
}

// ---------------- LayerNorm(a + b) ----------------
__global__ __launch_bounds__(256) void ln_residual(const float* __restrict__ a,
    const float* __restrict__ b, const float* __restrict__ g, const float* __restrict__ be,
    float* __restrict__ out) {
  int r = blockIdx.x;
  int t = threadIdx.x;
  float v0 = a[(size_t)r*DD + t]       + b[(size_t)r*DD + t];
  float v1 = a[(size_t)r*DD + t + 256] + b[(size_t)r*DD + t + 256];
  __shared__ float red[4];
  __shared__ float mu_s, rstd_s;
  float s = v0 + v1;
  #pragma unroll
  for (int off = 1; off < 64; off <<= 1) s += __shfl_xor(s, off, 64);
  int wid = t >> 6;
  if ((t & 63) == 0) red[wid] = s;
  __syncthreads();
  if (t == 0) mu_s = (red[0] + red[1] + red[2] + red[3]) / 512.f;
  __syncthreads();
  float mu = mu_s;
  float d0 = v0 - mu, d1 = v1 - mu;
  float vs = d0*d0 + d1*d1;
  #pragma unroll
  for (int off = 1; off < 64; off <<= 1) vs += __shfl_xor(vs, off, 64);
  if ((t & 63) == 0) red[wid] = vs;
  __syncthreads();
  if (t == 0) rstd_s = rsqrtf((red[0] + red[1] + red[2] + red[3]) / 512.f + 1e-5f);
  __syncthreads();
  float rs = rstd_s;
  out[(size_t)r*DD + t]       = d0 * rs * g[t]       + be[t];
  out[(size_t)r*DD + t + 256] = d1 * rs * g[t + 256] + be[t + 256];
}

// ---------------- K-plane fp32 -> bf16 : Kb[h][tok][64] ----------------
__global__ __launch_bounds__(256) void conv_k(const float* __restrict__ qkv,
                                              unsigned short* __restrict__ Kb) {
  int idx = blockIdx.x * 256 + threadIdx.x;   // 4 elems each, total 4096*512/4
  int e = idx * 4;
  int tok = e >> 9;
  int hd = e & 511;
  float4 v = *(const float4*)&qkv[(size_t)tok*1536 + 512 + hd];
  int h = hd >> 6, d = hd & 63;
  ushort4 w4;
  w4.x = f2bf(v.x); w4.y = f2bf(v.y); w4.z = f2bf(v.z); w4.w = f2bf(v.w);
  *(ushort4*)&Kb[(size_t)h*NN*64 + (size_t)tok*64 + d] = w4;
}

// ---------------- V-plane fp32 -> bf16 transposed : Vtb[h][d][tok] ----------------
__global__ __launch_bounds__(256) void conv_vt(const float* __restrict__ qkv,
                                               unsigned short* __restrict__ Vtb) {
  __shared__ unsigned short Tl[64][76];
  const int h = blockIdx.y;
  const int tt = blockIdx.x * 64;
  const int t = threadIdx.x;
  {
    int row = t >> 2;
    int cbase = (t & 3) * 16;
    const float* src = &qkv[(size_t)(tt + row)*1536 + 1024 + h*64 + cbase];
    #pragma unroll
    for (int jj = 0; jj < 4; ++jj) {
      float4 v = *(const float4*)&src[jj*4];
      ushort4 w4;
      w4.x = f2bf(v.x); w4.y = f2bf(v.y); w4.z = f2bf(v.z); w4.w = f2bf(v.w);
      *(ushort4*)&Tl[row][cbase + jj*4] = w4;
    }
  }
  __syncthreads();
  #pragma unroll
  for (int it = 0; it < 4; ++it) {
    int d = it*16 + (t >> 4);
    int tk = (t & 15) * 4;
    ushort4 w4;
    w4.x = Tl[tk+0][d]; w4.y = Tl[tk+1][d]; w4.z = Tl[tk+2][d]; w4.w = Tl[tk+3][d];
    *(ushort4*)&Vtb[(size_t)h*64*NN + (size_t)d*NN + tt + tk] = w4;
  }
}

// ---------------- MFMA flash attention: 64 q-rows/block, 4 waves, K-tile 64 ----------------
__global__ __launch_bounds__(256) void attn_mfma(const unsigned short* __restrict__ Kb,
                                                 const unsigned short* __restrict__ Vtb,
                                                 const float* __restrict__ qkv,
                                                 float* __restrict__ ctx) {
  const int head = blockIdx.y;
  const int q0 = blockIdx.x * 64;
  const int t = threadIdx.x;
  const int w = t >> 6;
  const int l = t & 63;
  const int lg = l >> 4;
  const int lid = l & 15;

  __shared__ __align__(16) unsigned short Kl[64*64];   // [tok][d], XOR-swizzled
  __shared__ __align__(16) unsigned short Vl[64*64];   // [d][tok], XOR-swizzled
  __shared__ __align__(16) unsigned short Pl[4][16*72];

  // Q A-fragments (rows = lid, k(d) = lg*8+j), scale folded in
  union { bf16x8 v; unsigned short u[8]; } qa[2];
  {
    const int qrow = q0 + w*16 + lid;
    const float* qp = &qkv[(size_t)qrow*1536 + head*64];
    #pragma unroll
    for (int hf = 0; hf < 2; ++hf)
      #pragma unroll
      for (int j = 0; j < 8; ++j)
        qa[hf].u[j] = f2bf(qp[hf*32 + lg*8 + j] * 0.125f);
  }

  float m[4], lsum[4];
  f32x4 o[4];
  #pragma unroll
  for (int r = 0; r < 4; ++r) { m[r] = -1e30f; lsum[r] = 0.f; }
  #pragma unroll
  for (int dt = 0; dt < 4; ++dt) o[dt] = (f32x4)0.f;

  const unsigned short* Kh = Kb  + (size_t)head*NN*64;
  const unsigned short* Vh = Vtb + (size_t)head*64*NN;
  unsigned short* pw = Pl[w];

  for (int kt = 0; kt < NN; kt += 64) {
    // ---- stage K [64 tok][64 d] and Vt [64 d][64 tok] (bf16, swizzled) ----
    #pragma unroll
    for (int it = 0; it < 2; ++it) {
      int idx = it*256 + t;          // 0..511 chunks of 8 ushorts (16B)
      int row = idx >> 3;
      int cc  = (idx & 7) * 8;
      int didx = (row*64 + cc) ^ ((row & 7) << 3);
      *(ulonglong2*)&Kl[didx] = *(const ulonglong2*)&Kh[(size_t)(kt + row)*64 + cc];
      *(ulonglong2*)&Vl[didx] = *(const ulonglong2*)&Vh[(size_t)row*NN + kt + cc];
    }
    __syncthreads();

    // ---- S = Q K^T  (rows=q, cols=k-token) ----
    f32x4 s[4];
    #pragma unroll
    for (int n = 0; n < 4; ++n) s[n] = (f32x4)0.f;
    #pragma unroll
    for (int n = 0; n < 4; ++n) {
      int tok = n*16 + lid;
      #pragma unroll
      for (int hf = 0; hf < 2; ++hf) {
        int didx = (tok*64 + hf*32 + lg*8) ^ ((tok & 7) << 3);
        bf16x8 kb = *(const bf16x8*)&Kl[didx];
        s[n] = __builtin_amdgcn_mfma_f32_16x16x32_bf16(qa[hf].v, kb, s[n], 0, 0, 0);
      }
    }

    // ---- online softmax (per q-row r, reduce over 16-lane group x 4 tiles) ----
    #pragma unroll
    for (int r = 0; r < 4; ++r) {
      float mx = fmaxf(fmaxf(s[0][r], s[1][r]), fmaxf(s[2][r], s[3][r]));
      mx = fmaxf(mx, __shfl_xor(mx, 1, 64));
      mx = fmaxf(mx, __shfl_xor(mx, 2, 64));
      mx = fmaxf(mx, __shfl_xor(mx, 4, 64));
      mx = fmaxf(mx, __shfl_xor(mx, 8, 64));
      float mn = fmaxf(m[r], mx);
      float c = __expf(m[r] - mn);
      m[r] = mn;
      lsum[r] *= c;
      #pragma unroll
      for (int dt = 0; dt < 4; ++dt) o[dt][r] *= c;
      float ps = 0.f;
      #pragma unroll
      for (int n = 0; n < 4; ++n) {
        float p = __expf(s[n][r] - mn);
        s[n][r] = p;
        ps += p;
      }
      ps += __shfl_xor(ps, 1, 64); ps += __shfl_xor(ps, 2, 64);
      ps += __shfl_xor(ps, 4, 64); ps += __shfl_xor(ps, 8, 64);
      lsum[r] += ps;
    }

    // ---- P -> LDS (bf16) in A-fragment layout, per-wave buffer ----
    #pragma unroll
    for (int n = 0; n < 4; ++n)
      #pragma unroll
      for (int r = 0; r < 4; ++r)
        pw[(lg*4 + r)*72 + n*16 + lid] = f2bf(s[n][r]);

    bf16x8 pa[2];
    #pragma unroll
    for (int hf = 0; hf < 2; ++hf)
      pa[hf] = *(const bf16x8*)&pw[lid*72 + hf*32 + lg*8];

    // ---- O += P V  (rows=q, cols=d) ----
    #pragma unroll
    for (int dt = 0; dt < 4; ++dt) {
      int drow = dt*16 + lid;
      #pragma unroll
      for (int hf = 0; hf < 2; ++hf) {
        int didx = (drow*64 + hf*32 + lg*8) ^ ((drow & 7) << 3);
        bf16x8 vb = *(const bf16x8*)&Vl[didx];
        o[dt] = __builtin_amdgcn_mfma_f32_16x16x32_bf16(pa[hf], vb, o[dt], 0, 0, 0);
      }
    }
    __syncthreads();
  }

  // ---- epilogue ----
  #pragma unroll
  for (int r = 0; r < 4; ++r) {
    float inv = 1.f / lsum[r];
    int q = q0 + w*16 + lg*4 + r;
    #pragma unroll
    for (int dt = 0; dt < 4; ++dt)
      ctx[(size_t)q*DD + head*64 + dt*16 + lid] = o[dt][r] * inv;
  }
}

// ---------------- host ----------------
extern "C" void kernel_launch(void* const* d_in, const int* in_sizes, int n_in,
                              void* d_out, int out_size, void* d_ws, size_t ws_size,
                              hipStream_t stream) {
  const float* x       = (const float*)d_in[0];
  const int*   hidx    = (const int*)d_in[1];
  const float* hattr   = (const float*)d_in[2];
  const float* Wh      = (const float*)d_in[3];
  const float* att     = (const float*)d_in[4];
  const float* bias_h  = (const float*)d_in[5];
  const float* ln1_g   = (const float*)d_in[6];
  const float* ln1_b   = (const float*)d_in[7];
  const float* ln2_g   = (const float*)d_in[8];
  const float* ln2_b   = (const float*)d_in[9];
  const float* in_proj_w  = (const float*)d_in[10];
  const float* in_proj_b  = (const float*)d_in[11];
  const float* out_proj_w = (const float*)d_in[12];
  const float* out_proj_b = (const float*)d_in[13];
  const float* ff1_w   = (const float*)d_in[14];
  const float* ff1_b   = (const float*)d_in[15];
  const float* ff2_w   = (const float*)d_in[16];
  const float* ff2_b   = (const float*)d_in[17];
  const float* tln1_g  = (const float*)d_in[18];
  const float* tln1_b  = (const float*)d_in[19];
  const float* tln2_g  = (const float*)d_in[20];
  const float* tln2_b  = (const float*)d_in[21];
  const int* node_idx = hidx;
  const int* edge_idx = hidx + NNZC;

  char* ws = (char*)d_ws;
  size_t off = 0;
  auto alloc = [&](size_t bytes) -> void* {
    void* p = ws + off;
    off = (off + bytes + 63) & ~(size_t)63;
    return p;
  };
  float* xl       = (float*)alloc(sizeof(float)*NN*DD);
  float* el       = (float*)alloc(sizeof(float)*MM*DD);
  float* s_node   = (float*)alloc(sizeof(float)*NN);
  float* s_edge   = (float*)alloc(sizeof(float)*MM);
  float* a_buf    = (float*)alloc(sizeof(float)*NNZC);
  float* amax     = (float*)alloc(sizeof(float)*NN);
  float* den      = (float*)alloc(sizeof(float)*NN);
  int*   DnCnt    = (int*)alloc(sizeof(int)*NN);
  int*   BnCnt    = (int*)alloc(sizeof(int)*MM);
  int*   node_off = (int*)alloc(sizeof(int)*(NN+1));
  int*   edge_off = (int*)alloc(sizeof(int)*(MM+1));
  int*   node_cur = (int*)alloc(sizeof(int)*NN);
  int*   edge_cur = (int*)alloc(sizeof(int)*MM);
  int*   node_list= (int*)alloc(sizeof(int)*NNZC);
  int*   edge_list= (int*)alloc(sizeof(int)*NNZC);
  float* ef       = (float*)alloc(sizeof(float)*MM*DD);
  float* conv     = (float*)alloc(sizeof(float)*NN*DD);
  float* x1       = (float*)alloc(sizeof(float)*NN*DD);
  float* qkvb     = (float*)alloc(sizeof(float)*NN*3*DD);
  float* ctx      = (float*)alloc(sizeof(float)*NN*DD);
  float* attn_out = (float*)alloc(sizeof(float)*NN*DD);
  float* x2       = (float*)alloc(sizeof(float)*NN*DD);
  float* ffh      = (float*)alloc(sizeof(float)*NN*DFFC);
  float* ffo      = (float*)alloc(sizeof(float)*NN*DD);
  float* x3       = (float*)alloc(sizeof(float)*NN*DD);
  unsigned short* Kb  = (unsigned short*)alloc(sizeof(unsigned short)*NN*DD);
  unsigned short* Vtb = (unsigned short*)alloc(sizeof(unsigned short)*NN*DD);
  (void)ws_size; (void)in_sizes; (void)n_in; (void)out_size;

  dim3 b256(256);
  gemm_nt<<<dim3(NN/64, DD/64), b256, 0, stream>>>(x,     Wh, nullptr, xl, DD, DD, 0);
  gemm_nt<<<dim3(MM/64, DD/64), b256, 0, stream>>>(hattr, Wh, nullptr, el, DD, DD, 0);
  rowdot<<<NN/4, b256, 0, stream>>>(xl, att,      s_node, NN);
  rowdot<<<MM/4, b256, 0, stream>>>(el, att + DD, s_edge, MM);
  init_kernel<<<NN/256, b256, 0, stream>>>(amax, den, DnCnt, BnCnt, node_cur, edge_cur);
  incidence_pass1<<<NNZC/256, b256, 0, stream>>>(node_idx, edge_idx, s_node, s_edge,
                                                 a_buf, amax, DnCnt, BnCnt);
  exscan_kernel<<<1, 1024, 0, stream>>>(DnCnt, node_off, NN);
  exscan_kernel<<<1, 1024, 0, stream>>>(BnCnt, edge_off, MM);
  incidence_pass2<<<NNZC/256, b256, 0, stream>>>(node_idx, edge_idx, a_buf, amax, den,
                                                 node_off, edge_off, node_cur, edge_cur,
                                                 node_list, edge_list);
  gather_edge<<<MM, b256, 0, stream>>>(edge_off, edge_list, node_idx, a_buf, den, xl, ef);
  gather_node<<<NN, b256, 0, stream>>>(node_off, node_list, edge_idx, a_buf, den, ef, bias_h, conv);
  ln_residual<<<NN, b256, 0, stream>>>(x, conv, ln1_g, ln1_b, x1);
  gemm_nt<<<dim3(NN/64, (3*DD)/64), b256, 0, stream>>>(x1, in_proj_w, in_proj_b, qkvb, 3*DD, DD, 0);
  // attention (bf16 MFMA)
  conv_k <<<NN*DD/(256*4), b256, 0, stream>>>(qkvb, Kb);
  conv_vt<<<dim3(NN/64, HH), b256, 0, stream>>>(qkvb, Vtb);
  attn_mfma<<<dim3(NN/64, HH), b256, 0, stream>>>(Kb, Vtb, qkvb, ctx);
  gemm_nt<<<dim3(NN/64, DD/64), b256, 0, stream>>>(ctx, out_proj_w, out_proj_b, attn_out, DD, DD, 0);
  ln_residual<<<NN, b256, 0, stream>>>(x1, attn_out, tln1_g, tln1_b, x2);
  gemm_nt<<<dim3(NN/64, DFFC/64), b256, 0, stream>>>(x2, ff1_w, ff1_b, ffh, DFFC, DD, 1);
  gemm_nt<<<dim3(NN/64, DD/64),   b256, 0, stream>>>(ffh, ff2_w, ff2_b, ffo, DD, DFFC, 0);
  ln_residual<<<NN, b256, 0, stream>>>(x2, ffo, tln2_g, tln2_b, x3);
  ln_residual<<<NN, b256, 0, stream>>>(x1, x3, ln2_g, ln2_b, (float*)d_out);
}

// Round 5
// 386.469 us; speedup vs baseline: 5.1291x; 2.4331x over previous
//
#include <hip/hip_runtime.h>
#include <math.h>

#define NN   4096
#define MM   1024
#define NNZC 65536
#define DD   512
#define HH   8
#define DHH  64
#define DFFC 2048

typedef short bf16x8 __attribute__((ext_vector_type(8)));
typedef float f32x4  __attribute__((ext_vector_type(4)));

static __device__ inline unsigned short f2bf(float f) {
  union { float f; unsigned int u; } v; v.f = f;
  unsigned int r = v.u + 0x7fff + ((v.u >> 16) & 1);   // RNE
  return (unsigned short)(r >> 16);
}

__device__ inline void gload16(const void* g, void* l) {
  __builtin_amdgcn_global_load_lds(
      (const __attribute__((address_space(1))) void*)g,
      (__attribute__((address_space(3))) void*)l, 16, 0, 0);
}

// ---------------- utility ----------------
__device__ inline void atomicMaxF(float* addr, float val) {
  if (val >= 0.f) atomicMax((int*)addr, __float_as_int(val));
  else            atomicMin((unsigned int*)addr, __float_as_uint(val));
}

// ---------------- init ----------------
__global__ void init_kernel(float* amax, float* den, int* DnCnt, int* BnCnt,
                            int* node_cur, int* edge_cur) {
  int i = blockIdx.x * 256 + threadIdx.x;
  if (i < NN) { amax[i] = -INFINITY; den[i] = 0.f; DnCnt[i] = 0; node_cur[i] = 0; }
  if (i < MM) { BnCnt[i] = 0; edge_cur[i] = 0; }
}

// ---------------- fp32 -> bf16 bulk convert (8 elems/thread) ----------------
__global__ __launch_bounds__(256) void f2b_kernel(const float* __restrict__ in,
    unsigned short* __restrict__ out, int n8) {
  int i = blockIdx.x * 256 + threadIdx.x;
  if (i >= n8) return;
  float4 v0 = *(const float4*)&in[(size_t)i*8];
  float4 v1 = *(const float4*)&in[(size_t)i*8 + 4];
  unsigned short w[8];
  w[0]=f2bf(v0.x); w[1]=f2bf(v0.y); w[2]=f2bf(v0.z); w[3]=f2bf(v0.w);
  w[4]=f2bf(v1.x); w[5]=f2bf(v1.y); w[6]=f2bf(v1.z); w[7]=f2bf(v1.w);
  *(ulonglong2*)&out[(size_t)i*8] = *(ulonglong2*)w;
}

// ---------------- bf16 MFMA NT GEMM: C[M,N] = A[M,K] @ B[N,K]^T (+bias,+relu) ----------------
// 128x128 tile, 4 waves (2x2), 64x64 per wave, BK=64, global_load_lds staging,
// source-side XOR swizzle (chunk ^= row&7) matched on ds_read side.
__global__ __launch_bounds__(256) void gemm_bt_bf16(
    const unsigned short* __restrict__ A, const unsigned short* __restrict__ B,
    const float* __restrict__ bias, float* __restrict__ Cf,
    unsigned short* __restrict__ Cb, int N, int K, int relu) {
  __shared__ __align__(16) unsigned short Al[128*64];
  __shared__ __align__(16) unsigned short Bl[128*64];
  const int t = threadIdx.x;
  const int w = t >> 6, l = t & 63;
  const int lg = l >> 4, lid = l & 15;
  const int wr = w >> 1, wc = w & 1;
  const int bm = blockIdx.x * 128, bn = blockIdx.y * 128;

  f32x4 acc[4][4];
  #pragma unroll
  for (int mi = 0; mi < 4; ++mi)
    #pragma unroll
    for (int ni = 0; ni < 4; ++ni) acc[mi][ni] = (f32x4)0.f;

  for (int k0 = 0; k0 < K; k0 += 64) {
    #pragma unroll
    for (int i = 0; i < 4; ++i) {
      int cid = i*256 + t;           // 0..1023 16B-chunks
      int row = cid >> 3, cp = cid & 7;
      int gc = cp ^ (row & 7);       // pre-swizzled global source chunk
      gload16(&A[(size_t)(bm + row)*K + k0 + gc*8], &Al[cid*8]);
      gload16(&B[(size_t)(bn + row)*K + k0 + gc*8], &Bl[cid*8]);
    }
    asm volatile("s_waitcnt vmcnt(0)" ::: "memory");
    __syncthreads();
    #pragma unroll
    for (int ks = 0; ks < 2; ++ks) {
      bf16x8 af[4], bfr[4];
      #pragma unroll
      for (int mi = 0; mi < 4; ++mi) {
        int r = wr*64 + mi*16 + lid;
        af[mi] = *(const bf16x8*)&Al[r*64 + ((ks*4 + lg) ^ (r & 7))*8];
      }
      #pragma unroll
      for (int ni = 0; ni < 4; ++ni) {
        int r = wc*64 + ni*16 + lid;
        bfr[ni] = *(const bf16x8*)&Bl[r*64 + ((ks*4 + lg) ^ (r & 7))*8];
      }
      #pragma unroll
      for (int mi = 0; mi < 4; ++mi)
        #pragma unroll
        for (int ni = 0; ni < 4; ++ni)
          acc[mi][ni] = __builtin_amdgcn_mfma_f32_16x16x32_bf16(af[mi], bfr[ni], acc[mi][ni], 0, 0, 0);
    }
    __syncthreads();
  }

  #pragma unroll
  for (int ni = 0; ni < 4; ++ni) {
    int col = bn + wc*64 + ni*16 + lid;
    float bv = bias ? bias[col] : 0.f;
    #pragma unroll
    for (int mi = 0; mi < 4; ++mi) {
      #pragma unroll
      for (int rg = 0; rg < 4; ++rg) {
        int row = bm + wr*64 + mi*16 + lg*4 + rg;
        float v = acc[mi][ni][rg] + bv;
        if (relu) v = fmaxf(v, 0.f);
        if (Cf) Cf[(size_t)row*N + col] = v;
        if (Cb) Cb[(size_t)row*N + col] = f2bf(v);
      }
    }
  }
}

// ---------------- per-row dot ----------------
__global__ __launch_bounds__(256) void rowdot(const float* __restrict__ X,
    const float* __restrict__ vec, float* __restrict__ out, int rows) {
  int w = (blockIdx.x * 256 + threadIdx.x) >> 6;
  int lane = threadIdx.x & 63;
  if (w >= rows) return;
  const float* xr = &X[(size_t)w * DD];
  float s = 0.f;
  #pragma unroll
  for (int j = 0; j < 8; ++j) s += xr[lane + 64*j] * vec[lane + 64*j];
  #pragma unroll
  for (int off = 1; off < 64; off <<= 1) s += __shfl_xor(s, off, 64);
  if (lane == 0) out[w] = s;
}

// ---------------- incidence pass 1 ----------------
__global__ void incidence_pass1(const int* __restrict__ node_idx, const int* __restrict__ edge_idx,
    const float* __restrict__ s_node, const float* __restrict__ s_edge,
    float* __restrict__ a_buf, float* amax, int* DnCnt, int* BnCnt) {
  int i = blockIdx.x * 256 + threadIdx.x;
  if (i >= NNZC) return;
  int n = node_idx[i], m = edge_idx[i];
  float a = s_node[n] + s_edge[m];
  a = (a >= 0.f) ? a : 0.2f * a;
  a_buf[i] = a;
  atomicMaxF(&amax[n], a);
  atomicAdd(&DnCnt[n], 1);
  atomicAdd(&BnCnt[m], 1);
}

// ---------------- single-block exclusive scan ----------------
__global__ __launch_bounds__(1024) void exscan_kernel(const int* __restrict__ in,
                                                      int* __restrict__ out, int n) {
  __shared__ int sums[1024];
  const int t = threadIdx.x;
  const int chunk = (n + 1023) >> 10;
  const int start = t * chunk;
  const int stop  = min(start + chunk, n);
  int local = 0;
  for (int i = start; i < stop; ++i) local += in[i];
  sums[t] = local;
  __syncthreads();
  for (int o = 1; o < 1024; o <<= 1) {
    int v = (t >= o) ? sums[t - o] : 0;
    __syncthreads();
    sums[t] += v;
    __syncthreads();
  }
  int run = (t == 0) ? 0 : sums[t - 1];
  for (int i = start; i < stop; ++i) { out[i] = run; run += in[i]; }
  if (t == 1023) out[n] = sums[1023];
}

// ---------------- incidence pass 2 ----------------
__global__ void incidence_pass2(const int* __restrict__ node_idx, const int* __restrict__ edge_idx,
    float* __restrict__ a_buf, const float* __restrict__ amax, float* den,
    const int* __restrict__ node_off, const int* __restrict__ edge_off,
    int* node_cur, int* edge_cur, int* node_list, int* edge_list) {
  int i = blockIdx.x * 256 + threadIdx.x;
  if (i >= NNZC) return;
  int n = node_idx[i], m = edge_idx[i];
  float e = __expf(a_buf[i] - amax[n]);
  a_buf[i] = e;
  atomicAdd(&den[n], e);
  int pn = atomicAdd(&node_cur[n], 1);
  node_list[node_off[n] + pn] = i;
  int pm = atomicAdd(&edge_cur[m], 1);
  edge_list[edge_off[m] + pm] = i;
}

// ---------------- edge gather ----------------
__global__ __launch_bounds__(256) void gather_edge(const int* __restrict__ edge_off,
    const int* __restrict__ edge_list, const int* __restrict__ node_idx,
    const float* __restrict__ a_buf, const float* __restrict__ den,
    const float* __restrict__ xl, float* __restrict__ ef) {
  int m = blockIdx.x;
  int t = threadIdx.x;
  int beg = edge_off[m], end = edge_off[m+1];
  int cnt = end - beg;
  float Binv = (cnt > 0) ? (1.0f / (float)cnt) : 0.f;
  __shared__ int   ln_[128];
  __shared__ float lw_[128];
  float acc0 = 0.f, acc1 = 0.f;
  for (int c = beg; c < end; c += 128) {
    int nchunk = min(128, end - c);
    if (t < nchunk) {
      int i = edge_list[c + t];
      int n = node_idx[i];
      ln_[t] = n;
      lw_[t] = a_buf[i] / (den[n] + 1e-16f) * Binv;
    }
    __syncthreads();
    for (int j = 0; j < nchunk; ++j) {
      const float w = lw_[j];
      const float* xr = &xl[(size_t)ln_[j] * DD];
      acc0 += w * xr[t];
      acc1 += w * xr[t + 256];
    }
    __syncthreads();
  }
  ef[(size_t)m * DD + t]       = acc0;
  ef[(size_t)m * DD + t + 256] = acc1;
}

// ---------------- node gather ----------------
__global__ __launch_bounds__(256) void gather_node(const int* __restrict__ node_off,
    const int* __restrict__ node_list, const int* __restrict__ edge_idx,
    const float* __restrict__ a_buf, const float* __restrict__ den,
    const float* __restrict__ ef, const float* __restrict__ bias_h, float* __restrict__ conv) {
  int n = blockIdx.x;
  int t = threadIdx.x;
  int beg = node_off[n], end = node_off[n+1];
  int cnt = end - beg;
  float Dinv = (cnt > 0) ? (1.0f / (float)cnt) : 0.f;
  float wscale = Dinv / (den[n] + 1e-16f);
  __shared__ int   le_[128];
  __shared__ float lw_[128];
  float acc0 = 0.f, acc1 = 0.f;
  for (int c = beg; c < end; c += 128) {
    int nchunk = min(128, end - c);
    if (t < nchunk) {
      int i = node_list[c + t];
      le_[t] = edge_idx[i];
      lw_[t] = a_buf[i] * wscale;
    }
    __syncthreads();
    for (int j = 0; j < nchunk; ++j) {
      const float w = lw_[j];
      const float* er = &ef[(size_t)le_[j] * DD];
      acc0 += w * er[t];
      acc1 += w * er[t + 256];
    }
    __syncthreads();
  }
  conv[(size_t)n * DD + t]       = acc0 + bias_h[t];
  conv[(size_t)n * DD + t + 256] = acc1 + bias_h[t + 256];
}

// ---------------- LayerNorm(a + b), optional bf16 copy ----------------
__global__ __launch_bounds__(256) void ln_residual(const float* __restrict__ a,
    const float* __restrict__ b, const float* __restrict__ g, const float* __restrict__ be,
    float* __restrict__ out, unsigned short* __restrict__ outb) {
  int r = blockIdx.x;
  int t = threadIdx.x;
  float v0 = a[(size_t)r*DD + t]       + b[(size_t)r*DD + t];
  float v1 = a[(size_t)r*DD + t + 256] + b[(size_t)r*DD + t + 256];
  __shared__ float red[4];
  __shared__ float mu_s, rstd_s;
  float s = v0 + v1;
  #pragma unroll
  for (int off = 1; off < 64; off <<= 1) s += __shfl_xor(s, off, 64);
  int wid = t >> 6;
  if ((t & 63) == 0) red[wid] = s;
  __syncthreads();
  if (t == 0) mu_s = (red[0] + red[1] + red[2] + red[3]) / 512.f;
  __syncthreads();
  float mu = mu_s;
  float d0 = v0 - mu, d1 = v1 - mu;
  float vs = d0*d0 + d1*d1;
  #pragma unroll
  for (int off = 1; off < 64; off <<= 1) vs += __shfl_xor(vs, off, 64);
  if ((t & 63) == 0) red[wid] = vs;
  __syncthreads();
  if (t == 0) rstd_s = rsqrtf((red[0] + red[1] + red[2] + red[3]) / 512.f + 1e-5f);
  __syncthreads();
  float rs = rstd_s;
  float o0 = d0 * rs * g[t]       + be[t];
  float o1 = d1 * rs * g[t + 256] + be[t + 256];
  out[(size_t)r*DD + t]       = o0;
  out[(size_t)r*DD + t + 256] = o1;
  if (outb) {
    outb[(size_t)r*DD + t]       = f2bf(o0);
    outb[(size_t)r*DD + t + 256] = f2bf(o1);
  }
}

// ---------------- K-plane fp32 -> bf16 : Kb[h][tok][64] ----------------
__global__ __launch_bounds__(256) void conv_k(const float* __restrict__ qkv,
                                              unsigned short* __restrict__ Kb) {
  int idx = blockIdx.x * 256 + threadIdx.x;
  int e = idx * 4;
  int tok = e >> 9;
  int hd = e & 511;
  float4 v = *(const float4*)&qkv[(size_t)tok*1536 + 512 + hd];
  int h = hd >> 6, d = hd & 63;
  ushort4 w4;
  w4.x = f2bf(v.x); w4.y = f2bf(v.y); w4.z = f2bf(v.z); w4.w = f2bf(v.w);
  *(ushort4*)&Kb[(size_t)h*NN*64 + (size_t)tok*64 + d] = w4;
}

// ---------------- V-plane fp32 -> bf16 transposed : Vtb[h][d][tok] ----------------
__global__ __launch_bounds__(256) void conv_vt(const float* __restrict__ qkv,
                                               unsigned short* __restrict__ Vtb) {
  __shared__ unsigned short Tl[64][76];
  const int h = blockIdx.y;
  const int tt = blockIdx.x * 64;
  const int t = threadIdx.x;
  {
    int row = t >> 2;
    int cbase = (t & 3) * 16;
    const float* src = &qkv[(size_t)(tt + row)*1536 + 1024 + h*64 + cbase];
    #pragma unroll
    for (int jj = 0; jj < 4; ++jj) {
      float4 v = *(const float4*)&src[jj*4];
      ushort4 w4;
      w4.x = f2bf(v.x); w4.y = f2bf(v.y); w4.z = f2bf(v.z); w4.w = f2bf(v.w);
      *(ushort4*)&Tl[row][cbase + jj*4] = w4;
    }
  }
  __syncthreads();
  #pragma unroll
  for (int it = 0; it < 4; ++it) {
    int d = it*16 + (t >> 4);
    int tk = (t & 15) * 4;
    ushort4 w4;
    w4.x = Tl[tk+0][d]; w4.y = Tl[tk+1][d]; w4.z = Tl[tk+2][d]; w4.w = Tl[tk+3][d];
    *(ushort4*)&Vtb[(size_t)h*64*NN + (size_t)d*NN + tt + tk] = w4;
  }
}

// ---------------- MFMA flash attention: 64 q-rows/block, 4 waves, K-tile 64 ----------------
__global__ __launch_bounds__(256) void attn_mfma(const unsigned short* __restrict__ Kb,
                                                 const unsigned short* __restrict__ Vtb,
                                                 const float* __restrict__ qkv,
                                                 unsigned short* __restrict__ ctxb) {
  const int head = blockIdx.y;
  const int q0 = blockIdx.x * 64;
  const int t = threadIdx.x;
  const int w = t >> 6;
  const int l = t & 63;
  const int lg = l >> 4;
  const int lid = l & 15;

  __shared__ __align__(16) unsigned short Kl[64*64];
  __shared__ __align__(16) unsigned short Vl[64*64];
  __shared__ __align__(16) unsigned short Pl[4][16*72];

  union { bf16x8 v; unsigned short u[8]; } qa[2];
  {
    const int qrow = q0 + w*16 + lid;
    const float* qp = &qkv[(size_t)qrow*1536 + head*64];
    #pragma unroll
    for (int hf = 0; hf < 2; ++hf)
      #pragma unroll
      for (int j = 0; j < 8; ++j)
        qa[hf].u[j] = f2bf(qp[hf*32 + lg*8 + j] * 0.125f);
  }

  float m[4], lsum[4];
  f32x4 o[4];
  #pragma unroll
  for (int r = 0; r < 4; ++r) { m[r] = -1e30f; lsum[r] = 0.f; }
  #pragma unroll
  for (int dt = 0; dt < 4; ++dt) o[dt] = (f32x4)0.f;

  const unsigned short* Kh = Kb  + (size_t)head*NN*64;
  const unsigned short* Vh = Vtb + (size_t)head*64*NN;
  unsigned short* pw = Pl[w];

  for (int kt = 0; kt < NN; kt += 64) {
    #pragma unroll
    for (int it = 0; it < 2; ++it) {
      int idx = it*256 + t;
      int row = idx >> 3;
      int cc  = (idx & 7) * 8;
      int didx = (row*64 + cc) ^ ((row & 7) << 3);
      *(ulonglong2*)&Kl[didx] = *(const ulonglong2*)&Kh[(size_t)(kt + row)*64 + cc];
      *(ulonglong2*)&Vl[didx] = *(const ulonglong2*)&Vh[(size_t)row*NN + kt + cc];
    }
    __syncthreads();

    f32x4 s[4];
    #pragma unroll
    for (int n = 0; n < 4; ++n) s[n] = (f32x4)0.f;
    #pragma unroll
    for (int n = 0; n < 4; ++n) {
      int tok = n*16 + lid;
      #pragma unroll
      for (int hf = 0; hf < 2; ++hf) {
        int didx = (tok*64 + hf*32 + lg*8) ^ ((tok & 7) << 3);
        bf16x8 kb = *(const bf16x8*)&Kl[didx];
        s[n] = __builtin_amdgcn_mfma_f32_16x16x32_bf16(qa[hf].v, kb, s[n], 0, 0, 0);
      }
    }

    #pragma unroll
    for (int r = 0; r < 4; ++r) {
      float mx = fmaxf(fmaxf(s[0][r], s[1][r]), fmaxf(s[2][r], s[3][r]));
      mx = fmaxf(mx, __shfl_xor(mx, 1, 64));
      mx = fmaxf(mx, __shfl_xor(mx, 2, 64));
      mx = fmaxf(mx, __shfl_xor(mx, 4, 64));
      mx = fmaxf(mx, __shfl_xor(mx, 8, 64));
      float mn = fmaxf(m[r], mx);
      float c = __expf(m[r] - mn);
      m[r] = mn;
      lsum[r] *= c;
      #pragma unroll
      for (int dt = 0; dt < 4; ++dt) o[dt][r] *= c;
      float ps = 0.f;
      #pragma unroll
      for (int n = 0; n < 4; ++n) {
        float p = __expf(s[n][r] - mn);
        s[n][r] = p;
        ps += p;
      }
      ps += __shfl_xor(ps, 1, 64); ps += __shfl_xor(ps, 2, 64);
      ps += __shfl_xor(ps, 4, 64); ps += __shfl_xor(ps, 8, 64);
      lsum[r] += ps;
    }

    #pragma unroll
    for (int n = 0; n < 4; ++n)
      #pragma unroll
      for (int r = 0; r < 4; ++r)
        pw[(lg*4 + r)*72 + n*16 + lid] = f2bf(s[n][r]);

    bf16x8 pa[2];
    #pragma unroll
    for (int hf = 0; hf < 2; ++hf)
      pa[hf] = *(const bf16x8*)&pw[lid*72 + hf*32 + lg*8];

    #pragma unroll
    for (int dt = 0; dt < 4; ++dt) {
      int drow = dt*16 + lid;
      #pragma unroll
      for (int hf = 0; hf < 2; ++hf) {
        int didx = (drow*64 + hf*32 + lg*8) ^ ((drow & 7) << 3);
        bf16x8 vb = *(const bf16x8*)&Vl[didx];
        o[dt] = __builtin_amdgcn_mfma_f32_16x16x32_bf16(pa[hf], vb, o[dt], 0, 0, 0);
      }
    }
    __syncthreads();
  }

  #pragma unroll
  for (int r = 0; r < 4; ++r) {
    float inv = 1.f / lsum[r];
    int q = q0 + w*16 + lg*4 + r;
    #pragma unroll
    for (int dt = 0; dt < 4; ++dt)
      ctxb[(size_t)q*DD + head*64 + dt*16 + lid] = f2bf(o[dt][r] * inv);
  }
}

// ---------------- host ----------------
extern "C" void kernel_launch(void* const* d_in, const int* in_sizes, int n_in,
                              void* d_out, int out_size, void* d_ws, size_t ws_size,
                              hipStream_t stream) {
  const float* x       = (const float*)d_in[0];
  const int*   hidx    = (const int*)d_in[1];
  const float* hattr   = (const float*)d_in[2];
  const float* Wh      = (const float*)d_in[3];
  const float* att     = (const float*)d_in[4];
  const float* bias_h  = (const float*)d_in[5];
  const float* ln1_g   = (const float*)d_in[6];
  const float* ln1_b   = (const float*)d_in[7];
  const float* ln2_g   = (const float*)d_in[8];
  const float* ln2_b   = (const float*)d_in[9];
  const float* in_proj_w  = (const float*)d_in[10];
  const float* in_proj_b  = (const float*)d_in[11];
  const float* out_proj_w = (const float*)d_in[12];
  const float* out_proj_b = (const float*)d_in[13];
  const float* ff1_w   = (const float*)d_in[14];
  const float* ff1_b   = (const float*)d_in[15];
  const float* ff2_w   = (const float*)d_in[16];
  const float* ff2_b   = (const float*)d_in[17];
  const float* tln1_g  = (const float*)d_in[18];
  const float* tln1_b  = (const float*)d_in[19];
  const float* tln2_g  = (const float*)d_in[20];
  const float* tln2_b  = (const float*)d_in[21];
  const int* node_idx = hidx;
  const int* edge_idx = hidx + NNZC;

  char* ws = (char*)d_ws;
  size_t off = 0;
  auto alloc = [&](size_t bytes) -> void* {
    void* p = ws + off;
    off = (off + bytes + 63) & ~(size_t)63;
    return p;
  };
  float* xl       = (float*)alloc(sizeof(float)*NN*DD);
  float* el       = (float*)alloc(sizeof(float)*MM*DD);
  float* s_node   = (float*)alloc(sizeof(float)*NN);
  float* s_edge   = (float*)alloc(sizeof(float)*MM);
  float* a_buf    = (float*)alloc(sizeof(float)*NNZC);
  float* amax     = (float*)alloc(sizeof(float)*NN);
  float* den      = (float*)alloc(sizeof(float)*NN);
  int*   DnCnt    = (int*)alloc(sizeof(int)*NN);
  int*   BnCnt    = (int*)alloc(sizeof(int)*MM);
  int*   node_off = (int*)alloc(sizeof(int)*(NN+1));
  int*   edge_off = (int*)alloc(sizeof(int)*(MM+1));
  int*   node_cur = (int*)alloc(sizeof(int)*NN);
  int*   edge_cur = (int*)alloc(sizeof(int)*MM);
  int*   node_list= (int*)alloc(sizeof(int)*NNZC);
  int*   edge_list= (int*)alloc(sizeof(int)*NNZC);
  float* ef       = (float*)alloc(sizeof(float)*MM*DD);
  float* conv     = (float*)alloc(sizeof(float)*NN*DD);
  float* x1       = (float*)alloc(sizeof(float)*NN*DD);
  float* qkvb     = (float*)alloc(sizeof(float)*NN*3*DD);
  float* attn_out = (float*)alloc(sizeof(float)*NN*DD);
  float* x2       = (float*)alloc(sizeof(float)*NN*DD);
  float* ffo      = (float*)alloc(sizeof(float)*NN*DD);
  float* x3       = (float*)alloc(sizeof(float)*NN*DD);
  unsigned short* Kb    = (unsigned short*)alloc(sizeof(unsigned short)*NN*DD);
  unsigned short* Vtb   = (unsigned short*)alloc(sizeof(unsigned short)*NN*DD);
  unsigned short* xb    = (unsigned short*)alloc(sizeof(unsigned short)*NN*DD);
  unsigned short* hattrb= (unsigned short*)alloc(sizeof(unsigned short)*MM*DD);
  unsigned short* Whb   = (unsigned short*)alloc(sizeof(unsigned short)*DD*DD);
  unsigned short* ipwb  = (unsigned short*)alloc(sizeof(unsigned short)*3*DD*DD);
  unsigned short* opwb  = (unsigned short*)alloc(sizeof(unsigned short)*DD*DD);
  unsigned short* ff1wb = (unsigned short*)alloc(sizeof(unsigned short)*DFFC*DD);
  unsigned short* ff2wb = (unsigned short*)alloc(sizeof(unsigned short)*DD*DFFC);
  unsigned short* x1b   = (unsigned short*)alloc(sizeof(unsigned short)*NN*DD);
  unsigned short* x2b   = (unsigned short*)alloc(sizeof(unsigned short)*NN*DD);
  unsigned short* ctxb  = (unsigned short*)alloc(sizeof(unsigned short)*NN*DD);
  unsigned short* ffhb  = (unsigned short*)alloc(sizeof(unsigned short)*NN*DFFC);
  (void)ws_size; (void)in_sizes; (void)n_in; (void)out_size;

  dim3 b256(256);
  auto f2bL = [&](const float* src, unsigned short* dst, int n) {
    f2b_kernel<<<(n/8 + 255)/256, b256, 0, stream>>>(src, dst, n/8);
  };
  // one-time bf16 conversions
  f2bL(x, xb, NN*DD);
  f2bL(hattr, hattrb, MM*DD);
  f2bL(Wh, Whb, DD*DD);
  f2bL(in_proj_w, ipwb, 3*DD*DD);
  f2bL(out_proj_w, opwb, DD*DD);
  f2bL(ff1_w, ff1wb, DFFC*DD);
  f2bL(ff2_w, ff2wb, DD*DFFC);

  // xl = x @ Wh^T ; el = hattr @ Wh^T  (bf16 MFMA, fp32 out)
  gemm_bt_bf16<<<dim3(NN/128, DD/128), b256, 0, stream>>>(xb, Whb, nullptr, xl, nullptr, DD, DD, 0);
  gemm_bt_bf16<<<dim3(MM/128, DD/128), b256, 0, stream>>>(hattrb, Whb, nullptr, el, nullptr, DD, DD, 0);
  // sparse hypergraph conv
  rowdot<<<NN/4, b256, 0, stream>>>(xl, att,      s_node, NN);
  rowdot<<<MM/4, b256, 0, stream>>>(el, att + DD, s_edge, MM);
  init_kernel<<<NN/256, b256, 0, stream>>>(amax, den, DnCnt, BnCnt, node_cur, edge_cur);
  incidence_pass1<<<NNZC/256, b256, 0, stream>>>(node_idx, edge_idx, s_node, s_edge,
                                                 a_buf, amax, DnCnt, BnCnt);
  exscan_kernel<<<1, 1024, 0, stream>>>(DnCnt, node_off, NN);
  exscan_kernel<<<1, 1024, 0, stream>>>(BnCnt, edge_off, MM);
  incidence_pass2<<<NNZC/256, b256, 0, stream>>>(node_idx, edge_idx, a_buf, amax, den,
                                                 node_off, edge_off, node_cur, edge_cur,
                                                 node_list, edge_list);
  gather_edge<<<MM, b256, 0, stream>>>(edge_off, edge_list, node_idx, a_buf, den, xl, ef);
  gather_node<<<NN, b256, 0, stream>>>(node_off, node_list, edge_idx, a_buf, den, ef, bias_h, conv);
  // x1 = LN(x + conv) (+ bf16 copy)
  ln_residual<<<NN, b256, 0, stream>>>(x, conv, ln1_g, ln1_b, x1, x1b);
  // qkv (fp32 out; attn converts K/V planes itself)
  gemm_bt_bf16<<<dim3(NN/128, (3*DD)/128), b256, 0, stream>>>(x1b, ipwb, in_proj_b, qkvb, nullptr, 3*DD, DD, 0);
  // attention (bf16 MFMA, bf16 ctx out)
  conv_k <<<NN*DD/(256*4), b256, 0, stream>>>(qkvb, Kb);
  conv_vt<<<dim3(NN/64, HH), b256, 0, stream>>>(qkvb, Vtb);
  attn_mfma<<<dim3(NN/64, HH), b256, 0, stream>>>(Kb, Vtb, qkvb, ctxb);
  // out_proj
  gemm_bt_bf16<<<dim3(NN/128, DD/128), b256, 0, stream>>>(ctxb, opwb, out_proj_b, attn_out, nullptr, DD, DD, 0);
  // x2 = LN(x1 + attn_out) (+ bf16)
  ln_residual<<<NN, b256, 0, stream>>>(x1, attn_out, tln1_g, tln1_b, x2, x2b);
  // ffn: ff1 (bf16 out w/ relu), ff2 (fp32 out)
  gemm_bt_bf16<<<dim3(NN/128, DFFC/128), b256, 0, stream>>>(x2b, ff1wb, ff1_b, nullptr, ffhb, DFFC, DD, 1);
  gemm_bt_bf16<<<dim3(NN/128, DD/128),   b256, 0, stream>>>(ffhb, ff2wb, ff2_b, ffo, nullptr, DD, DFFC, 0);
  // x3 = LN(x2 + ff)
  ln_residual<<<NN, b256, 0, stream>>>(x2, ffo, tln2_g, tln2_b, x3, nullptr);
  // out = LN(x1 + x3)
  ln_residual<<<NN, b256, 0, stream>>>(x1, x3, ln2_g, ln2_b, (float*)d_out, nullptr);
}

// Round 6
// 381.990 us; speedup vs baseline: 5.1892x; 1.0117x over previous
//
#include <hip/hip_runtime.h>
#include <math.h>

#define NN   4096
#define MM   1024
#define NNZC 65536
#define DD   512
#define HH   8
#define DHH  64
#define DFFC 2048
#define NSPLIT 4

typedef short bf16x8 __attribute__((ext_vector_type(8)));
typedef float f32x4  __attribute__((ext_vector_type(4)));

static __device__ inline unsigned short f2bf(float f) {
  union { float f; unsigned int u; } v; v.f = f;
  unsigned int r = v.u + 0x7fff + ((v.u >> 16) & 1);   // RNE
  return (unsigned short)(r >> 16);
}

__device__ inline void gload16(const void* g, void* l) {
  __builtin_amdgcn_global_load_lds(
      (const __attribute__((address_space(1))) void*)g,
      (__attribute__((address_space(3))) void*)l, 16, 0, 0);
}

// ---------------- utility ----------------
__device__ inline void atomicMaxF(float* addr, float val) {
  if (val >= 0.f) atomicMax((int*)addr, __float_as_int(val));
  else            atomicMin((unsigned int*)addr, __float_as_uint(val));
}

// ---------------- init ----------------
__global__ void init_kernel(float* amax, float* den, int* DnCnt, int* BnCnt,
                            int* node_cur, int* edge_cur) {
  int i = blockIdx.x * 256 + threadIdx.x;
  if (i < NN) { amax[i] = -INFINITY; den[i] = 0.f; DnCnt[i] = 0; node_cur[i] = 0; }
  if (i < MM) { BnCnt[i] = 0; edge_cur[i] = 0; }
}

// ---------------- fp32 -> bf16 bulk convert (8 elems/thread) ----------------
__global__ __launch_bounds__(256) void f2b_kernel(const float* __restrict__ in,
    unsigned short* __restrict__ out, int n8) {
  int i = blockIdx.x * 256 + threadIdx.x;
  if (i >= n8) return;
  float4 v0 = *(const float4*)&in[(size_t)i*8];
  float4 v1 = *(const float4*)&in[(size_t)i*8 + 4];
  unsigned short w[8];
  w[0]=f2bf(v0.x); w[1]=f2bf(v0.y); w[2]=f2bf(v0.z); w[3]=f2bf(v0.w);
  w[4]=f2bf(v1.x); w[5]=f2bf(v1.y); w[6]=f2bf(v1.z); w[7]=f2bf(v1.w);
  *(ulonglong2*)&out[(size_t)i*8] = *(ulonglong2*)w;
}

// ---------------- bf16 MFMA NT GEMM: C[M,N] = A[M,K] @ B[N,K]^T (+bias,+relu) ----------------
__global__ __launch_bounds__(256) void gemm_bt_bf16(
    const unsigned short* __restrict__ A, const unsigned short* __restrict__ B,
    const float* __restrict__ bias, float* __restrict__ Cf,
    unsigned short* __restrict__ Cb, int N, int K, int relu) {
  __shared__ __align__(16) unsigned short Al[128*64];
  __shared__ __align__(16) unsigned short Bl[128*64];
  const int t = threadIdx.x;
  const int w = t >> 6, l = t & 63;
  const int lg = l >> 4, lid = l & 15;
  const int wr = w >> 1, wc = w & 1;
  const int bm = blockIdx.x * 128, bn = blockIdx.y * 128;

  f32x4 acc[4][4];
  #pragma unroll
  for (int mi = 0; mi < 4; ++mi)
    #pragma unroll
    for (int ni = 0; ni < 4; ++ni) acc[mi][ni] = (f32x4)0.f;

  for (int k0 = 0; k0 < K; k0 += 64) {
    #pragma unroll
    for (int i = 0; i < 4; ++i) {
      int cid = i*256 + t;
      int row = cid >> 3, cp = cid & 7;
      int gc = cp ^ (row & 7);
      gload16(&A[(size_t)(bm + row)*K + k0 + gc*8], &Al[cid*8]);
      gload16(&B[(size_t)(bn + row)*K + k0 + gc*8], &Bl[cid*8]);
    }
    asm volatile("s_waitcnt vmcnt(0)" ::: "memory");
    __syncthreads();
    #pragma unroll
    for (int ks = 0; ks < 2; ++ks) {
      bf16x8 af[4], bfr[4];
      #pragma unroll
      for (int mi = 0; mi < 4; ++mi) {
        int r = wr*64 + mi*16 + lid;
        af[mi] = *(const bf16x8*)&Al[r*64 + ((ks*4 + lg) ^ (r & 7))*8];
      }
      #pragma unroll
      for (int ni = 0; ni < 4; ++ni) {
        int r = wc*64 + ni*16 + lid;
        bfr[ni] = *(const bf16x8*)&Bl[r*64 + ((ks*4 + lg) ^ (r & 7))*8];
      }
      __builtin_amdgcn_s_setprio(1);
      #pragma unroll
      for (int mi = 0; mi < 4; ++mi)
        #pragma unroll
        for (int ni = 0; ni < 4; ++ni)
          acc[mi][ni] = __builtin_amdgcn_mfma_f32_16x16x32_bf16(af[mi], bfr[ni], acc[mi][ni], 0, 0, 0);
      __builtin_amdgcn_s_setprio(0);
    }
    __syncthreads();
  }

  #pragma unroll
  for (int ni = 0; ni < 4; ++ni) {
    int col = bn + wc*64 + ni*16 + lid;
    float bv = bias ? bias[col] : 0.f;
    #pragma unroll
    for (int mi = 0; mi < 4; ++mi) {
      #pragma unroll
      for (int rg = 0; rg < 4; ++rg) {
        int row = bm + wr*64 + mi*16 + lg*4 + rg;
        float v = acc[mi][ni][rg] + bv;
        if (relu) v = fmaxf(v, 0.f);
        if (Cf) Cf[(size_t)row*N + col] = v;
        if (Cb) Cb[(size_t)row*N + col] = f2bf(v);
      }
    }
  }
}

// ---------------- per-row dot ----------------
__global__ __launch_bounds__(256) void rowdot(const float* __restrict__ X,
    const float* __restrict__ vec, float* __restrict__ out, int rows) {
  int w = (blockIdx.x * 256 + threadIdx.x) >> 6;
  int lane = threadIdx.x & 63;
  if (w >= rows) return;
  const float* xr = &X[(size_t)w * DD];
  float s = 0.f;
  #pragma unroll
  for (int j = 0; j < 8; ++j) s += xr[lane + 64*j] * vec[lane + 64*j];
  #pragma unroll
  for (int off = 1; off < 64; off <<= 1) s += __shfl_xor(s, off, 64);
  if (lane == 0) out[w] = s;
}

// ---------------- incidence pass 1 ----------------
__global__ void incidence_pass1(const int* __restrict__ node_idx, const int* __restrict__ edge_idx,
    const float* __restrict__ s_node, const float* __restrict__ s_edge,
    float* __restrict__ a_buf, float* amax, int* DnCnt, int* BnCnt) {
  int i = blockIdx.x * 256 + threadIdx.x;
  if (i >= NNZC) return;
  int n = node_idx[i], m = edge_idx[i];
  float a = s_node[n] + s_edge[m];
  a = (a >= 0.f) ? a : 0.2f * a;
  a_buf[i] = a;
  atomicMaxF(&amax[n], a);
  atomicAdd(&DnCnt[n], 1);
  atomicAdd(&BnCnt[m], 1);
}

// ---------------- single-block exclusive scan ----------------
__global__ __launch_bounds__(1024) void exscan_kernel(const int* __restrict__ in,
                                                      int* __restrict__ out, int n) {
  __shared__ int sums[1024];
  const int t = threadIdx.x;
  const int chunk = (n + 1023) >> 10;
  const int start = t * chunk;
  const int stop  = min(start + chunk, n);
  int local = 0;
  for (int i = start; i < stop; ++i) local += in[i];
  sums[t] = local;
  __syncthreads();
  for (int o = 1; o < 1024; o <<= 1) {
    int v = (t >= o) ? sums[t - o] : 0;
    __syncthreads();
    sums[t] += v;
    __syncthreads();
  }
  int run = (t == 0) ? 0 : sums[t - 1];
  for (int i = start; i < stop; ++i) { out[i] = run; run += in[i]; }
  if (t == 1023) out[n] = sums[1023];
}

// ---------------- incidence pass 2 ----------------
__global__ void incidence_pass2(const int* __restrict__ node_idx, const int* __restrict__ edge_idx,
    float* __restrict__ a_buf, const float* __restrict__ amax, float* den,
    const int* __restrict__ node_off, const int* __restrict__ edge_off,
    int* node_cur, int* edge_cur, int* node_list, int* edge_list) {
  int i = blockIdx.x * 256 + threadIdx.x;
  if (i >= NNZC) return;
  int n = node_idx[i], m = edge_idx[i];
  float e = __expf(a_buf[i] - amax[n]);
  a_buf[i] = e;
  atomicAdd(&den[n], e);
  int pn = atomicAdd(&node_cur[n], 1);
  node_list[node_off[n] + pn] = i;
  int pm = atomicAdd(&edge_cur[m], 1);
  edge_list[edge_off[m] + pm] = i;
}

// ---------------- edge gather ----------------
__global__ __launch_bounds__(256) void gather_edge(const int* __restrict__ edge_off,
    const int* __restrict__ edge_list, const int* __restrict__ node_idx,
    const float* __restrict__ a_buf, const float* __restrict__ den,
    const float* __restrict__ xl, float* __restrict__ ef) {
  int m = blockIdx.x;
  int t = threadIdx.x;
  int beg = edge_off[m], end = edge_off[m+1];
  int cnt = end - beg;
  float Binv = (cnt > 0) ? (1.0f / (float)cnt) : 0.f;
  __shared__ int   ln_[128];
  __shared__ float lw_[128];
  float acc0 = 0.f, acc1 = 0.f;
  for (int c = beg; c < end; c += 128) {
    int nchunk = min(128, end - c);
    if (t < nchunk) {
      int i = edge_list[c + t];
      int n = node_idx[i];
      ln_[t] = n;
      lw_[t] = a_buf[i] / (den[n] + 1e-16f) * Binv;
    }
    __syncthreads();
    for (int j = 0; j < nchunk; ++j) {
      const float w = lw_[j];
      const float* xr = &xl[(size_t)ln_[j] * DD];
      acc0 += w * xr[t];
      acc1 += w * xr[t + 256];
    }
    __syncthreads();
  }
  ef[(size_t)m * DD + t]       = acc0;
  ef[(size_t)m * DD + t + 256] = acc1;
}

// ---------------- node gather ----------------
__global__ __launch_bounds__(256) void gather_node(const int* __restrict__ node_off,
    const int* __restrict__ node_list, const int* __restrict__ edge_idx,
    const float* __restrict__ a_buf, const float* __restrict__ den,
    const float* __restrict__ ef, const float* __restrict__ bias_h, float* __restrict__ conv) {
  int n = blockIdx.x;
  int t = threadIdx.x;
  int beg = node_off[n], end = node_off[n+1];
  int cnt = end - beg;
  float Dinv = (cnt > 0) ? (1.0f / (float)cnt) : 0.f;
  float wscale = Dinv / (den[n] + 1e-16f);
  __shared__ int   le_[128];
  __shared__ float lw_[128];
  float acc0 = 0.f, acc1 = 0.f;
  for (int c = beg; c < end; c += 128) {
    int nchunk = min(128, end - c);
    if (t < nchunk) {
      int i = node_list[c + t];
      le_[t] = edge_idx[i];
      lw_[t] = a_buf[i] * wscale;
    }
    __syncthreads();
    for (int j = 0; j < nchunk; ++j) {
      const float w = lw_[j];
      const float* er = &ef[(size_t)le_[j] * DD];
      acc0 += w * er[t];
      acc1 += w * er[t + 256];
    }
    __syncthreads();
  }
  conv[(size_t)n * DD + t]       = acc0 + bias_h[t];
  conv[(size_t)n * DD + t + 256] = acc1 + bias_h[t + 256];
}

// ---------------- LayerNorm(a + b), optional bf16 copy ----------------
__global__ __launch_bounds__(256) void ln_residual(const float* __restrict__ a,
    const float* __restrict__ b, const float* __restrict__ g, const float* __restrict__ be,
    float* __restrict__ out, unsigned short* __restrict__ outb) {
  int r = blockIdx.x;
  int t = threadIdx.x;
  float v0 = a[(size_t)r*DD + t]       + b[(size_t)r*DD + t];
  float v1 = a[(size_t)r*DD + t + 256] + b[(size_t)r*DD + t + 256];
  __shared__ float red[4];
  __shared__ float mu_s, rstd_s;
  float s = v0 + v1;
  #pragma unroll
  for (int off = 1; off < 64; off <<= 1) s += __shfl_xor(s, off, 64);
  int wid = t >> 6;
  if ((t & 63) == 0) red[wid] = s;
  __syncthreads();
  if (t == 0) mu_s = (red[0] + red[1] + red[2] + red[3]) / 512.f;
  __syncthreads();
  float mu = mu_s;
  float d0 = v0 - mu, d1 = v1 - mu;
  float vs = d0*d0 + d1*d1;
  #pragma unroll
  for (int off = 1; off < 64; off <<= 1) vs += __shfl_xor(vs, off, 64);
  if ((t & 63) == 0) red[wid] = vs;
  __syncthreads();
  if (t == 0) rstd_s = rsqrtf((red[0] + red[1] + red[2] + red[3]) / 512.f + 1e-5f);
  __syncthreads();
  float rs = rstd_s;
  float o0 = d0 * rs * g[t]       + be[t];
  float o1 = d1 * rs * g[t + 256] + be[t + 256];
  out[(size_t)r*DD + t]       = o0;
  out[(size_t)r*DD + t + 256] = o1;
  if (outb) {
    outb[(size_t)r*DD + t]       = f2bf(o0);
    outb[(size_t)r*DD + t + 256] = f2bf(o1);
  }
}

// ---------------- K-plane fp32 -> bf16 : Kb[h][tok][64] ----------------
__global__ __launch_bounds__(256) void conv_k(const float* __restrict__ qkv,
                                              unsigned short* __restrict__ Kb) {
  int idx = blockIdx.x * 256 + threadIdx.x;
  int e = idx * 4;
  int tok = e >> 9;
  int hd = e & 511;
  float4 v = *(const float4*)&qkv[(size_t)tok*1536 + 512 + hd];
  int h = hd >> 6, d = hd & 63;
  ushort4 w4;
  w4.x = f2bf(v.x); w4.y = f2bf(v.y); w4.z = f2bf(v.z); w4.w = f2bf(v.w);
  *(ushort4*)&Kb[(size_t)h*NN*64 + (size_t)tok*64 + d] = w4;
}

// ---------------- V-plane fp32 -> bf16 transposed : Vtb[h][d][tok] ----------------
__global__ __launch_bounds__(256) void conv_vt(const float* __restrict__ qkv,
                                               unsigned short* __restrict__ Vtb) {
  __shared__ unsigned short Tl[64][76];
  const int h = blockIdx.y;
  const int tt = blockIdx.x * 64;
  const int t = threadIdx.x;
  {
    int row = t >> 2;
    int cbase = (t & 3) * 16;
    const float* src = &qkv[(size_t)(tt + row)*1536 + 1024 + h*64 + cbase];
    #pragma unroll
    for (int jj = 0; jj < 4; ++jj) {
      float4 v = *(const float4*)&src[jj*4];
      ushort4 w4;
      w4.x = f2bf(v.x); w4.y = f2bf(v.y); w4.z = f2bf(v.z); w4.w = f2bf(v.w);
      *(ushort4*)&Tl[row][cbase + jj*4] = w4;
    }
  }
  __syncthreads();
  #pragma unroll
  for (int it = 0; it < 4; ++it) {
    int d = it*16 + (t >> 4);
    int tk = (t & 15) * 4;
    ushort4 w4;
    w4.x = Tl[tk+0][d]; w4.y = Tl[tk+1][d]; w4.z = Tl[tk+2][d]; w4.w = Tl[tk+3][d];
    *(ushort4*)&Vtb[(size_t)h*64*NN + (size_t)d*NN + tt + tk] = w4;
  }
}

// ---------------- MFMA flash attention partial (split-K): 64 q-rows/block, 4 waves ----------------
// base-2 softmax (log2e folded into Q scale); writes unnormalized O + (m,l) per q-row.
__global__ __launch_bounds__(256) void attn_mfma_part(const unsigned short* __restrict__ Kb,
                                                      const unsigned short* __restrict__ Vtb,
                                                      const float* __restrict__ qkv,
                                                      float* __restrict__ Opart,
                                                      float* __restrict__ ml) {
  const int head = blockIdx.y;
  const int z = blockIdx.z;
  const int q0 = blockIdx.x * 64;
  const int t = threadIdx.x;
  const int w = t >> 6;
  const int l = t & 63;
  const int lg = l >> 4;
  const int lid = l & 15;

  __shared__ __align__(16) unsigned short Kl[64*64];
  __shared__ __align__(16) unsigned short Vl[64*64];
  __shared__ __align__(16) unsigned short Pl[4][16*72];

  union { bf16x8 v; unsigned short u[8]; } qa[2];
  {
    const int qrow = q0 + w*16 + lid;
    const float* qp = &qkv[(size_t)qrow*1536 + head*64];
    const float qs = 0.125f * 1.44269504f;   // 1/sqrt(64) * log2(e)
    #pragma unroll
    for (int hf = 0; hf < 2; ++hf)
      #pragma unroll
      for (int j = 0; j < 8; ++j)
        qa[hf].u[j] = f2bf(qp[hf*32 + lg*8 + j] * qs);
  }

  float m[4], lsum[4];
  f32x4 o[4];
  #pragma unroll
  for (int r = 0; r < 4; ++r) { m[r] = -1e30f; lsum[r] = 0.f; }
  #pragma unroll
  for (int dt = 0; dt < 4; ++dt) o[dt] = (f32x4)0.f;

  const unsigned short* Kh = Kb  + (size_t)head*NN*64;
  const unsigned short* Vh = Vtb + (size_t)head*64*NN;
  unsigned short* pw = Pl[w];
  const int kt0 = z * (NN / NSPLIT);
  const int kt1 = kt0 + (NN / NSPLIT);

  for (int kt = kt0; kt < kt1; kt += 64) {
    #pragma unroll
    for (int it = 0; it < 2; ++it) {
      int idx = it*256 + t;
      int row = idx >> 3;
      int cc  = (idx & 7) * 8;
      int didx = (row*64 + cc) ^ ((row & 7) << 3);
      *(ulonglong2*)&Kl[didx] = *(const ulonglong2*)&Kh[(size_t)(kt + row)*64 + cc];
      *(ulonglong2*)&Vl[didx] = *(const ulonglong2*)&Vh[(size_t)row*NN + kt + cc];
    }
    __syncthreads();

    f32x4 s[4];
    #pragma unroll
    for (int n = 0; n < 4; ++n) s[n] = (f32x4)0.f;
    __builtin_amdgcn_s_setprio(1);
    #pragma unroll
    for (int n = 0; n < 4; ++n) {
      int tok = n*16 + lid;
      #pragma unroll
      for (int hf = 0; hf < 2; ++hf) {
        int didx = (tok*64 + hf*32 + lg*8) ^ ((tok & 7) << 3);
        bf16x8 kb = *(const bf16x8*)&Kl[didx];
        s[n] = __builtin_amdgcn_mfma_f32_16x16x32_bf16(qa[hf].v, kb, s[n], 0, 0, 0);
      }
    }
    __builtin_amdgcn_s_setprio(0);

    #pragma unroll
    for (int r = 0; r < 4; ++r) {
      float mx = fmaxf(fmaxf(s[0][r], s[1][r]), fmaxf(s[2][r], s[3][r]));
      mx = fmaxf(mx, __shfl_xor(mx, 1, 64));
      mx = fmaxf(mx, __shfl_xor(mx, 2, 64));
      mx = fmaxf(mx, __shfl_xor(mx, 4, 64));
      mx = fmaxf(mx, __shfl_xor(mx, 8, 64));
      float mn = fmaxf(m[r], mx);
      float c = exp2f(m[r] - mn);
      m[r] = mn;
      lsum[r] *= c;
      #pragma unroll
      for (int dt = 0; dt < 4; ++dt) o[dt][r] *= c;
      float ps = 0.f;
      #pragma unroll
      for (int n = 0; n < 4; ++n) {
        float p = exp2f(s[n][r] - mn);
        s[n][r] = p;
        ps += p;
      }
      ps += __shfl_xor(ps, 1, 64); ps += __shfl_xor(ps, 2, 64);
      ps += __shfl_xor(ps, 4, 64); ps += __shfl_xor(ps, 8, 64);
      lsum[r] += ps;
    }

    #pragma unroll
    for (int n = 0; n < 4; ++n)
      #pragma unroll
      for (int r = 0; r < 4; ++r)
        pw[(lg*4 + r)*72 + n*16 + lid] = f2bf(s[n][r]);

    bf16x8 pa[2];
    #pragma unroll
    for (int hf = 0; hf < 2; ++hf)
      pa[hf] = *(const bf16x8*)&pw[lid*72 + hf*32 + lg*8];

    __builtin_amdgcn_s_setprio(1);
    #pragma unroll
    for (int dt = 0; dt < 4; ++dt) {
      int drow = dt*16 + lid;
      #pragma unroll
      for (int hf = 0; hf < 2; ++hf) {
        int didx = (drow*64 + hf*32 + lg*8) ^ ((drow & 7) << 3);
        bf16x8 vb = *(const bf16x8*)&Vl[didx];
        o[dt] = __builtin_amdgcn_mfma_f32_16x16x32_bf16(pa[hf], vb, o[dt], 0, 0, 0);
      }
    }
    __builtin_amdgcn_s_setprio(0);
    __syncthreads();
  }

  // ---- epilogue: unnormalized partial O + (m, l) ----
  #pragma unroll
  for (int r = 0; r < 4; ++r) {
    int q = q0 + w*16 + lg*4 + r;
    size_t base = ((size_t)(z*HH + head)*NN + q)*64;
    #pragma unroll
    for (int dt = 0; dt < 4; ++dt)
      Opart[base + dt*16 + lid] = o[dt][r];
    if (lid == 0) {
      size_t mb = ((size_t)(z*HH + head)*NN + q)*2;
      ml[mb]     = m[r];
      ml[mb + 1] = lsum[r];
    }
  }
}

// ---------------- combine split-K partials -> ctx bf16 ----------------
__global__ __launch_bounds__(256) void attn_combine(const float* __restrict__ Opart,
                                                    const float* __restrict__ ml,
                                                    unsigned short* __restrict__ ctxb) {
  const int w = threadIdx.x >> 6, lane = threadIdx.x & 63;
  const int row = blockIdx.x * 4 + w;     // 0 .. NN*HH-1
  const int q = row >> 3, head = row & 7;
  float ms[NSPLIT], ls[NSPLIT];
  float mglob = -1e30f;
  #pragma unroll
  for (int s = 0; s < NSPLIT; ++s) {
    size_t mb = ((size_t)(s*HH + head)*NN + q)*2;
    ms[s] = ml[mb]; ls[s] = ml[mb + 1];
    mglob = fmaxf(mglob, ms[s]);
  }
  float lt = 0.f, ov = 0.f;
  #pragma unroll
  for (int s = 0; s < NSPLIT; ++s) {
    float wgt = exp2f(ms[s] - mglob);
    lt += ls[s] * wgt;
    ov += Opart[((size_t)(s*HH + head)*NN + q)*64 + lane] * wgt;
  }
  ctxb[(size_t)q*DD + head*64 + lane] = f2bf(ov / lt);
}

// ---------------- host ----------------
extern "C" void kernel_launch(void* const* d_in, const int* in_sizes, int n_in,
                              void* d_out, int out_size, void* d_ws, size_t ws_size,
                              hipStream_t stream) {
  const float* x       = (const float*)d_in[0];
  const int*   hidx    = (const int*)d_in[1];
  const float* hattr   = (const float*)d_in[2];
  const float* Wh      = (const float*)d_in[3];
  const float* att     = (const float*)d_in[4];
  const float* bias_h  = (const float*)d_in[5];
  const float* ln1_g   = (const float*)d_in[6];
  const float* ln1_b   = (const float*)d_in[7];
  const float* ln2_g   = (const float*)d_in[8];
  const float* ln2_b   = (const float*)d_in[9];
  const float* in_proj_w  = (const float*)d_in[10];
  const float* in_proj_b  = (const float*)d_in[11];
  const float* out_proj_w = (const float*)d_in[12];
  const float* out_proj_b = (const float*)d_in[13];
  const float* ff1_w   = (const float*)d_in[14];
  const float* ff1_b   = (const float*)d_in[15];
  const float* ff2_w   = (const float*)d_in[16];
  const float* ff2_b   = (const float*)d_in[17];
  const float* tln1_g  = (const float*)d_in[18];
  const float* tln1_b  = (const float*)d_in[19];
  const float* tln2_g  = (const float*)d_in[20];
  const float* tln2_b  = (const float*)d_in[21];
  const int* node_idx = hidx;
  const int* edge_idx = hidx + NNZC;

  char* ws = (char*)d_ws;
  size_t off = 0;
  auto alloc = [&](size_t bytes) -> void* {
    void* p = ws + off;
    off = (off + bytes + 63) & ~(size_t)63;
    return p;
  };
  float* xl       = (float*)alloc(sizeof(float)*NN*DD);
  float* el       = (float*)alloc(sizeof(float)*MM*DD);
  float* s_node   = (float*)alloc(sizeof(float)*NN);
  float* s_edge   = (float*)alloc(sizeof(float)*MM);
  float* a_buf    = (float*)alloc(sizeof(float)*NNZC);
  float* amax     = (float*)alloc(sizeof(float)*NN);
  float* den      = (float*)alloc(sizeof(float)*NN);
  int*   DnCnt    = (int*)alloc(sizeof(int)*NN);
  int*   BnCnt    = (int*)alloc(sizeof(int)*MM);
  int*   node_off = (int*)alloc(sizeof(int)*(NN+1));
  int*   edge_off = (int*)alloc(sizeof(int)*(MM+1));
  int*   node_cur = (int*)alloc(sizeof(int)*NN);
  int*   edge_cur = (int*)alloc(sizeof(int)*MM);
  int*   node_list= (int*)alloc(sizeof(int)*NNZC);
  int*   edge_list= (int*)alloc(sizeof(int)*NNZC);
  float* ef       = (float*)alloc(sizeof(float)*MM*DD);
  float* conv     = (float*)alloc(sizeof(float)*NN*DD);
  float* x1       = (float*)alloc(sizeof(float)*NN*DD);
  float* qkvb     = (float*)alloc(sizeof(float)*NN*3*DD);
  float* attn_out = (float*)alloc(sizeof(float)*NN*DD);
  float* x2       = (float*)alloc(sizeof(float)*NN*DD);
  unsigned short* Kb    = (unsigned short*)alloc(sizeof(unsigned short)*NN*DD);
  unsigned short* Vtb   = (unsigned short*)alloc(sizeof(unsigned short)*NN*DD);
  unsigned short* xb    = (unsigned short*)alloc(sizeof(unsigned short)*NN*DD);
  unsigned short* hattrb= (unsigned short*)alloc(sizeof(unsigned short)*MM*DD);
  unsigned short* Whb   = (unsigned short*)alloc(sizeof(unsigned short)*DD*DD);
  unsigned short* ipwb  = (unsigned short*)alloc(sizeof(unsigned short)*3*DD*DD);
  unsigned short* opwb  = (unsigned short*)alloc(sizeof(unsigned short)*DD*DD);
  unsigned short* ff1wb = (unsigned short*)alloc(sizeof(unsigned short)*DFFC*DD);
  unsigned short* ff2wb = (unsigned short*)alloc(sizeof(unsigned short)*DD*DFFC);
  unsigned short* x1b   = (unsigned short*)alloc(sizeof(unsigned short)*NN*DD);
  unsigned short* x2b   = (unsigned short*)alloc(sizeof(unsigned short)*NN*DD);
  unsigned short* ctxb  = (unsigned short*)alloc(sizeof(unsigned short)*NN*DD);
  // "late" region: attention partials (Opart 32MB + ml 1MB) alias the FFN-phase
  // buffers (ffhb 16MB + ffo 8MB + x3 8MB) — Opart/ml are dead before ff1 runs.
  char* late = (char*)alloc(33u*1024*1024);
  float*          Opart = (float*)late;                                  // 32 MB (attn phase)
  float*          mlb   = (float*)(late + 32u*1024*1024);                // 1 MB (attn phase)
  unsigned short* ffhb  = (unsigned short*)late;                         // 16 MB (FFN phase)
  float*          ffo   = (float*)(late + 16u*1024*1024);                // 8 MB (FFN phase)
  float*          x3    = (float*)(late + 24u*1024*1024);                // 8 MB (FFN phase)
  (void)ws_size; (void)in_sizes; (void)n_in; (void)out_size;

  dim3 b256(256);
  auto f2bL = [&](const float* src, unsigned short* dst, int n) {
    f2b_kernel<<<(n/8 + 255)/256, b256, 0, stream>>>(src, dst, n/8);
  };
  // one-time bf16 conversions
  f2bL(x, xb, NN*DD);
  f2bL(hattr, hattrb, MM*DD);
  f2bL(Wh, Whb, DD*DD);
  f2bL(in_proj_w, ipwb, 3*DD*DD);
  f2bL(out_proj_w, opwb, DD*DD);
  f2bL(ff1_w, ff1wb, DFFC*DD);
  f2bL(ff2_w, ff2wb, DD*DFFC);

  // xl = x @ Wh^T ; el = hattr @ Wh^T  (bf16 MFMA, fp32 out)
  gemm_bt_bf16<<<dim3(NN/128, DD/128), b256, 0, stream>>>(xb, Whb, nullptr, xl, nullptr, DD, DD, 0);
  gemm_bt_bf16<<<dim3(MM/128, DD/128), b256, 0, stream>>>(hattrb, Whb, nullptr, el, nullptr, DD, DD, 0);
  // sparse hypergraph conv
  rowdot<<<NN/4, b256, 0, stream>>>(xl, att,      s_node, NN);
  rowdot<<<MM/4, b256, 0, stream>>>(el, att + DD, s_edge, MM);
  init_kernel<<<NN/256, b256, 0, stream>>>(amax, den, DnCnt, BnCnt, node_cur, edge_cur);
  incidence_pass1<<<NNZC/256, b256, 0, stream>>>(node_idx, edge_idx, s_node, s_edge,
                                                 a_buf, amax, DnCnt, BnCnt);
  exscan_kernel<<<1, 1024, 0, stream>>>(DnCnt, node_off, NN);
  exscan_kernel<<<1, 1024, 0, stream>>>(BnCnt, edge_off, MM);
  incidence_pass2<<<NNZC/256, b256, 0, stream>>>(node_idx, edge_idx, a_buf, amax, den,
                                                 node_off, edge_off, node_cur, edge_cur,
                                                 node_list, edge_list);
  gather_edge<<<MM, b256, 0, stream>>>(edge_off, edge_list, node_idx, a_buf, den, xl, ef);
  gather_node<<<NN, b256, 0, stream>>>(node_off, node_list, edge_idx, a_buf, den, ef, bias_h, conv);
  // x1 = LN(x + conv) (+ bf16 copy)
  ln_residual<<<NN, b256, 0, stream>>>(x, conv, ln1_g, ln1_b, x1, x1b);
  // qkv
  gemm_bt_bf16<<<dim3(NN/128, (3*DD)/128), b256, 0, stream>>>(x1b, ipwb, in_proj_b, qkvb, nullptr, 3*DD, DD, 0);
  // attention (bf16 MFMA, split-K x4 + combine)
  conv_k <<<NN*DD/(256*4), b256, 0, stream>>>(qkvb, Kb);
  conv_vt<<<dim3(NN/64, HH), b256, 0, stream>>>(qkvb, Vtb);
  attn_mfma_part<<<dim3(NN/64, HH, NSPLIT), b256, 0, stream>>>(Kb, Vtb, qkvb, Opart, mlb);
  attn_combine<<<NN*HH/4, b256, 0, stream>>>(Opart, mlb, ctxb);
  // out_proj
  gemm_bt_bf16<<<dim3(NN/128, DD/128), b256, 0, stream>>>(ctxb, opwb, out_proj_b, attn_out, nullptr, DD, DD, 0);
  // x2 = LN(x1 + attn_out) (+ bf16)
  ln_residual<<<NN, b256, 0, stream>>>(x1, attn_out, tln1_g, tln1_b, x2, x2b);
  // ffn: ff1 (bf16 out w/ relu), ff2 (fp32 out)
  gemm_bt_bf16<<<dim3(NN/128, DFFC/128), b256, 0, stream>>>(x2b, ff1wb, ff1_b, nullptr, ffhb, DFFC, DD, 1);
  gemm_bt_bf16<<<dim3(NN/128, DD/128),   b256, 0, stream>>>(ffhb, ff2wb, ff2_b, ffo, nullptr, DD, DFFC, 0);
  // x3 = LN(x2 + ff)
  ln_residual<<<NN, b256, 0, stream>>>(x2, ffo, tln2_g, tln2_b, x3, nullptr);
  // out = LN(x1 + x3)
  ln_residual<<<NN, b256, 0, stream>>>(x1, x3, ln2_g, ln2_b, (float*)d_out, nullptr);
}

// Round 7
// 371.374 us; speedup vs baseline: 5.3376x; 1.0286x over previous
//
#include <hip/hip_runtime.h>
#include <math.h>

#define NN   4096
#define MM   1024
#define NNZC 65536
#define DD   512
#define HH   8
#define DHH  64
#define DFFC 2048
#define NSPLIT 4

typedef short bf16x8 __attribute__((ext_vector_type(8)));
typedef float f32x4  __attribute__((ext_vector_type(4)));

static __device__ inline unsigned short f2bf(float f) {
  union { float f; unsigned int u; } v; v.f = f;
  unsigned int r = v.u + 0x7fff + ((v.u >> 16) & 1);   // RNE
  return (unsigned short)(r >> 16);
}

__device__ inline void gload16(const void* g, void* l) {
  __builtin_amdgcn_global_load_lds(
      (const __attribute__((address_space(1))) void*)g,
      (__attribute__((address_space(3))) void*)l, 16, 0, 0);
}

// ---------------- utility ----------------
__device__ inline void atomicMaxF(float* addr, float val) {
  if (val >= 0.f) atomicMax((int*)addr, __float_as_int(val));
  else            atomicMin((unsigned int*)addr, __float_as_uint(val));
}

// ---------------- init ----------------
__global__ void init_kernel(float* amax, float* den, int* DnCnt, int* BnCnt,
                            int* node_cur, int* edge_cur) {
  int i = blockIdx.x * 256 + threadIdx.x;
  if (i < NN) { amax[i] = -INFINITY; den[i] = 0.f; DnCnt[i] = 0; node_cur[i] = 0; }
  if (i < MM) { BnCnt[i] = 0; edge_cur[i] = 0; }
}

// ---------------- fp32 -> bf16 bulk convert (8 elems/thread) ----------------
__global__ __launch_bounds__(256) void f2b_kernel(const float* __restrict__ in,
    unsigned short* __restrict__ out, int n8) {
  int i = blockIdx.x * 256 + threadIdx.x;
  if (i >= n8) return;
  float4 v0 = *(const float4*)&in[(size_t)i*8];
  float4 v1 = *(const float4*)&in[(size_t)i*8 + 4];
  unsigned short w[8];
  w[0]=f2bf(v0.x); w[1]=f2bf(v0.y); w[2]=f2bf(v0.z); w[3]=f2bf(v0.w);
  w[4]=f2bf(v1.x); w[5]=f2bf(v1.y); w[6]=f2bf(v1.z); w[7]=f2bf(v1.w);
  *(ulonglong2*)&out[(size_t)i*8] = *(ulonglong2*)w;
}

// ---------------- bf16 MFMA NT GEMM: C[M,N] = A[M,K] @ B[N,K]^T (+bias,+relu) ----------------
__global__ __launch_bounds__(256) void gemm_bt_bf16(
    const unsigned short* __restrict__ A, const unsigned short* __restrict__ B,
    const float* __restrict__ bias, float* __restrict__ Cf,
    unsigned short* __restrict__ Cb, int N, int K, int relu) {
  __shared__ __align__(16) unsigned short Al[128*64];
  __shared__ __align__(16) unsigned short Bl[128*64];
  const int t = threadIdx.x;
  const int w = t >> 6, l = t & 63;
  const int lg = l >> 4, lid = l & 15;
  const int wr = w >> 1, wc = w & 1;
  const int bm = blockIdx.x * 128, bn = blockIdx.y * 128;

  f32x4 acc[4][4];
  #pragma unroll
  for (int mi = 0; mi < 4; ++mi)
    #pragma unroll
    for (int ni = 0; ni < 4; ++ni) acc[mi][ni] = (f32x4)0.f;

  for (int k0 = 0; k0 < K; k0 += 64) {
    #pragma unroll
    for (int i = 0; i < 4; ++i) {
      int cid = i*256 + t;
      int row = cid >> 3, cp = cid & 7;
      int gc = cp ^ (row & 7);
      gload16(&A[(size_t)(bm + row)*K + k0 + gc*8], &Al[cid*8]);
      gload16(&B[(size_t)(bn + row)*K + k0 + gc*8], &Bl[cid*8]);
    }
    asm volatile("s_waitcnt vmcnt(0)" ::: "memory");
    __syncthreads();
    #pragma unroll
    for (int ks = 0; ks < 2; ++ks) {
      bf16x8 af[4], bfr[4];
      #pragma unroll
      for (int mi = 0; mi < 4; ++mi) {
        int r = wr*64 + mi*16 + lid;
        af[mi] = *(const bf16x8*)&Al[r*64 + ((ks*4 + lg) ^ (r & 7))*8];
      }
      #pragma unroll
      for (int ni = 0; ni < 4; ++ni) {
        int r = wc*64 + ni*16 + lid;
        bfr[ni] = *(const bf16x8*)&Bl[r*64 + ((ks*4 + lg) ^ (r & 7))*8];
      }
      __builtin_amdgcn_s_setprio(1);
      #pragma unroll
      for (int mi = 0; mi < 4; ++mi)
        #pragma unroll
        for (int ni = 0; ni < 4; ++ni)
          acc[mi][ni] = __builtin_amdgcn_mfma_f32_16x16x32_bf16(af[mi], bfr[ni], acc[mi][ni], 0, 0, 0);
      __builtin_amdgcn_s_setprio(0);
    }
    __syncthreads();
  }

  #pragma unroll
  for (int ni = 0; ni < 4; ++ni) {
    int col = bn + wc*64 + ni*16 + lid;
    float bv = bias ? bias[col] : 0.f;
    #pragma unroll
    for (int mi = 0; mi < 4; ++mi) {
      #pragma unroll
      for (int rg = 0; rg < 4; ++rg) {
        int row = bm + wr*64 + mi*16 + lg*4 + rg;
        float v = acc[mi][ni][rg] + bv;
        if (relu) v = fmaxf(v, 0.f);
        if (Cf) Cf[(size_t)row*N + col] = v;
        if (Cb) Cb[(size_t)row*N + col] = f2bf(v);
      }
    }
  }
}

// ---------------- per-row dot ----------------
__global__ __launch_bounds__(256) void rowdot(const float* __restrict__ X,
    const float* __restrict__ vec, float* __restrict__ out, int rows) {
  int w = (blockIdx.x * 256 + threadIdx.x) >> 6;
  int lane = threadIdx.x & 63;
  if (w >= rows) return;
  const float* xr = &X[(size_t)w * DD];
  float s = 0.f;
  #pragma unroll
  for (int j = 0; j < 8; ++j) s += xr[lane + 64*j] * vec[lane + 64*j];
  #pragma unroll
  for (int off = 1; off < 64; off <<= 1) s += __shfl_xor(s, off, 64);
  if (lane == 0) out[w] = s;
}

// ---------------- incidence pass 1 ----------------
__global__ void incidence_pass1(const int* __restrict__ node_idx, const int* __restrict__ edge_idx,
    const float* __restrict__ s_node, const float* __restrict__ s_edge,
    float* __restrict__ a_buf, float* amax, int* DnCnt, int* BnCnt) {
  int i = blockIdx.x * 256 + threadIdx.x;
  if (i >= NNZC) return;
  int n = node_idx[i], m = edge_idx[i];
  float a = s_node[n] + s_edge[m];
  a = (a >= 0.f) ? a : 0.2f * a;
  a_buf[i] = a;
  atomicMaxF(&amax[n], a);
  atomicAdd(&DnCnt[n], 1);
  atomicAdd(&BnCnt[m], 1);
}

// ---------------- single-block exclusive scan ----------------
__global__ __launch_bounds__(1024) void exscan_kernel(const int* __restrict__ in,
                                                      int* __restrict__ out, int n) {
  __shared__ int sums[1024];
  const int t = threadIdx.x;
  const int chunk = (n + 1023) >> 10;
  const int start = t * chunk;
  const int stop  = min(start + chunk, n);
  int local = 0;
  for (int i = start; i < stop; ++i) local += in[i];
  sums[t] = local;
  __syncthreads();
  for (int o = 1; o < 1024; o <<= 1) {
    int v = (t >= o) ? sums[t - o] : 0;
    __syncthreads();
    sums[t] += v;
    __syncthreads();
  }
  int run = (t == 0) ? 0 : sums[t - 1];
  for (int i = start; i < stop; ++i) { out[i] = run; run += in[i]; }
  if (t == 1023) out[n] = sums[1023];
}

// ---------------- incidence pass 2 ----------------
__global__ void incidence_pass2(const int* __restrict__ node_idx, const int* __restrict__ edge_idx,
    float* __restrict__ a_buf, const float* __restrict__ amax, float* den,
    const int* __restrict__ node_off, const int* __restrict__ edge_off,
    int* node_cur, int* edge_cur, int* node_list, int* edge_list) {
  int i = blockIdx.x * 256 + threadIdx.x;
  if (i >= NNZC) return;
  int n = node_idx[i], m = edge_idx[i];
  float e = __expf(a_buf[i] - amax[n]);
  a_buf[i] = e;
  atomicAdd(&den[n], e);
  int pn = atomicAdd(&node_cur[n], 1);
  node_list[node_off[n] + pn] = i;
  int pm = atomicAdd(&edge_cur[m], 1);
  edge_list[edge_off[m] + pm] = i;
}

// ---------------- edge gather ----------------
__global__ __launch_bounds__(256) void gather_edge(const int* __restrict__ edge_off,
    const int* __restrict__ edge_list, const int* __restrict__ node_idx,
    const float* __restrict__ a_buf, const float* __restrict__ den,
    const float* __restrict__ xl, float* __restrict__ ef) {
  int m = blockIdx.x;
  int t = threadIdx.x;
  int beg = edge_off[m], end = edge_off[m+1];
  int cnt = end - beg;
  float Binv = (cnt > 0) ? (1.0f / (float)cnt) : 0.f;
  __shared__ int   ln_[128];
  __shared__ float lw_[128];
  float acc0 = 0.f, acc1 = 0.f;
  for (int c = beg; c < end; c += 128) {
    int nchunk = min(128, end - c);
    if (t < nchunk) {
      int i = edge_list[c + t];
      int n = node_idx[i];
      ln_[t] = n;
      lw_[t] = a_buf[i] / (den[n] + 1e-16f) * Binv;
    }
    __syncthreads();
    for (int j = 0; j < nchunk; ++j) {
      const float w = lw_[j];
      const float* xr = &xl[(size_t)ln_[j] * DD];
      acc0 += w * xr[t];
      acc1 += w * xr[t + 256];
    }
    __syncthreads();
  }
  ef[(size_t)m * DD + t]       = acc0;
  ef[(size_t)m * DD + t + 256] = acc1;
}

// ---------------- node gather ----------------
__global__ __launch_bounds__(256) void gather_node(const int* __restrict__ node_off,
    const int* __restrict__ node_list, const int* __restrict__ edge_idx,
    const float* __restrict__ a_buf, const float* __restrict__ den,
    const float* __restrict__ ef, const float* __restrict__ bias_h, float* __restrict__ conv) {
  int n = blockIdx.x;
  int t = threadIdx.x;
  int beg = node_off[n], end = node_off[n+1];
  int cnt = end - beg;
  float Dinv = (cnt > 0) ? (1.0f / (float)cnt) : 0.f;
  float wscale = Dinv / (den[n] + 1e-16f);
  __shared__ int   le_[128];
  __shared__ float lw_[128];
  float acc0 = 0.f, acc1 = 0.f;
  for (int c = beg; c < end; c += 128) {
    int nchunk = min(128, end - c);
    if (t < nchunk) {
      int i = node_list[c + t];
      le_[t] = edge_idx[i];
      lw_[t] = a_buf[i] * wscale;
    }
    __syncthreads();
    for (int j = 0; j < nchunk; ++j) {
      const float w = lw_[j];
      const float* er = &ef[(size_t)le_[j] * DD];
      acc0 += w * er[t];
      acc1 += w * er[t + 256];
    }
    __syncthreads();
  }
  conv[(size_t)n * DD + t]       = acc0 + bias_h[t];
  conv[(size_t)n * DD + t + 256] = acc1 + bias_h[t + 256];
}

// ---------------- LayerNorm(a + b), optional bf16 copy ----------------
__global__ __launch_bounds__(256) void ln_residual(const float* __restrict__ a,
    const float* __restrict__ b, const float* __restrict__ g, const float* __restrict__ be,
    float* __restrict__ out, unsigned short* __restrict__ outb) {
  int r = blockIdx.x;
  int t = threadIdx.x;
  float v0 = a[(size_t)r*DD + t]       + b[(size_t)r*DD + t];
  float v1 = a[(size_t)r*DD + t + 256] + b[(size_t)r*DD + t + 256];
  __shared__ float red[4];
  __shared__ float mu_s, rstd_s;
  float s = v0 + v1;
  #pragma unroll
  for (int off = 1; off < 64; off <<= 1) s += __shfl_xor(s, off, 64);
  int wid = t >> 6;
  if ((t & 63) == 0) red[wid] = s;
  __syncthreads();
  if (t == 0) mu_s = (red[0] + red[1] + red[2] + red[3]) / 512.f;
  __syncthreads();
  float mu = mu_s;
  float d0 = v0 - mu, d1 = v1 - mu;
  float vs = d0*d0 + d1*d1;
  #pragma unroll
  for (int off = 1; off < 64; off <<= 1) vs += __shfl_xor(vs, off, 64);
  if ((t & 63) == 0) red[wid] = vs;
  __syncthreads();
  if (t == 0) rstd_s = rsqrtf((red[0] + red[1] + red[2] + red[3]) / 512.f + 1e-5f);
  __syncthreads();
  float rs = rstd_s;
  float o0 = d0 * rs * g[t]       + be[t];
  float o1 = d1 * rs * g[t + 256] + be[t + 256];
  out[(size_t)r*DD + t]       = o0;
  out[(size_t)r*DD + t + 256] = o1;
  if (outb) {
    outb[(size_t)r*DD + t]       = f2bf(o0);
    outb[(size_t)r*DD + t + 256] = f2bf(o1);
  }
}

// ---------------- K-plane fp32 -> bf16 : Kb[h][tok][64] ----------------
__global__ __launch_bounds__(256) void conv_k(const float* __restrict__ qkv,
                                              unsigned short* __restrict__ Kb) {
  int idx = blockIdx.x * 256 + threadIdx.x;
  int e = idx * 4;
  int tok = e >> 9;
  int hd = e & 511;
  float4 v = *(const float4*)&qkv[(size_t)tok*1536 + 512 + hd];
  int h = hd >> 6, d = hd & 63;
  ushort4 w4;
  w4.x = f2bf(v.x); w4.y = f2bf(v.y); w4.z = f2bf(v.z); w4.w = f2bf(v.w);
  *(ushort4*)&Kb[(size_t)h*NN*64 + (size_t)tok*64 + d] = w4;
}

// ---------------- V-plane fp32 -> bf16 transposed : Vtb[h][d][tok] ----------------
__global__ __launch_bounds__(256) void conv_vt(const float* __restrict__ qkv,
                                               unsigned short* __restrict__ Vtb) {
  __shared__ unsigned short Tl[64][76];
  const int h = blockIdx.y;
  const int tt = blockIdx.x * 64;
  const int t = threadIdx.x;
  {
    int row = t >> 2;
    int cbase = (t & 3) * 16;
    const float* src = &qkv[(size_t)(tt + row)*1536 + 1024 + h*64 + cbase];
    #pragma unroll
    for (int jj = 0; jj < 4; ++jj) {
      float4 v = *(const float4*)&src[jj*4];
      ushort4 w4;
      w4.x = f2bf(v.x); w4.y = f2bf(v.y); w4.z = f2bf(v.z); w4.w = f2bf(v.w);
      *(ushort4*)&Tl[row][cbase + jj*4] = w4;
    }
  }
  __syncthreads();
  #pragma unroll
  for (int it = 0; it < 4; ++it) {
    int d = it*16 + (t >> 4);
    int tk = (t & 15) * 4;
    ushort4 w4;
    w4.x = Tl[tk+0][d]; w4.y = Tl[tk+1][d]; w4.z = Tl[tk+2][d]; w4.w = Tl[tk+3][d];
    *(ushort4*)&Vtb[(size_t)h*64*NN + (size_t)d*NN + tt + tk] = w4;
  }
}

// ---------------- MFMA flash attention partial (split-K): 64 q-rows/block, 4 waves ----------------
// base-2 softmax; defer-max (THR=8); fp32 P in LDS + cvt_pk on read; async K/V prefetch.
__global__ __launch_bounds__(256) void attn_mfma_part(const unsigned short* __restrict__ Kb,
                                                      const unsigned short* __restrict__ Vtb,
                                                      const float* __restrict__ qkv,
                                                      float* __restrict__ Opart,
                                                      float* __restrict__ ml) {
  const int head = blockIdx.y;
  const int z = blockIdx.z;
  const int q0 = blockIdx.x * 64;
  const int t = threadIdx.x;
  const int w = t >> 6;
  const int l = t & 63;
  const int lg = l >> 4;
  const int lid = l & 15;

  __shared__ __align__(16) unsigned short Kl[64*64];
  __shared__ __align__(16) unsigned short Vl[64*64];
  __shared__ __align__(16) float Pf[4][16*68];   // fp32 P, stride 68 floats

  union { bf16x8 v; unsigned short u[8]; } qa[2];
  {
    const int qrow = q0 + w*16 + lid;
    const float* qp = &qkv[(size_t)qrow*1536 + head*64];
    const float qs = 0.125f * 1.44269504f;   // 1/sqrt(64) * log2(e)
    #pragma unroll
    for (int hf = 0; hf < 2; ++hf)
      #pragma unroll
      for (int j = 0; j < 8; ++j)
        qa[hf].u[j] = f2bf(qp[hf*32 + lg*8 + j] * qs);
  }

  float m[4], lsum[4];
  f32x4 o[4];
  #pragma unroll
  for (int r = 0; r < 4; ++r) { m[r] = -1e30f; lsum[r] = 0.f; }
  #pragma unroll
  for (int dt = 0; dt < 4; ++dt) o[dt] = (f32x4)0.f;

  const unsigned short* Kh = Kb  + (size_t)head*NN*64;
  const unsigned short* Vh = Vtb + (size_t)head*64*NN;
  float* pwf = Pf[w];
  const int kt0 = z * (NN / NSPLIT);
  const int kt1 = kt0 + (NN / NSPLIT);

  // staging geometry (2 chunks of 16B per thread for K and V each)
  const int srow0 = t >> 3,        scc0 = (t & 7) * 8;
  const int sdst0 = (srow0*64 + scc0) ^ ((srow0 & 7) << 3);
  const int srow1 = (256 + t) >> 3, scc1 = (t & 7) * 8;
  const int sdst1 = (srow1*64 + scc1) ^ ((srow1 & 7) << 3);
  ulonglong2 kreg0, kreg1, vreg0, vreg1;

#define LOADKV(ktv) do { \
    kreg0 = *(const ulonglong2*)&Kh[(size_t)((ktv) + srow0)*64 + scc0]; \
    vreg0 = *(const ulonglong2*)&Vh[(size_t)srow0*NN + (ktv) + scc0]; \
    kreg1 = *(const ulonglong2*)&Kh[(size_t)((ktv) + srow1)*64 + scc1]; \
    vreg1 = *(const ulonglong2*)&Vh[(size_t)srow1*NN + (ktv) + scc1]; \
  } while (0)
#define STORKV() do { \
    *(ulonglong2*)&Kl[sdst0] = kreg0; *(ulonglong2*)&Vl[sdst0] = vreg0; \
    *(ulonglong2*)&Kl[sdst1] = kreg1; *(ulonglong2*)&Vl[sdst1] = vreg1; \
  } while (0)

  LOADKV(kt0);
  STORKV();
  __syncthreads();

  for (int kt = kt0; kt < kt1; kt += 64) {
    const bool hn = (kt + 64) < kt1;
    if (hn) LOADKV(kt + 64);   // issue early; lands during compute (T14)

    // ---- S = Q K^T ----
    f32x4 s[4];
    #pragma unroll
    for (int n = 0; n < 4; ++n) s[n] = (f32x4)0.f;
    __builtin_amdgcn_s_setprio(1);
    #pragma unroll
    for (int n = 0; n < 4; ++n) {
      int tok = n*16 + lid;
      #pragma unroll
      for (int hf = 0; hf < 2; ++hf) {
        int didx = (tok*64 + hf*32 + lg*8) ^ ((tok & 7) << 3);
        bf16x8 kb = *(const bf16x8*)&Kl[didx];
        s[n] = __builtin_amdgcn_mfma_f32_16x16x32_bf16(qa[hf].v, kb, s[n], 0, 0, 0);
      }
    }
    __builtin_amdgcn_s_setprio(0);

    // ---- online softmax with defer-max (base-2) ----
    float mx[4];
    #pragma unroll
    for (int r = 0; r < 4; ++r) {
      float m0 = fmaxf(fmaxf(s[0][r], s[1][r]), fmaxf(s[2][r], s[3][r]));
      m0 = fmaxf(m0, __shfl_xor(m0, 1, 64));
      m0 = fmaxf(m0, __shfl_xor(m0, 2, 64));
      m0 = fmaxf(m0, __shfl_xor(m0, 4, 64));
      m0 = fmaxf(m0, __shfl_xor(m0, 8, 64));
      mx[r] = m0;
    }
    int ok = (mx[0] <= m[0] + 8.f) & (mx[1] <= m[1] + 8.f) &
             (mx[2] <= m[2] + 8.f) & (mx[3] <= m[3] + 8.f);
    if (!__all(ok)) {
      #pragma unroll
      for (int r = 0; r < 4; ++r) {
        float mn = fmaxf(m[r], mx[r]);
        float c = exp2f(m[r] - mn);
        m[r] = mn;
        lsum[r] *= c;
        #pragma unroll
        for (int dt = 0; dt < 4; ++dt) o[dt][r] *= c;
      }
    }
    #pragma unroll
    for (int r = 0; r < 4; ++r) {
      float ps = 0.f;
      #pragma unroll
      for (int n = 0; n < 4; ++n) {
        float p = exp2f(s[n][r] - m[r]);
        s[n][r] = p;
        ps += p;
      }
      ps += __shfl_xor(ps, 1, 64); ps += __shfl_xor(ps, 2, 64);
      ps += __shfl_xor(ps, 4, 64); ps += __shfl_xor(ps, 8, 64);
      lsum[r] += ps;
    }

    // ---- P -> LDS (fp32), read back as A-frag, hw cvt_pk to bf16 ----
    #pragma unroll
    for (int n = 0; n < 4; ++n)
      #pragma unroll
      for (int r = 0; r < 4; ++r)
        pwf[(lg*4 + r)*68 + n*16 + lid] = s[n][r];

    union { bf16x8 v; unsigned int u[4]; } pa[2];
    #pragma unroll
    for (int hf = 0; hf < 2; ++hf) {
      float4 a0 = *(const float4*)&pwf[lid*68 + hf*32 + lg*8];
      float4 a1 = *(const float4*)&pwf[lid*68 + hf*32 + lg*8 + 4];
      asm("v_cvt_pk_bf16_f32 %0, %1, %2" : "=v"(pa[hf].u[0]) : "v"(a0.x), "v"(a0.y));
      asm("v_cvt_pk_bf16_f32 %0, %1, %2" : "=v"(pa[hf].u[1]) : "v"(a0.z), "v"(a0.w));
      asm("v_cvt_pk_bf16_f32 %0, %1, %2" : "=v"(pa[hf].u[2]) : "v"(a1.x), "v"(a1.y));
      asm("v_cvt_pk_bf16_f32 %0, %1, %2" : "=v"(pa[hf].u[3]) : "v"(a1.z), "v"(a1.w));
    }

    // ---- O += P V ----
    __builtin_amdgcn_s_setprio(1);
    #pragma unroll
    for (int dt = 0; dt < 4; ++dt) {
      int drow = dt*16 + lid;
      #pragma unroll
      for (int hf = 0; hf < 2; ++hf) {
        int didx = (drow*64 + hf*32 + lg*8) ^ ((drow & 7) << 3);
        bf16x8 vb = *(const bf16x8*)&Vl[didx];
        o[dt] = __builtin_amdgcn_mfma_f32_16x16x32_bf16(pa[hf].v, vb, o[dt], 0, 0, 0);
      }
    }
    __builtin_amdgcn_s_setprio(0);

    __syncthreads();           // all waves done reading Kl/Vl
    if (hn) {
      STORKV();                // write prefetched tile
      __syncthreads();
    }
  }
#undef LOADKV
#undef STORKV

  // ---- epilogue: unnormalized partial O + (m, l) ----
  #pragma unroll
  for (int r = 0; r < 4; ++r) {
    int q = q0 + w*16 + lg*4 + r;
    size_t base = ((size_t)(z*HH + head)*NN + q)*64;
    #pragma unroll
    for (int dt = 0; dt < 4; ++dt)
      Opart[base + dt*16 + lid] = o[dt][r];
    if (lid == 0) {
      size_t mb = ((size_t)(z*HH + head)*NN + q)*2;
      ml[mb]     = m[r];
      ml[mb + 1] = lsum[r];
    }
  }
}

// ---------------- combine split-K partials -> ctx bf16 ----------------
__global__ __launch_bounds__(256) void attn_combine(const float* __restrict__ Opart,
                                                    const float* __restrict__ ml,
                                                    unsigned short* __restrict__ ctxb) {
  const int w = threadIdx.x >> 6, lane = threadIdx.x & 63;
  const int row = blockIdx.x * 4 + w;     // 0 .. NN*HH-1
  const int q = row >> 3, head = row & 7;
  float ms[NSPLIT], ls[NSPLIT];
  float mglob = -1e30f;
  #pragma unroll
  for (int s = 0; s < NSPLIT; ++s) {
    size_t mb = ((size_t)(s*HH + head)*NN + q)*2;
    ms[s] = ml[mb]; ls[s] = ml[mb + 1];
    mglob = fmaxf(mglob, ms[s]);
  }
  float lt = 0.f, ov = 0.f;
  #pragma unroll
  for (int s = 0; s < NSPLIT; ++s) {
    float wgt = exp2f(ms[s] - mglob);
    lt += ls[s] * wgt;
    ov += Opart[((size_t)(s*HH + head)*NN + q)*64 + lane] * wgt;
  }
  ctxb[(size_t)q*DD + head*64 + lane] = f2bf(ov / lt);
}

// ---------------- host ----------------
extern "C" void kernel_launch(void* const* d_in, const int* in_sizes, int n_in,
                              void* d_out, int out_size, void* d_ws, size_t ws_size,
                              hipStream_t stream) {
  const float* x       = (const float*)d_in[0];
  const int*   hidx    = (const int*)d_in[1];
  const float* hattr   = (const float*)d_in[2];
  const float* Wh      = (const float*)d_in[3];
  const float* att     = (const float*)d_in[4];
  const float* bias_h  = (const float*)d_in[5];
  const float* ln1_g   = (const float*)d_in[6];
  const float* ln1_b   = (const float*)d_in[7];
  const float* ln2_g   = (const float*)d_in[8];
  const float* ln2_b   = (const float*)d_in[9];
  const float* in_proj_w  = (const float*)d_in[10];
  const float* in_proj_b  = (const float*)d_in[11];
  const float* out_proj_w = (const float*)d_in[12];
  const float* out_proj_b = (const float*)d_in[13];
  const float* ff1_w   = (const float*)d_in[14];
  const float* ff1_b   = (const float*)d_in[15];
  const float* ff2_w   = (const float*)d_in[16];
  const float* ff2_b   = (const float*)d_in[17];
  const float* tln1_g  = (const float*)d_in[18];
  const float* tln1_b  = (const float*)d_in[19];
  const float* tln2_g  = (const float*)d_in[20];
  const float* tln2_b  = (const float*)d_in[21];
  const int* node_idx = hidx;
  const int* edge_idx = hidx + NNZC;

  char* ws = (char*)d_ws;
  size_t off = 0;
  auto alloc = [&](size_t bytes) -> void* {
    void* p = ws + off;
    off = (off + bytes + 63) & ~(size_t)63;
    return p;
  };
  float* xl       = (float*)alloc(sizeof(float)*NN*DD);
  float* el       = (float*)alloc(sizeof(float)*MM*DD);
  float* s_node   = (float*)alloc(sizeof(float)*NN);
  float* s_edge   = (float*)alloc(sizeof(float)*MM);
  float* a_buf    = (float*)alloc(sizeof(float)*NNZC);
  float* amax     = (float*)alloc(sizeof(float)*NN);
  float* den      = (float*)alloc(sizeof(float)*NN);
  int*   DnCnt    = (int*)alloc(sizeof(int)*NN);
  int*   BnCnt    = (int*)alloc(sizeof(int)*MM);
  int*   node_off = (int*)alloc(sizeof(int)*(NN+1));
  int*   edge_off = (int*)alloc(sizeof(int)*(MM+1));
  int*   node_cur = (int*)alloc(sizeof(int)*NN);
  int*   edge_cur = (int*)alloc(sizeof(int)*MM);
  int*   node_list= (int*)alloc(sizeof(int)*NNZC);
  int*   edge_list= (int*)alloc(sizeof(int)*NNZC);
  float* ef       = (float*)alloc(sizeof(float)*MM*DD);
  float* conv     = (float*)alloc(sizeof(float)*NN*DD);
  float* x1       = (float*)alloc(sizeof(float)*NN*DD);
  float* qkvb     = (float*)alloc(sizeof(float)*NN*3*DD);
  float* attn_out = (float*)alloc(sizeof(float)*NN*DD);
  float* x2       = (float*)alloc(sizeof(float)*NN*DD);
  unsigned short* Kb    = (unsigned short*)alloc(sizeof(unsigned short)*NN*DD);
  unsigned short* Vtb   = (unsigned short*)alloc(sizeof(unsigned short)*NN*DD);
  unsigned short* xb    = (unsigned short*)alloc(sizeof(unsigned short)*NN*DD);
  unsigned short* hattrb= (unsigned short*)alloc(sizeof(unsigned short)*MM*DD);
  unsigned short* Whb   = (unsigned short*)alloc(sizeof(unsigned short)*DD*DD);
  unsigned short* ipwb  = (unsigned short*)alloc(sizeof(unsigned short)*3*DD*DD);
  unsigned short* opwb  = (unsigned short*)alloc(sizeof(unsigned short)*DD*DD);
  unsigned short* ff1wb = (unsigned short*)alloc(sizeof(unsigned short)*DFFC*DD);
  unsigned short* ff2wb = (unsigned short*)alloc(sizeof(unsigned short)*DD*DFFC);
  unsigned short* x1b   = (unsigned short*)alloc(sizeof(unsigned short)*NN*DD);
  unsigned short* x2b   = (unsigned short*)alloc(sizeof(unsigned short)*NN*DD);
  unsigned short* ctxb  = (unsigned short*)alloc(sizeof(unsigned short)*NN*DD);
  // "late" region: attention partials alias FFN-phase buffers (dead before ff1).
  char* late = (char*)alloc(33u*1024*1024);
  float*          Opart = (float*)late;                                  // 32 MB (attn phase)
  float*          mlb   = (float*)(late + 32u*1024*1024);                // 1 MB (attn phase)
  unsigned short* ffhb  = (unsigned short*)late;                         // 16 MB (FFN phase)
  float*          ffo   = (float*)(late + 16u*1024*1024);                // 8 MB (FFN phase)
  float*          x3    = (float*)(late + 24u*1024*1024);                // 8 MB (FFN phase)
  (void)ws_size; (void)in_sizes; (void)n_in; (void)out_size;

  dim3 b256(256);
  auto f2bL = [&](const float* src, unsigned short* dst, int n) {
    f2b_kernel<<<(n/8 + 255)/256, b256, 0, stream>>>(src, dst, n/8);
  };
  // one-time bf16 conversions
  f2bL(x, xb, NN*DD);
  f2bL(hattr, hattrb, MM*DD);
  f2bL(Wh, Whb, DD*DD);
  f2bL(in_proj_w, ipwb, 3*DD*DD);
  f2bL(out_proj_w, opwb, DD*DD);
  f2bL(ff1_w, ff1wb, DFFC*DD);
  f2bL(ff2_w, ff2wb, DD*DFFC);

  // xl = x @ Wh^T ; el = hattr @ Wh^T  (bf16 MFMA, fp32 out)
  gemm_bt_bf16<<<dim3(NN/128, DD/128), b256, 0, stream>>>(xb, Whb, nullptr, xl, nullptr, DD, DD, 0);
  gemm_bt_bf16<<<dim3(MM/128, DD/128), b256, 0, stream>>>(hattrb, Whb, nullptr, el, nullptr, DD, DD, 0);
  // sparse hypergraph conv
  rowdot<<<NN/4, b256, 0, stream>>>(xl, att,      s_node, NN);
  rowdot<<<MM/4, b256, 0, stream>>>(el, att + DD, s_edge, MM);
  init_kernel<<<NN/256, b256, 0, stream>>>(amax, den, DnCnt, BnCnt, node_cur, edge_cur);
  incidence_pass1<<<NNZC/256, b256, 0, stream>>>(node_idx, edge_idx, s_node, s_edge,
                                                 a_buf, amax, DnCnt, BnCnt);
  exscan_kernel<<<1, 1024, 0, stream>>>(DnCnt, node_off, NN);
  exscan_kernel<<<1, 1024, 0, stream>>>(BnCnt, edge_off, MM);
  incidence_pass2<<<NNZC/256, b256, 0, stream>>>(node_idx, edge_idx, a_buf, amax, den,
                                                 node_off, edge_off, node_cur, edge_cur,
                                                 node_list, edge_list);
  gather_edge<<<MM, b256, 0, stream>>>(edge_off, edge_list, node_idx, a_buf, den, xl, ef);
  gather_node<<<NN, b256, 0, stream>>>(node_off, node_list, edge_idx, a_buf, den, ef, bias_h, conv);
  // x1 = LN(x + conv) (+ bf16 copy)
  ln_residual<<<NN, b256, 0, stream>>>(x, conv, ln1_g, ln1_b, x1, x1b);
  // qkv
  gemm_bt_bf16<<<dim3(NN/128, (3*DD)/128), b256, 0, stream>>>(x1b, ipwb, in_proj_b, qkvb, nullptr, 3*DD, DD, 0);
  // attention (bf16 MFMA, split-K x4 + combine)
  conv_k <<<NN*DD/(256*4), b256, 0, stream>>>(qkvb, Kb);
  conv_vt<<<dim3(NN/64, HH), b256, 0, stream>>>(qkvb, Vtb);
  attn_mfma_part<<<dim3(NN/64, HH, NSPLIT), b256, 0, stream>>>(Kb, Vtb, qkvb, Opart, mlb);
  attn_combine<<<NN*HH/4, b256, 0, stream>>>(Opart, mlb, ctxb);
  // out_proj
  gemm_bt_bf16<<<dim3(NN/128, DD/128), b256, 0, stream>>>(ctxb, opwb, out_proj_b, attn_out, nullptr, DD, DD, 0);
  // x2 = LN(x1 + attn_out) (+ bf16)
  ln_residual<<<NN, b256, 0, stream>>>(x1, attn_out, tln1_g, tln1_b, x2, x2b);
  // ffn: ff1 (bf16 out w/ relu), ff2 (fp32 out)
  gemm_bt_bf16<<<dim3(NN/128, DFFC/128), b256, 0, stream>>>(x2b, ff1wb, ff1_b, nullptr, ffhb, DFFC, DD, 1);
  gemm_bt_bf16<<<dim3(NN/128, DD/128),   b256, 0, stream>>>(ffhb, ff2wb, ff2_b, ffo, nullptr, DD, DFFC, 0);
  // x3 = LN(x2 + ff)
  ln_residual<<<NN, b256, 0, stream>>>(x2, ffo, tln2_g, tln2_b, x3, nullptr);
  // out = LN(x1 + x3)
  ln_residual<<<NN, b256, 0, stream>>>(x1, x3, ln2_g, ln2_b, (float*)d_out, nullptr);
}

// Round 8
// 330.169 us; speedup vs baseline: 6.0037x; 1.1248x over previous
//
#include <hip/hip_runtime.h>
#include <math.h>

#define NN   4096
#define MM   1024
#define NNZC 65536
#define DD   512
#define HH   8
#define DHH  64
#define DFFC 2048
#define NSPLIT 4

typedef short bf16x8 __attribute__((ext_vector_type(8)));
typedef float f32x4  __attribute__((ext_vector_type(4)));

static __device__ inline unsigned short f2bf(float f) {
  union { float f; unsigned int u; } v; v.f = f;
  unsigned int r = v.u + 0x7fff + ((v.u >> 16) & 1);   // RNE
  return (unsigned short)(r >> 16);
}

__device__ inline void gload16(const void* g, void* l) {
  __builtin_amdgcn_global_load_lds(
      (const __attribute__((address_space(1))) void*)g,
      (__attribute__((address_space(3))) void*)l, 16, 0, 0);
}

// ---------------- utility ----------------
__device__ inline void atomicMaxF(float* addr, float val) {
  if (val >= 0.f) atomicMax((int*)addr, __float_as_int(val));
  else            atomicMin((unsigned int*)addr, __float_as_uint(val));
}

// ---------------- init ----------------
__global__ void init_kernel(float* amax, float* den, int* DnCnt, int* BnCnt,
                            int* node_cur, int* edge_cur) {
  int i = blockIdx.x * 256 + threadIdx.x;
  if (i < NN) { amax[i] = -INFINITY; den[i] = 0.f; DnCnt[i] = 0; node_cur[i] = 0; }
  if (i < MM) { BnCnt[i] = 0; edge_cur[i] = 0; }
}

// ---------------- fp32 -> bf16 bulk convert (8 elems/thread) ----------------
__global__ __launch_bounds__(256) void f2b_kernel(const float* __restrict__ in,
    unsigned short* __restrict__ out, int n8) {
  int i = blockIdx.x * 256 + threadIdx.x;
  if (i >= n8) return;
  float4 v0 = *(const float4*)&in[(size_t)i*8];
  float4 v1 = *(const float4*)&in[(size_t)i*8 + 4];
  unsigned short w[8];
  w[0]=f2bf(v0.x); w[1]=f2bf(v0.y); w[2]=f2bf(v0.z); w[3]=f2bf(v0.w);
  w[4]=f2bf(v1.x); w[5]=f2bf(v1.y); w[6]=f2bf(v1.z); w[7]=f2bf(v1.w);
  *(ulonglong2*)&out[(size_t)i*8] = *(ulonglong2*)w;
}

// ---------------- bf16 MFMA NT GEMM: C[M,N] = A[M,K] @ B[N,K]^T (+bias,+relu) ----------------
__global__ __launch_bounds__(256) void gemm_bt_bf16(
    const unsigned short* __restrict__ A, const unsigned short* __restrict__ B,
    const float* __restrict__ bias, float* __restrict__ Cf,
    unsigned short* __restrict__ Cb, int N, int K, int relu) {
  __shared__ __align__(16) unsigned short Al[128*64];
  __shared__ __align__(16) unsigned short Bl[128*64];
  const int t = threadIdx.x;
  const int w = t >> 6, l = t & 63;
  const int lg = l >> 4, lid = l & 15;
  const int wr = w >> 1, wc = w & 1;
  const int bm = blockIdx.x * 128, bn = blockIdx.y * 128;

  f32x4 acc[4][4];
  #pragma unroll
  for (int mi = 0; mi < 4; ++mi)
    #pragma unroll
    for (int ni = 0; ni < 4; ++ni) acc[mi][ni] = (f32x4)0.f;

  for (int k0 = 0; k0 < K; k0 += 64) {
    #pragma unroll
    for (int i = 0; i < 4; ++i) {
      int cid = i*256 + t;
      int row = cid >> 3, cp = cid & 7;
      int gc = cp ^ (row & 7);
      gload16(&A[(size_t)(bm + row)*K + k0 + gc*8], &Al[cid*8]);
      gload16(&B[(size_t)(bn + row)*K + k0 + gc*8], &Bl[cid*8]);
    }
    asm volatile("s_waitcnt vmcnt(0)" ::: "memory");
    __syncthreads();
    #pragma unroll
    for (int ks = 0; ks < 2; ++ks) {
      bf16x8 af[4], bfr[4];
      #pragma unroll
      for (int mi = 0; mi < 4; ++mi) {
        int r = wr*64 + mi*16 + lid;
        af[mi] = *(const bf16x8*)&Al[r*64 + ((ks*4 + lg) ^ (r & 7))*8];
      }
      #pragma unroll
      for (int ni = 0; ni < 4; ++ni) {
        int r = wc*64 + ni*16 + lid;
        bfr[ni] = *(const bf16x8*)&Bl[r*64 + ((ks*4 + lg) ^ (r & 7))*8];
      }
      __builtin_amdgcn_s_setprio(1);
      #pragma unroll
      for (int mi = 0; mi < 4; ++mi)
        #pragma unroll
        for (int ni = 0; ni < 4; ++ni)
          acc[mi][ni] = __builtin_amdgcn_mfma_f32_16x16x32_bf16(af[mi], bfr[ni], acc[mi][ni], 0, 0, 0);
      __builtin_amdgcn_s_setprio(0);
    }
    __syncthreads();
  }

  #pragma unroll
  for (int ni = 0; ni < 4; ++ni) {
    int col = bn + wc*64 + ni*16 + lid;
    float bv = bias ? bias[col] : 0.f;
    #pragma unroll
    for (int mi = 0; mi < 4; ++mi) {
      #pragma unroll
      for (int rg = 0; rg < 4; ++rg) {
        int row = bm + wr*64 + mi*16 + lg*4 + rg;
        float v = acc[mi][ni][rg] + bv;
        if (relu) v = fmaxf(v, 0.f);
        if (Cf) Cf[(size_t)row*N + col] = v;
        if (Cb) Cb[(size_t)row*N + col] = f2bf(v);
      }
    }
  }
}

// ---------------- per-row dot ----------------
__global__ __launch_bounds__(256) void rowdot(const float* __restrict__ X,
    const float* __restrict__ vec, float* __restrict__ out, int rows) {
  int w = (blockIdx.x * 256 + threadIdx.x) >> 6;
  int lane = threadIdx.x & 63;
  if (w >= rows) return;
  const float* xr = &X[(size_t)w * DD];
  float s = 0.f;
  #pragma unroll
  for (int j = 0; j < 8; ++j) s += xr[lane + 64*j] * vec[lane + 64*j];
  #pragma unroll
  for (int off = 1; off < 64; off <<= 1) s += __shfl_xor(s, off, 64);
  if (lane == 0) out[w] = s;
}

// ---------------- incidence pass 1 ----------------
__global__ void incidence_pass1(const int* __restrict__ node_idx, const int* __restrict__ edge_idx,
    const float* __restrict__ s_node, const float* __restrict__ s_edge,
    float* __restrict__ a_buf, float* amax, int* DnCnt, int* BnCnt) {
  int i = blockIdx.x * 256 + threadIdx.x;
  if (i >= NNZC) return;
  int n = node_idx[i], m = edge_idx[i];
  float a = s_node[n] + s_edge[m];
  a = (a >= 0.f) ? a : 0.2f * a;
  a_buf[i] = a;
  atomicMaxF(&amax[n], a);
  atomicAdd(&DnCnt[n], 1);
  atomicAdd(&BnCnt[m], 1);
}

// ---------------- single-block exclusive scan ----------------
__global__ __launch_bounds__(1024) void exscan_kernel(const int* __restrict__ in,
                                                      int* __restrict__ out, int n) {
  __shared__ int sums[1024];
  const int t = threadIdx.x;
  const int chunk = (n + 1023) >> 10;
  const int start = t * chunk;
  const int stop  = min(start + chunk, n);
  int local = 0;
  for (int i = start; i < stop; ++i) local += in[i];
  sums[t] = local;
  __syncthreads();
  for (int o = 1; o < 1024; o <<= 1) {
    int v = (t >= o) ? sums[t - o] : 0;
    __syncthreads();
    sums[t] += v;
    __syncthreads();
  }
  int run = (t == 0) ? 0 : sums[t - 1];
  for (int i = start; i < stop; ++i) { out[i] = run; run += in[i]; }
  if (t == 1023) out[n] = sums[1023];
}

// ---------------- incidence pass 2 ----------------
__global__ void incidence_pass2(const int* __restrict__ node_idx, const int* __restrict__ edge_idx,
    float* __restrict__ a_buf, const float* __restrict__ amax, float* den,
    const int* __restrict__ node_off, const int* __restrict__ edge_off,
    int* node_cur, int* edge_cur, int* node_list, int* edge_list) {
  int i = blockIdx.x * 256 + threadIdx.x;
  if (i >= NNZC) return;
  int n = node_idx[i], m = edge_idx[i];
  float e = __expf(a_buf[i] - amax[n]);
  a_buf[i] = e;
  atomicAdd(&den[n], e);
  int pn = atomicAdd(&node_cur[n], 1);
  node_list[node_off[n] + pn] = i;
  int pm = atomicAdd(&edge_cur[m], 1);
  edge_list[edge_off[m] + pm] = i;
}

// ---------------- edge gather ----------------
__global__ __launch_bounds__(256) void gather_edge(const int* __restrict__ edge_off,
    const int* __restrict__ edge_list, const int* __restrict__ node_idx,
    const float* __restrict__ a_buf, const float* __restrict__ den,
    const float* __restrict__ xl, float* __restrict__ ef) {
  int m = blockIdx.x;
  int t = threadIdx.x;
  int beg = edge_off[m], end = edge_off[m+1];
  int cnt = end - beg;
  float Binv = (cnt > 0) ? (1.0f / (float)cnt) : 0.f;
  __shared__ int   ln_[128];
  __shared__ float lw_[128];
  float acc0 = 0.f, acc1 = 0.f;
  for (int c = beg; c < end; c += 128) {
    int nchunk = min(128, end - c);
    if (t < nchunk) {
      int i = edge_list[c + t];
      int n = node_idx[i];
      ln_[t] = n;
      lw_[t] = a_buf[i] / (den[n] + 1e-16f) * Binv;
    }
    __syncthreads();
    for (int j = 0; j < nchunk; ++j) {
      const float w = lw_[j];
      const float* xr = &xl[(size_t)ln_[j] * DD];
      acc0 += w * xr[t];
      acc1 += w * xr[t + 256];
    }
    __syncthreads();
  }
  ef[(size_t)m * DD + t]       = acc0;
  ef[(size_t)m * DD + t + 256] = acc1;
}

// ---------------- node gather ----------------
__global__ __launch_bounds__(256) void gather_node(const int* __restrict__ node_off,
    const int* __restrict__ node_list, const int* __restrict__ edge_idx,
    const float* __restrict__ a_buf, const float* __restrict__ den,
    const float* __restrict__ ef, const float* __restrict__ bias_h, float* __restrict__ conv) {
  int n = blockIdx.x;
  int t = threadIdx.x;
  int beg = node_off[n], end = node_off[n+1];
  int cnt = end - beg;
  float Dinv = (cnt > 0) ? (1.0f / (float)cnt) : 0.f;
  float wscale = Dinv / (den[n] + 1e-16f);
  __shared__ int   le_[128];
  __shared__ float lw_[128];
  float acc0 = 0.f, acc1 = 0.f;
  for (int c = beg; c < end; c += 128) {
    int nchunk = min(128, end - c);
    if (t < nchunk) {
      int i = node_list[c + t];
      le_[t] = edge_idx[i];
      lw_[t] = a_buf[i] * wscale;
    }
    __syncthreads();
    for (int j = 0; j < nchunk; ++j) {
      const float w = lw_[j];
      const float* er = &ef[(size_t)le_[j] * DD];
      acc0 += w * er[t];
      acc1 += w * er[t + 256];
    }
    __syncthreads();
  }
  conv[(size_t)n * DD + t]       = acc0 + bias_h[t];
  conv[(size_t)n * DD + t + 256] = acc1 + bias_h[t + 256];
}

// ---------------- LayerNorm(a + b), optional bf16 copy ----------------
__global__ __launch_bounds__(256) void ln_residual(const float* __restrict__ a,
    const float* __restrict__ b, const float* __restrict__ g, const float* __restrict__ be,
    float* __restrict__ out, unsigned short* __restrict__ outb) {
  int r = blockIdx.x;
  int t = threadIdx.x;
  float v0 = a[(size_t)r*DD + t]       + b[(size_t)r*DD + t];
  float v1 = a[(size_t)r*DD + t + 256] + b[(size_t)r*DD + t + 256];
  __shared__ float red[4];
  __shared__ float mu_s, rstd_s;
  float s = v0 + v1;
  #pragma unroll
  for (int off = 1; off < 64; off <<= 1) s += __shfl_xor(s, off, 64);
  int wid = t >> 6;
  if ((t & 63) == 0) red[wid] = s;
  __syncthreads();
  if (t == 0) mu_s = (red[0] + red[1] + red[2] + red[3]) / 512.f;
  __syncthreads();
  float mu = mu_s;
  float d0 = v0 - mu, d1 = v1 - mu;
  float vs = d0*d0 + d1*d1;
  #pragma unroll
  for (int off = 1; off < 64; off <<= 1) vs += __shfl_xor(vs, off, 64);
  if ((t & 63) == 0) red[wid] = vs;
  __syncthreads();
  if (t == 0) rstd_s = rsqrtf((red[0] + red[1] + red[2] + red[3]) / 512.f + 1e-5f);
  __syncthreads();
  float rs = rstd_s;
  float o0 = d0 * rs * g[t]       + be[t];
  float o1 = d1 * rs * g[t + 256] + be[t + 256];
  out[(size_t)r*DD + t]       = o0;
  out[(size_t)r*DD + t + 256] = o1;
  if (outb) {
    outb[(size_t)r*DD + t]       = f2bf(o0);
    outb[(size_t)r*DD + t + 256] = f2bf(o1);
  }
}

// ---------------- K-plane fp32 -> bf16 : Kb[h][tok][64] ----------------
__global__ __launch_bounds__(256) void conv_k(const float* __restrict__ qkv,
                                              unsigned short* __restrict__ Kb) {
  int idx = blockIdx.x * 256 + threadIdx.x;
  int e = idx * 4;
  int tok = e >> 9;
  int hd = e & 511;
  float4 v = *(const float4*)&qkv[(size_t)tok*1536 + 512 + hd];
  int h = hd >> 6, d = hd & 63;
  ushort4 w4;
  w4.x = f2bf(v.x); w4.y = f2bf(v.y); w4.z = f2bf(v.z); w4.w = f2bf(v.w);
  *(ushort4*)&Kb[(size_t)h*NN*64 + (size_t)tok*64 + d] = w4;
}

// ---------------- V-plane fp32 -> bf16 transposed : Vtb[h][d][tok] ----------------
__global__ __launch_bounds__(256) void conv_vt(const float* __restrict__ qkv,
                                               unsigned short* __restrict__ Vtb) {
  __shared__ unsigned short Tl[64][76];
  const int h = blockIdx.y;
  const int tt = blockIdx.x * 64;
  const int t = threadIdx.x;
  {
    int row = t >> 2;
    int cbase = (t & 3) * 16;
    const float* src = &qkv[(size_t)(tt + row)*1536 + 1024 + h*64 + cbase];
    #pragma unroll
    for (int jj = 0; jj < 4; ++jj) {
      float4 v = *(const float4*)&src[jj*4];
      ushort4 w4;
      w4.x = f2bf(v.x); w4.y = f2bf(v.y); w4.z = f2bf(v.z); w4.w = f2bf(v.w);
      *(ushort4*)&Tl[row][cbase + jj*4] = w4;
    }
  }
  __syncthreads();
  #pragma unroll
  for (int it = 0; it < 4; ++it) {
    int d = it*16 + (t >> 4);
    int tk = (t & 15) * 4;
    ushort4 w4;
    w4.x = Tl[tk+0][d]; w4.y = Tl[tk+1][d]; w4.z = Tl[tk+2][d]; w4.w = Tl[tk+3][d];
    *(ushort4*)&Vtb[(size_t)h*64*NN + (size_t)d*NN + tt + tk] = w4;
  }
}

// ---------------- MFMA flash attention partial (split-K), swapped-QK^T in-register softmax ----
// S^T = mfma(K, Q): lane holds one q-row (q = lid). K rows permuted at staging so each
// lane's 16 S values are exactly k in {8*lg+j, 32+8*lg+j} -> P repack for PV is 8 in-lane
// cvt_pk, no LDS bounce. m/lsum are per-lane scalars; defer-max (THR=8, base-2).
__global__ __launch_bounds__(256) void attn_mfma_part(const unsigned short* __restrict__ Kb,
                                                      const unsigned short* __restrict__ Vtb,
                                                      const float* __restrict__ qkv,
                                                      float* __restrict__ Opart,
                                                      float* __restrict__ ml) {
  const int head = blockIdx.y;
  const int z = blockIdx.z;
  const int q0 = blockIdx.x * 64;
  const int t = threadIdx.x;
  const int w = t >> 6;
  const int l = t & 63;
  const int lg = l >> 4;
  const int lid = l & 15;

  __shared__ __align__(16) unsigned short Kl[64*64];
  __shared__ __align__(16) unsigned short Vl[64*64];

  // Q fragment (B-operand: col=lane&15 -> q=lid, k(d)=lg*8+j+32*hf) — same data as before
  union { bf16x8 v; unsigned short u[8]; } qa[2];
  {
    const int qrow = q0 + w*16 + lid;
    const float* qp = &qkv[(size_t)qrow*1536 + head*64];
    const float qs = 0.125f * 1.44269504f;   // 1/sqrt(64) * log2(e)
    #pragma unroll
    for (int hf = 0; hf < 2; ++hf)
      #pragma unroll
      for (int j = 0; j < 8; ++j)
        qa[hf].u[j] = f2bf(qp[hf*32 + lg*8 + j] * qs);
  }

  float m = -1e30f, lsum = 0.f;
  f32x4 o[4];
  #pragma unroll
  for (int dt = 0; dt < 4; ++dt) o[dt] = (f32x4)0.f;

  const unsigned short* Kh = Kb  + (size_t)head*NN*64;
  const unsigned short* Vh = Vtb + (size_t)head*64*NN;
  const int kt0 = z * (NN / NSPLIT);
  const int kt1 = kt0 + (NN / NSPLIT);

  // staging geometry: 2 rows per thread; K rows permuted at the GLOBAL source
  const int srow0 = t >> 3,        scc = (t & 7) * 8;
  const int srow1 = 32 + (t >> 3);
  const int sdst0 = (srow0*64 + scc) ^ ((srow0 & 7) << 3);
  const int sdst1 = (srow1*64 + scc) ^ ((srow1 & 7) << 3);
  const int kperm0 = 8*((srow0>>2)&3) + 4*((srow0>>4)&1) + (srow0&3) + 32*(srow0>>5);
  const int kperm1 = 8*((srow1>>2)&3) + 4*((srow1>>4)&1) + (srow1&3) + 32*(srow1>>5);
  ulonglong2 kreg0, kreg1, vreg0, vreg1;

#define LOADKV(ktv) do { \
    kreg0 = *(const ulonglong2*)&Kh[(size_t)((ktv) + kperm0)*64 + scc]; \
    vreg0 = *(const ulonglong2*)&Vh[(size_t)srow0*NN + (ktv) + scc]; \
    kreg1 = *(const ulonglong2*)&Kh[(size_t)((ktv) + kperm1)*64 + scc]; \
    vreg1 = *(const ulonglong2*)&Vh[(size_t)srow1*NN + (ktv) + scc]; \
  } while (0)
#define STORKV() do { \
    *(ulonglong2*)&Kl[sdst0] = kreg0; *(ulonglong2*)&Vl[sdst0] = vreg0; \
    *(ulonglong2*)&Kl[sdst1] = kreg1; *(ulonglong2*)&Vl[sdst1] = vreg1; \
  } while (0)

  LOADKV(kt0);
  STORKV();
  __syncthreads();

  for (int kt = kt0; kt < kt1; kt += 64) {
    const bool hn = (kt + 64) < kt1;
    if (hn) LOADKV(kt + 64);   // issue early; lands during compute (T14)

    // ---- S^T = K Q^T (swapped operands) ----
    f32x4 s[4];
    #pragma unroll
    for (int n = 0; n < 4; ++n) s[n] = (f32x4)0.f;
    __builtin_amdgcn_s_setprio(1);
    #pragma unroll
    for (int n = 0; n < 4; ++n) {
      int tok = n*16 + lid;
      #pragma unroll
      for (int hf = 0; hf < 2; ++hf) {
        int didx = (tok*64 + hf*32 + lg*8) ^ ((tok & 7) << 3);
        bf16x8 kb = *(const bf16x8*)&Kl[didx];
        s[n] = __builtin_amdgcn_mfma_f32_16x16x32_bf16(kb, qa[hf].v, s[n], 0, 0, 0);
      }
    }
    __builtin_amdgcn_s_setprio(0);

    // ---- in-register online softmax (q = lid per lane) ----
    float mx = s[0][0];
    #pragma unroll
    for (int n = 0; n < 4; ++n)
      #pragma unroll
      for (int r = 0; r < 4; ++r) mx = fmaxf(mx, s[n][r]);
    mx = fmaxf(mx, __shfl_xor(mx, 16, 64));
    mx = fmaxf(mx, __shfl_xor(mx, 32, 64));
    if (!__all(mx <= m + 8.f)) {
      float mn = fmaxf(m, mx);
      float c = exp2f(m - mn);
      m = mn;
      lsum *= c;
      // o rows are q = lg*4+r -> fetch c from lane (lg*4+r)
      #pragma unroll
      for (int r = 0; r < 4; ++r) {
        float cr = __shfl(c, lg*4 + r, 64);
        #pragma unroll
        for (int dt = 0; dt < 4; ++dt) o[dt][r] *= cr;
      }
    }
    float ps = 0.f;
    #pragma unroll
    for (int n = 0; n < 4; ++n)
      #pragma unroll
      for (int r = 0; r < 4; ++r) {
        float p = exp2f(s[n][r] - m);
        s[n][r] = p;
        ps += p;
      }
    ps += __shfl_xor(ps, 16, 64);
    ps += __shfl_xor(ps, 32, 64);
    lsum += ps;

    // ---- P repack: fully in-lane (thanks to K row permutation) ----
    // pa[hf].u[i] = pk(s[2hf + (i>>1)][2*(i&1)], s[2hf + (i>>1)][2*(i&1)+1])
    union { bf16x8 v; unsigned int u[4]; } pa[2];
    #pragma unroll
    for (int hf = 0; hf < 2; ++hf) {
      asm("v_cvt_pk_bf16_f32 %0, %1, %2" : "=v"(pa[hf].u[0]) : "v"(s[2*hf][0]),   "v"(s[2*hf][1]));
      asm("v_cvt_pk_bf16_f32 %0, %1, %2" : "=v"(pa[hf].u[1]) : "v"(s[2*hf][2]),   "v"(s[2*hf][3]));
      asm("v_cvt_pk_bf16_f32 %0, %1, %2" : "=v"(pa[hf].u[2]) : "v"(s[2*hf+1][0]), "v"(s[2*hf+1][1]));
      asm("v_cvt_pk_bf16_f32 %0, %1, %2" : "=v"(pa[hf].u[3]) : "v"(s[2*hf+1][2]), "v"(s[2*hf+1][3]));
    }

    // ---- O += P V ----
    __builtin_amdgcn_s_setprio(1);
    #pragma unroll
    for (int dt = 0; dt < 4; ++dt) {
      int drow = dt*16 + lid;
      #pragma unroll
      for (int hf = 0; hf < 2; ++hf) {
        int didx = (drow*64 + hf*32 + lg*8) ^ ((drow & 7) << 3);
        bf16x8 vb = *(const bf16x8*)&Vl[didx];
        o[dt] = __builtin_amdgcn_mfma_f32_16x16x32_bf16(pa[hf].v, vb, o[dt], 0, 0, 0);
      }
    }
    __builtin_amdgcn_s_setprio(0);

    __syncthreads();           // all waves done reading Kl/Vl
    if (hn) {
      STORKV();                // write prefetched tile
      __syncthreads();
    }
  }
#undef LOADKV
#undef STORKV

  // ---- epilogue: unnormalized partial O (rows q=lg*4+r) + per-lane (m,l) for q=lid ----
  #pragma unroll
  for (int r = 0; r < 4; ++r) {
    int q = q0 + w*16 + lg*4 + r;
    size_t base = ((size_t)(z*HH + head)*NN + q)*64;
    #pragma unroll
    for (int dt = 0; dt < 4; ++dt)
      Opart[base + dt*16 + lid] = o[dt][r];
  }
  if (l < 16) {
    int q = q0 + w*16 + l;
    size_t mb = ((size_t)(z*HH + head)*NN + q)*2;
    ml[mb]     = m;
    ml[mb + 1] = lsum;
  }
}

// ---------------- combine split-K partials -> ctx bf16 ----------------
__global__ __launch_bounds__(256) void attn_combine(const float* __restrict__ Opart,
                                                    const float* __restrict__ ml,
                                                    unsigned short* __restrict__ ctxb) {
  const int w = threadIdx.x >> 6, lane = threadIdx.x & 63;
  const int row = blockIdx.x * 4 + w;     // 0 .. NN*HH-1
  const int q = row >> 3, head = row & 7;
  float ms[NSPLIT], ls[NSPLIT];
  float mglob = -1e30f;
  #pragma unroll
  for (int s = 0; s < NSPLIT; ++s) {
    size_t mb = ((size_t)(s*HH + head)*NN + q)*2;
    ms[s] = ml[mb]; ls[s] = ml[mb + 1];
    mglob = fmaxf(mglob, ms[s]);
  }
  float lt = 0.f, ov = 0.f;
  #pragma unroll
  for (int s = 0; s < NSPLIT; ++s) {
    float wgt = exp2f(ms[s] - mglob);
    lt += ls[s] * wgt;
    ov += Opart[((size_t)(s*HH + head)*NN + q)*64 + lane] * wgt;
  }
  ctxb[(size_t)q*DD + head*64 + lane] = f2bf(ov / lt);
}

// ---------------- host ----------------
extern "C" void kernel_launch(void* const* d_in, const int* in_sizes, int n_in,
                              void* d_out, int out_size, void* d_ws, size_t ws_size,
                              hipStream_t stream) {
  const float* x       = (const float*)d_in[0];
  const int*   hidx    = (const int*)d_in[1];
  const float* hattr   = (const float*)d_in[2];
  const float* Wh      = (const float*)d_in[3];
  const float* att     = (const float*)d_in[4];
  const float* bias_h  = (const float*)d_in[5];
  const float* ln1_g   = (const float*)d_in[6];
  const float* ln1_b   = (const float*)d_in[7];
  const float* ln2_g   = (const float*)d_in[8];
  const float* ln2_b   = (const float*)d_in[9];
  const float* in_proj_w  = (const float*)d_in[10];
  const float* in_proj_b  = (const float*)d_in[11];
  const float* out_proj_w = (const float*)d_in[12];
  const float* out_proj_b = (const float*)d_in[13];
  const float* ff1_w   = (const float*)d_in[14];
  const float* ff1_b   = (const float*)d_in[15];
  const float* ff2_w   = (const float*)d_in[16];
  const float* ff2_b   = (const float*)d_in[17];
  const float* tln1_g  = (const float*)d_in[18];
  const float* tln1_b  = (const float*)d_in[19];
  const float* tln2_g  = (const float*)d_in[20];
  const float* tln2_b  = (const float*)d_in[21];
  const int* node_idx = hidx;
  const int* edge_idx = hidx + NNZC;

  char* ws = (char*)d_ws;
  size_t off = 0;
  auto alloc = [&](size_t bytes) -> void* {
    void* p = ws + off;
    off = (off + bytes + 63) & ~(size_t)63;
    return p;
  };
  float* xl       = (float*)alloc(sizeof(float)*NN*DD);
  float* el       = (float*)alloc(sizeof(float)*MM*DD);
  float* s_node   = (float*)alloc(sizeof(float)*NN);
  float* s_edge   = (float*)alloc(sizeof(float)*MM);
  float* a_buf    = (float*)alloc(sizeof(float)*NNZC);
  float* amax     = (float*)alloc(sizeof(float)*NN);
  float* den      = (float*)alloc(sizeof(float)*NN);
  int*   DnCnt    = (int*)alloc(sizeof(int)*NN);
  int*   BnCnt    = (int*)alloc(sizeof(int)*MM);
  int*   node_off = (int*)alloc(sizeof(int)*(NN+1));
  int*   edge_off = (int*)alloc(sizeof(int)*(MM+1));
  int*   node_cur = (int*)alloc(sizeof(int)*NN);
  int*   edge_cur = (int*)alloc(sizeof(int)*MM);
  int*   node_list= (int*)alloc(sizeof(int)*NNZC);
  int*   edge_list= (int*)alloc(sizeof(int)*NNZC);
  float* ef       = (float*)alloc(sizeof(float)*MM*DD);
  float* conv     = (float*)alloc(sizeof(float)*NN*DD);
  float* x1       = (float*)alloc(sizeof(float)*NN*DD);
  float* qkvb     = (float*)alloc(sizeof(float)*NN*3*DD);
  float* attn_out = (float*)alloc(sizeof(float)*NN*DD);
  float* x2       = (float*)alloc(sizeof(float)*NN*DD);
  unsigned short* Kb    = (unsigned short*)alloc(sizeof(unsigned short)*NN*DD);
  unsigned short* Vtb   = (unsigned short*)alloc(sizeof(unsigned short)*NN*DD);
  unsigned short* xb    = (unsigned short*)alloc(sizeof(unsigned short)*NN*DD);
  unsigned short* hattrb= (unsigned short*)alloc(sizeof(unsigned short)*MM*DD);
  unsigned short* Whb   = (unsigned short*)alloc(sizeof(unsigned short)*DD*DD);
  unsigned short* ipwb  = (unsigned short*)alloc(sizeof(unsigned short)*3*DD*DD);
  unsigned short* opwb  = (unsigned short*)alloc(sizeof(unsigned short)*DD*DD);
  unsigned short* ff1wb = (unsigned short*)alloc(sizeof(unsigned short)*DFFC*DD);
  unsigned short* ff2wb = (unsigned short*)alloc(sizeof(unsigned short)*DD*DFFC);
  unsigned short* x1b   = (unsigned short*)alloc(sizeof(unsigned short)*NN*DD);
  unsigned short* x2b   = (unsigned short*)alloc(sizeof(unsigned short)*NN*DD);
  unsigned short* ctxb  = (unsigned short*)alloc(sizeof(unsigned short)*NN*DD);
  // "late" region: attention partials alias FFN-phase buffers (dead before ff1).
  char* late = (char*)alloc(33u*1024*1024);
  float*          Opart = (float*)late;                                  // 32 MB (attn phase)
  float*          mlb   = (float*)(late + 32u*1024*1024);                // 1 MB (attn phase)
  unsigned short* ffhb  = (unsigned short*)late;                         // 16 MB (FFN phase)
  float*          ffo   = (float*)(late + 16u*1024*1024);                // 8 MB (FFN phase)
  float*          x3    = (float*)(late + 24u*1024*1024);                // 8 MB (FFN phase)
  (void)ws_size; (void)in_sizes; (void)n_in; (void)out_size;

  dim3 b256(256);
  auto f2bL = [&](const float* src, unsigned short* dst, int n) {
    f2b_kernel<<<(n/8 + 255)/256, b256, 0, stream>>>(src, dst, n/8);
  };
  // one-time bf16 conversions
  f2bL(x, xb, NN*DD);
  f2bL(hattr, hattrb, MM*DD);
  f2bL(Wh, Whb, DD*DD);
  f2bL(in_proj_w, ipwb, 3*DD*DD);
  f2bL(out_proj_w, opwb, DD*DD);
  f2bL(ff1_w, ff1wb, DFFC*DD);
  f2bL(ff2_w, ff2wb, DD*DFFC);

  // xl = x @ Wh^T ; el = hattr @ Wh^T  (bf16 MFMA, fp32 out)
  gemm_bt_bf16<<<dim3(NN/128, DD/128), b256, 0, stream>>>(xb, Whb, nullptr, xl, nullptr, DD, DD, 0);
  gemm_bt_bf16<<<dim3(MM/128, DD/128), b256, 0, stream>>>(hattrb, Whb, nullptr, el, nullptr, DD, DD, 0);
  // sparse hypergraph conv
  rowdot<<<NN/4, b256, 0, stream>>>(xl, att,      s_node, NN);
  rowdot<<<MM/4, b256, 0, stream>>>(el, att + DD, s_edge, MM);
  init_kernel<<<NN/256, b256, 0, stream>>>(amax, den, DnCnt, BnCnt, node_cur, edge_cur);
  incidence_pass1<<<NNZC/256, b256, 0, stream>>>(node_idx, edge_idx, s_node, s_edge,
                                                 a_buf, amax, DnCnt, BnCnt);
  exscan_kernel<<<1, 1024, 0, stream>>>(DnCnt, node_off, NN);
  exscan_kernel<<<1, 1024, 0, stream>>>(BnCnt, edge_off, MM);
  incidence_pass2<<<NNZC/256, b256, 0, stream>>>(node_idx, edge_idx, a_buf, amax, den,
                                                 node_off, edge_off, node_cur, edge_cur,
                                                 node_list, edge_list);
  gather_edge<<<MM, b256, 0, stream>>>(edge_off, edge_list, node_idx, a_buf, den, xl, ef);
  gather_node<<<NN, b256, 0, stream>>>(node_off, node_list, edge_idx, a_buf, den, ef, bias_h, conv);
  // x1 = LN(x + conv) (+ bf16 copy)
  ln_residual<<<NN, b256, 0, stream>>>(x, conv, ln1_g, ln1_b, x1, x1b);
  // qkv
  gemm_bt_bf16<<<dim3(NN/128, (3*DD)/128), b256, 0, stream>>>(x1b, ipwb, in_proj_b, qkvb, nullptr, 3*DD, DD, 0);
  // attention (bf16 MFMA, split-K x4 + combine)
  conv_k <<<NN*DD/(256*4), b256, 0, stream>>>(qkvb, Kb);
  conv_vt<<<dim3(NN/64, HH), b256, 0, stream>>>(qkvb, Vtb);
  attn_mfma_part<<<dim3(NN/64, HH, NSPLIT), b256, 0, stream>>>(Kb, Vtb, qkvb, Opart, mlb);
  attn_combine<<<NN*HH/4, b256, 0, stream>>>(Opart, mlb, ctxb);
  // out_proj
  gemm_bt_bf16<<<dim3(NN/128, DD/128), b256, 0, stream>>>(ctxb, opwb, out_proj_b, attn_out, nullptr, DD, DD, 0);
  // x2 = LN(x1 + attn_out) (+ bf16)
  ln_residual<<<NN, b256, 0, stream>>>(x1, attn_out, tln1_g, tln1_b, x2, x2b);
  // ffn: ff1 (bf16 out w/ relu), ff2 (fp32 out)
  gemm_bt_bf16<<<dim3(NN/128, DFFC/128), b256, 0, stream>>>(x2b, ff1wb, ff1_b, nullptr, ffhb, DFFC, DD, 1);
  gemm_bt_bf16<<<dim3(NN/128, DD/128),   b256, 0, stream>>>(ffhb, ff2wb, ff2_b, ffo, nullptr, DD, DFFC, 0);
  // x3 = LN(x2 + ff)
  ln_residual<<<NN, b256, 0, stream>>>(x2, ffo, tln2_g, tln2_b, x3, nullptr);
  // out = LN(x1 + x3)
  ln_residual<<<NN, b256, 0, stream>>>(x1, x3, ln2_g, ln2_b, (float*)d_out, nullptr);
}

// Round 9
// 326.860 us; speedup vs baseline: 6.0645x; 1.0101x over previous
//
#include <hip/hip_runtime.h>
#include <math.h>

#define NN   4096
#define MM   1024
#define NNZC 65536
#define DD   512
#define HH   8
#define DHH  64
#define DFFC 2048
#define NSPLIT 4

typedef short bf16x8 __attribute__((ext_vector_type(8)));
typedef float f32x4  __attribute__((ext_vector_type(4)));

static __device__ inline unsigned short f2bf(float f) {
  union { float f; unsigned int u; } v; v.f = f;
  unsigned int r = v.u + 0x7fff + ((v.u >> 16) & 1);   // RNE
  return (unsigned short)(r >> 16);
}
static __device__ inline float bf2f(unsigned short u) {
  return __uint_as_float((unsigned int)u << 16);
}

__device__ inline void gload16(const void* g, void* l) {
  __builtin_amdgcn_global_load_lds(
      (const __attribute__((address_space(1))) void*)g,
      (__attribute__((address_space(3))) void*)l, 16, 0, 0);
}

// ---------------- utility ----------------
__device__ inline void atomicMaxF(float* addr, float val) {
  if (val >= 0.f) atomicMax((int*)addr, __float_as_int(val));
  else            atomicMin((unsigned int*)addr, __float_as_uint(val));
}

// ---------------- init ----------------
__global__ void init_kernel(float* amax, float* den, int* DnCnt, int* BnCnt,
                            int* node_cur, int* edge_cur) {
  int i = blockIdx.x * 256 + threadIdx.x;
  if (i < NN) { amax[i] = -INFINITY; den[i] = 0.f; DnCnt[i] = 0; node_cur[i] = 0; }
  if (i < MM) { BnCnt[i] = 0; edge_cur[i] = 0; }
}

// ---------------- fp32 -> bf16 bulk convert (8 elems/thread) ----------------
__global__ __launch_bounds__(256) void f2b_kernel(const float* __restrict__ in,
    unsigned short* __restrict__ out, int n8) {
  int i = blockIdx.x * 256 + threadIdx.x;
  if (i >= n8) return;
  float4 v0 = *(const float4*)&in[(size_t)i*8];
  float4 v1 = *(const float4*)&in[(size_t)i*8 + 4];
  unsigned short w[8];
  w[0]=f2bf(v0.x); w[1]=f2bf(v0.y); w[2]=f2bf(v0.z); w[3]=f2bf(v0.w);
  w[4]=f2bf(v1.x); w[5]=f2bf(v1.y); w[6]=f2bf(v1.z); w[7]=f2bf(v1.w);
  *(ulonglong2*)&out[(size_t)i*8] = *(ulonglong2*)w;
}

// ---------------- bf16 MFMA NT GEMM: C[M,N] = A[M,K] @ B[N,K]^T (+bias,+relu) ----------------
__global__ __launch_bounds__(256) void gemm_bt_bf16(
    const unsigned short* __restrict__ A, const unsigned short* __restrict__ B,
    const float* __restrict__ bias, float* __restrict__ Cf,
    unsigned short* __restrict__ Cb, int N, int K, int relu) {
  __shared__ __align__(16) unsigned short Al[128*64];
  __shared__ __align__(16) unsigned short Bl[128*64];
  const int t = threadIdx.x;
  const int w = t >> 6, l = t & 63;
  const int lg = l >> 4, lid = l & 15;
  const int wr = w >> 1, wc = w & 1;
  const int bm = blockIdx.x * 128, bn = blockIdx.y * 128;

  f32x4 acc[4][4];
  #pragma unroll
  for (int mi = 0; mi < 4; ++mi)
    #pragma unroll
    for (int ni = 0; ni < 4; ++ni) acc[mi][ni] = (f32x4)0.f;

  for (int k0 = 0; k0 < K; k0 += 64) {
    #pragma unroll
    for (int i = 0; i < 4; ++i) {
      int cid = i*256 + t;
      int row = cid >> 3, cp = cid & 7;
      int gc = cp ^ (row & 7);
      gload16(&A[(size_t)(bm + row)*K + k0 + gc*8], &Al[cid*8]);
      gload16(&B[(size_t)(bn + row)*K + k0 + gc*8], &Bl[cid*8]);
    }
    asm volatile("s_waitcnt vmcnt(0)" ::: "memory");
    __syncthreads();
    #pragma unroll
    for (int ks = 0; ks < 2; ++ks) {
      bf16x8 af[4], bfr[4];
      #pragma unroll
      for (int mi = 0; mi < 4; ++mi) {
        int r = wr*64 + mi*16 + lid;
        af[mi] = *(const bf16x8*)&Al[r*64 + ((ks*4 + lg) ^ (r & 7))*8];
      }
      #pragma unroll
      for (int ni = 0; ni < 4; ++ni) {
        int r = wc*64 + ni*16 + lid;
        bfr[ni] = *(const bf16x8*)&Bl[r*64 + ((ks*4 + lg) ^ (r & 7))*8];
      }
      __builtin_amdgcn_s_setprio(1);
      #pragma unroll
      for (int mi = 0; mi < 4; ++mi)
        #pragma unroll
        for (int ni = 0; ni < 4; ++ni)
          acc[mi][ni] = __builtin_amdgcn_mfma_f32_16x16x32_bf16(af[mi], bfr[ni], acc[mi][ni], 0, 0, 0);
      __builtin_amdgcn_s_setprio(0);
    }
    __syncthreads();
  }

  #pragma unroll
  for (int ni = 0; ni < 4; ++ni) {
    int col = bn + wc*64 + ni*16 + lid;
    float bv = bias ? bias[col] : 0.f;
    #pragma unroll
    for (int mi = 0; mi < 4; ++mi) {
      #pragma unroll
      for (int rg = 0; rg < 4; ++rg) {
        int row = bm + wr*64 + mi*16 + lg*4 + rg;
        float v = acc[mi][ni][rg] + bv;
        if (relu) v = fmaxf(v, 0.f);
        if (Cf) Cf[(size_t)row*N + col] = v;
        if (Cb) Cb[(size_t)row*N + col] = f2bf(v);
      }
    }
  }
}

// ---------------- per-row dot (bf16 input) ----------------
__global__ __launch_bounds__(256) void rowdot_b16(const unsigned short* __restrict__ X,
    const float* __restrict__ vec, float* __restrict__ out, int rows) {
  int w = (blockIdx.x * 256 + threadIdx.x) >> 6;
  int lane = threadIdx.x & 63;
  if (w >= rows) return;
  const unsigned short* xr = &X[(size_t)w * DD];
  float s = 0.f;
  #pragma unroll
  for (int j = 0; j < 8; ++j) s += bf2f(xr[lane + 64*j]) * vec[lane + 64*j];
  #pragma unroll
  for (int off = 1; off < 64; off <<= 1) s += __shfl_xor(s, off, 64);
  if (lane == 0) out[w] = s;
}

// ---------------- incidence pass 1 ----------------
__global__ void incidence_pass1(const int* __restrict__ node_idx, const int* __restrict__ edge_idx,
    const float* __restrict__ s_node, const float* __restrict__ s_edge,
    float* __restrict__ a_buf, float* amax, int* DnCnt, int* BnCnt) {
  int i = blockIdx.x * 256 + threadIdx.x;
  if (i >= NNZC) return;
  int n = node_idx[i], m = edge_idx[i];
  float a = s_node[n] + s_edge[m];
  a = (a >= 0.f) ? a : 0.2f * a;
  a_buf[i] = a;
  atomicMaxF(&amax[n], a);
  atomicAdd(&DnCnt[n], 1);
  atomicAdd(&BnCnt[m], 1);
}

// ---------------- single-block exclusive scan ----------------
__global__ __launch_bounds__(1024) void exscan_kernel(const int* __restrict__ in,
                                                      int* __restrict__ out, int n) {
  __shared__ int sums[1024];
  const int t = threadIdx.x;
  const int chunk = (n + 1023) >> 10;
  const int start = t * chunk;
  const int stop  = min(start + chunk, n);
  int local = 0;
  for (int i = start; i < stop; ++i) local += in[i];
  sums[t] = local;
  __syncthreads();
  for (int o = 1; o < 1024; o <<= 1) {
    int v = (t >= o) ? sums[t - o] : 0;
    __syncthreads();
    sums[t] += v;
    __syncthreads();
  }
  int run = (t == 0) ? 0 : sums[t - 1];
  for (int i = start; i < stop; ++i) { out[i] = run; run += in[i]; }
  if (t == 1023) out[n] = sums[1023];
}

// ---------------- incidence pass 2 ----------------
__global__ void incidence_pass2(const int* __restrict__ node_idx, const int* __restrict__ edge_idx,
    float* __restrict__ a_buf, const float* __restrict__ amax, float* den,
    const int* __restrict__ node_off, const int* __restrict__ edge_off,
    int* node_cur, int* edge_cur, int* node_list, int* edge_list) {
  int i = blockIdx.x * 256 + threadIdx.x;
  if (i >= NNZC) return;
  int n = node_idx[i], m = edge_idx[i];
  float e = __expf(a_buf[i] - amax[n]);
  a_buf[i] = e;
  atomicAdd(&den[n], e);
  int pn = atomicAdd(&node_cur[n], 1);
  node_list[node_off[n] + pn] = i;
  int pm = atomicAdd(&edge_cur[m], 1);
  edge_list[edge_off[m] + pm] = i;
}

// ---------------- edge gather (bf16 xl in, bf16 ef out) ----------------
__global__ __launch_bounds__(256) void gather_edge(const int* __restrict__ edge_off,
    const int* __restrict__ edge_list, const int* __restrict__ node_idx,
    const float* __restrict__ a_buf, const float* __restrict__ den,
    const unsigned short* __restrict__ xlb, unsigned short* __restrict__ efb) {
  int m = blockIdx.x;
  int t = threadIdx.x;
  int beg = edge_off[m], end = edge_off[m+1];
  int cnt = end - beg;
  float Binv = (cnt > 0) ? (1.0f / (float)cnt) : 0.f;
  __shared__ int   ln_[128];
  __shared__ float lw_[128];
  float acc0 = 0.f, acc1 = 0.f;
  for (int c = beg; c < end; c += 128) {
    int nchunk = min(128, end - c);
    if (t < nchunk) {
      int i = edge_list[c + t];
      int n = node_idx[i];
      ln_[t] = n;
      lw_[t] = a_buf[i] / (den[n] + 1e-16f) * Binv;
    }
    __syncthreads();
    float a0 = 0.f, a1 = 0.f, b0 = 0.f, b1 = 0.f;
    int j = 0;
    for (; j + 1 < nchunk; j += 2) {
      float w0 = lw_[j], w1 = lw_[j+1];
      const unsigned short* r0 = &xlb[(size_t)ln_[j]   * DD];
      const unsigned short* r1 = &xlb[(size_t)ln_[j+1] * DD];
      a0 += w0 * bf2f(r0[t]);       b0 += w0 * bf2f(r0[t + 256]);
      a1 += w1 * bf2f(r1[t]);       b1 += w1 * bf2f(r1[t + 256]);
    }
    if (j < nchunk) {
      float w0 = lw_[j];
      const unsigned short* r0 = &xlb[(size_t)ln_[j] * DD];
      a0 += w0 * bf2f(r0[t]);       b0 += w0 * bf2f(r0[t + 256]);
    }
    acc0 += a0 + a1;
    acc1 += b0 + b1;
    __syncthreads();
  }
  efb[(size_t)m * DD + t]       = f2bf(acc0);
  efb[(size_t)m * DD + t + 256] = f2bf(acc1);
}

// ---------------- node gather (bf16 ef in, fp32 conv out) ----------------
__global__ __launch_bounds__(256) void gather_node(const int* __restrict__ node_off,
    const int* __restrict__ node_list, const int* __restrict__ edge_idx,
    const float* __restrict__ a_buf, const float* __restrict__ den,
    const unsigned short* __restrict__ efb, const float* __restrict__ bias_h,
    float* __restrict__ conv) {
  int n = blockIdx.x;
  int t = threadIdx.x;
  int beg = node_off[n], end = node_off[n+1];
  int cnt = end - beg;
  float Dinv = (cnt > 0) ? (1.0f / (float)cnt) : 0.f;
  float wscale = Dinv / (den[n] + 1e-16f);
  __shared__ int   le_[128];
  __shared__ float lw_[128];
  float acc0 = 0.f, acc1 = 0.f;
  for (int c = beg; c < end; c += 128) {
    int nchunk = min(128, end - c);
    if (t < nchunk) {
      int i = node_list[c + t];
      le_[t] = edge_idx[i];
      lw_[t] = a_buf[i] * wscale;
    }
    __syncthreads();
    float a0 = 0.f, a1 = 0.f, b0 = 0.f, b1 = 0.f;
    int j = 0;
    for (; j + 1 < nchunk; j += 2) {
      float w0 = lw_[j], w1 = lw_[j+1];
      const unsigned short* r0 = &efb[(size_t)le_[j]   * DD];
      const unsigned short* r1 = &efb[(size_t)le_[j+1] * DD];
      a0 += w0 * bf2f(r0[t]);       b0 += w0 * bf2f(r0[t + 256]);
      a1 += w1 * bf2f(r1[t]);       b1 += w1 * bf2f(r1[t + 256]);
    }
    if (j < nchunk) {
      float w0 = lw_[j];
      const unsigned short* r0 = &efb[(size_t)le_[j] * DD];
      a0 += w0 * bf2f(r0[t]);       b0 += w0 * bf2f(r0[t + 256]);
    }
    acc0 += a0 + a1;
    acc1 += b0 + b1;
    __syncthreads();
  }
  conv[(size_t)n * DD + t]       = acc0 + bias_h[t];
  conv[(size_t)n * DD + t + 256] = acc1 + bias_h[t + 256];
}

// ---------------- LayerNorm(a + b), b fp32 or bf16; optional bf16 copy ----------------
__global__ __launch_bounds__(256) void ln_residual(const float* __restrict__ a,
    const float* __restrict__ b, const unsigned short* __restrict__ bB,
    const float* __restrict__ g, const float* __restrict__ be,
    float* __restrict__ out, unsigned short* __restrict__ outb) {
  int r = blockIdx.x;
  int t = threadIdx.x;
  float b0 = b ? b[(size_t)r*DD + t]       : bf2f(bB[(size_t)r*DD + t]);
  float b1 = b ? b[(size_t)r*DD + t + 256] : bf2f(bB[(size_t)r*DD + t + 256]);
  float v0 = a[(size_t)r*DD + t]       + b0;
  float v1 = a[(size_t)r*DD + t + 256] + b1;
  __shared__ float red[4];
  __shared__ float mu_s, rstd_s;
  float s = v0 + v1;
  #pragma unroll
  for (int off = 1; off < 64; off <<= 1) s += __shfl_xor(s, off, 64);
  int wid = t >> 6;
  if ((t & 63) == 0) red[wid] = s;
  __syncthreads();
  if (t == 0) mu_s = (red[0] + red[1] + red[2] + red[3]) / 512.f;
  __syncthreads();
  float mu = mu_s;
  float d0 = v0 - mu, d1 = v1 - mu;
  float vs = d0*d0 + d1*d1;
  #pragma unroll
  for (int off = 1; off < 64; off <<= 1) vs += __shfl_xor(vs, off, 64);
  if ((t & 63) == 0) red[wid] = vs;
  __syncthreads();
  if (t == 0) rstd_s = rsqrtf((red[0] + red[1] + red[2] + red[3]) / 512.f + 1e-5f);
  __syncthreads();
  float rs = rstd_s;
  float o0 = d0 * rs * g[t]       + be[t];
  float o1 = d1 * rs * g[t + 256] + be[t + 256];
  out[(size_t)r*DD + t]       = o0;
  out[(size_t)r*DD + t + 256] = o1;
  if (outb) {
    outb[(size_t)r*DD + t]       = f2bf(o0);
    outb[(size_t)r*DD + t + 256] = f2bf(o1);
  }
}

// ---------------- V-plane bf16 qkv -> transposed : Vtb[h][d][tok] ----------------
__global__ __launch_bounds__(256) void conv_vt(const unsigned short* __restrict__ qkvbb,
                                               unsigned short* __restrict__ Vtb) {
  __shared__ unsigned short Tl[64][76];
  const int h = blockIdx.y;
  const int tt = blockIdx.x * 64;
  const int t = threadIdx.x;
  {
    int row = t >> 2;
    int cbase = (t & 3) * 16;
    const unsigned short* src = &qkvbb[(size_t)(tt + row)*1536 + 1024 + h*64];
    #pragma unroll
    for (int jj = 0; jj < 4; ++jj)
      *(ushort4*)&Tl[row][cbase + jj*4] = *(const ushort4*)&src[cbase + jj*4];
  }
  __syncthreads();
  #pragma unroll
  for (int it = 0; it < 4; ++it) {
    int d = it*16 + (t >> 4);
    int tk = (t & 15) * 4;
    ushort4 w4;
    w4.x = Tl[tk+0][d]; w4.y = Tl[tk+1][d]; w4.z = Tl[tk+2][d]; w4.w = Tl[tk+3][d];
    *(ushort4*)&Vtb[(size_t)h*64*NN + (size_t)d*NN + tt + tk] = w4;
  }
}

// ---------------- MFMA flash attention partial (split-K), swapped-QK^T in-register softmax ----
// Q,K read directly from bf16 qkv (row stride 1536); raw-unit softmax: p = exp2(s*sc - msc).
__global__ __launch_bounds__(256) void attn_mfma_part(const unsigned short* __restrict__ qkvbb,
                                                      const unsigned short* __restrict__ Vtb,
                                                      float* __restrict__ Opart,
                                                      float* __restrict__ ml) {
  const int head = blockIdx.y;
  const int z = blockIdx.z;
  const int q0 = blockIdx.x * 64;
  const int t = threadIdx.x;
  const int w = t >> 6;
  const int l = t & 63;
  const int lg = l >> 4;
  const int lid = l & 15;
  const float sc = 0.125f * 1.44269504f;    // 1/sqrt(64) * log2(e)
  const float THRraw = 44.36f;              // 8 / sc

  __shared__ __align__(16) unsigned short Kl[64*64];
  __shared__ __align__(16) unsigned short Vl[64*64];

  // Q fragment: raw bf16, no scaling (scale folded into exp)
  bf16x8 qa[2];
  {
    const int qrow = q0 + w*16 + lid;
    const unsigned short* qp = &qkvbb[(size_t)qrow*1536 + head*64];
    qa[0] = *(const bf16x8*)&qp[lg*8];
    qa[1] = *(const bf16x8*)&qp[32 + lg*8];
  }

  float m = -1e30f, msc = -1e30f, lsum = 0.f;
  f32x4 o[4];
  #pragma unroll
  for (int dt = 0; dt < 4; ++dt) o[dt] = (f32x4)0.f;

  const unsigned short* Kh = qkvbb + 512 + head*64;          // row stride 1536
  const unsigned short* Vh = Vtb + (size_t)head*64*NN;
  const int kt0 = z * (NN / NSPLIT);
  const int kt1 = kt0 + (NN / NSPLIT);

  // staging geometry: 2 rows per thread; K rows permuted at the GLOBAL source
  const int srow0 = t >> 3,        scc = (t & 7) * 8;
  const int srow1 = 32 + (t >> 3);
  const int sdst0 = (srow0*64 + scc) ^ ((srow0 & 7) << 3);
  const int sdst1 = (srow1*64 + scc) ^ ((srow1 & 7) << 3);
  const int kperm0 = 8*((srow0>>2)&3) + 4*((srow0>>4)&1) + (srow0&3) + 32*(srow0>>5);
  const int kperm1 = 8*((srow1>>2)&3) + 4*((srow1>>4)&1) + (srow1&3) + 32*(srow1>>5);
  ulonglong2 kreg0, kreg1, vreg0, vreg1;

#define LOADKV(ktv) do { \
    kreg0 = *(const ulonglong2*)&Kh[(size_t)((ktv) + kperm0)*1536 + scc]; \
    vreg0 = *(const ulonglong2*)&Vh[(size_t)srow0*NN + (ktv) + scc]; \
    kreg1 = *(const ulonglong2*)&Kh[(size_t)((ktv) + kperm1)*1536 + scc]; \
    vreg1 = *(const ulonglong2*)&Vh[(size_t)srow1*NN + (ktv) + scc]; \
  } while (0)
#define STORKV() do { \
    *(ulonglong2*)&Kl[sdst0] = kreg0; *(ulonglong2*)&Vl[sdst0] = vreg0; \
    *(ulonglong2*)&Kl[sdst1] = kreg1; *(ulonglong2*)&Vl[sdst1] = vreg1; \
  } while (0)

  LOADKV(kt0);
  STORKV();
  __syncthreads();

  for (int kt = kt0; kt < kt1; kt += 64) {
    const bool hn = (kt + 64) < kt1;
    if (hn) LOADKV(kt + 64);   // issue early; lands during compute (T14)

    // ---- S^T = K Q^T (swapped operands) ----
    f32x4 s[4];
    #pragma unroll
    for (int n = 0; n < 4; ++n) s[n] = (f32x4)0.f;
    __builtin_amdgcn_s_setprio(1);
    #pragma unroll
    for (int n = 0; n < 4; ++n) {
      int tok = n*16 + lid;
      #pragma unroll
      for (int hf = 0; hf < 2; ++hf) {
        int didx = (tok*64 + hf*32 + lg*8) ^ ((tok & 7) << 3);
        bf16x8 kb = *(const bf16x8*)&Kl[didx];
        s[n] = __builtin_amdgcn_mfma_f32_16x16x32_bf16(kb, qa[hf], s[n], 0, 0, 0);
      }
    }
    __builtin_amdgcn_s_setprio(0);

    // ---- in-register online softmax, raw units (q = lid per lane) ----
    float mx = s[0][0];
    #pragma unroll
    for (int n = 0; n < 4; ++n)
      #pragma unroll
      for (int r = 0; r < 4; ++r) mx = fmaxf(mx, s[n][r]);
    mx = fmaxf(mx, __shfl_xor(mx, 16, 64));
    mx = fmaxf(mx, __shfl_xor(mx, 32, 64));
    if (!__all(mx <= m + THRraw)) {
      float mn = fmaxf(m, mx);
      float c = exp2f((m - mn) * sc);
      m = mn;
      msc = m * sc;
      lsum *= c;
      #pragma unroll
      for (int r = 0; r < 4; ++r) {
        float cr = __shfl(c, lg*4 + r, 64);
        #pragma unroll
        for (int dt = 0; dt < 4; ++dt) o[dt][r] *= cr;
      }
    }
    float ps = 0.f;
    #pragma unroll
    for (int n = 0; n < 4; ++n)
      #pragma unroll
      for (int r = 0; r < 4; ++r) {
        float p = exp2f(fmaf(s[n][r], sc, -msc));
        s[n][r] = p;
        ps += p;
      }
    ps += __shfl_xor(ps, 16, 64);
    ps += __shfl_xor(ps, 32, 64);
    lsum += ps;

    // ---- P repack: fully in-lane (thanks to K row permutation) ----
    union { bf16x8 v; unsigned int u[4]; } pa[2];
    #pragma unroll
    for (int hf = 0; hf < 2; ++hf) {
      asm("v_cvt_pk_bf16_f32 %0, %1, %2" : "=v"(pa[hf].u[0]) : "v"(s[2*hf][0]),   "v"(s[2*hf][1]));
      asm("v_cvt_pk_bf16_f32 %0, %1, %2" : "=v"(pa[hf].u[1]) : "v"(s[2*hf][2]),   "v"(s[2*hf][3]));
      asm("v_cvt_pk_bf16_f32 %0, %1, %2" : "=v"(pa[hf].u[2]) : "v"(s[2*hf+1][0]), "v"(s[2*hf+1][1]));
      asm("v_cvt_pk_bf16_f32 %0, %1, %2" : "=v"(pa[hf].u[3]) : "v"(s[2*hf+1][2]), "v"(s[2*hf+1][3]));
    }

    // ---- O += P V ----
    __builtin_amdgcn_s_setprio(1);
    #pragma unroll
    for (int dt = 0; dt < 4; ++dt) {
      int drow = dt*16 + lid;
      #pragma unroll
      for (int hf = 0; hf < 2; ++hf) {
        int didx = (drow*64 + hf*32 + lg*8) ^ ((drow & 7) << 3);
        bf16x8 vb = *(const bf16x8*)&Vl[didx];
        o[dt] = __builtin_amdgcn_mfma_f32_16x16x32_bf16(pa[hf].v, vb, o[dt], 0, 0, 0);
      }
    }
    __builtin_amdgcn_s_setprio(0);

    __syncthreads();           // all waves done reading Kl/Vl
    if (hn) {
      STORKV();                // write prefetched tile
      __syncthreads();
    }
  }
#undef LOADKV
#undef STORKV

  // ---- epilogue: unnormalized partial O (rows q=lg*4+r) + per-lane (msc, l) for q=lid ----
  #pragma unroll
  for (int r = 0; r < 4; ++r) {
    int q = q0 + w*16 + lg*4 + r;
    size_t base = ((size_t)(z*HH + head)*NN + q)*64;
    #pragma unroll
    for (int dt = 0; dt < 4; ++dt)
      Opart[base + dt*16 + lid] = o[dt][r];
  }
  if (l < 16) {
    int q = q0 + w*16 + l;
    size_t mb = ((size_t)(z*HH + head)*NN + q)*2;
    ml[mb]     = msc;
    ml[mb + 1] = lsum;
  }
}

// ---------------- combine split-K partials -> ctx bf16 ----------------
__global__ __launch_bounds__(256) void attn_combine(const float* __restrict__ Opart,
                                                    const float* __restrict__ ml,
                                                    unsigned short* __restrict__ ctxb) {
  const int w = threadIdx.x >> 6, lane = threadIdx.x & 63;
  const int row = blockIdx.x * 4 + w;     // 0 .. NN*HH-1
  const int q = row >> 3, head = row & 7;
  float ms[NSPLIT], ls[NSPLIT];
  float mglob = -1e30f;
  #pragma unroll
  for (int s = 0; s < NSPLIT; ++s) {
    size_t mb = ((size_t)(s*HH + head)*NN + q)*2;
    ms[s] = ml[mb]; ls[s] = ml[mb + 1];
    mglob = fmaxf(mglob, ms[s]);
  }
  float lt = 0.f, ov = 0.f;
  #pragma unroll
  for (int s = 0; s < NSPLIT; ++s) {
    float wgt = exp2f(ms[s] - mglob);
    lt += ls[s] * wgt;
    ov += Opart[((size_t)(s*HH + head)*NN + q)*64 + lane] * wgt;
  }
  ctxb[(size_t)q*DD + head*64 + lane] = f2bf(ov / lt);
}

// ---------------- host ----------------
extern "C" void kernel_launch(void* const* d_in, const int* in_sizes, int n_in,
                              void* d_out, int out_size, void* d_ws, size_t ws_size,
                              hipStream_t stream) {
  const float* x       = (const float*)d_in[0];
  const int*   hidx    = (const int*)d_in[1];
  const float* hattr   = (const float*)d_in[2];
  const float* Wh      = (const float*)d_in[3];
  const float* att     = (const float*)d_in[4];
  const float* bias_h  = (const float*)d_in[5];
  const float* ln1_g   = (const float*)d_in[6];
  const float* ln1_b   = (const float*)d_in[7];
  const float* ln2_g   = (const float*)d_in[8];
  const float* ln2_b   = (const float*)d_in[9];
  const float* in_proj_w  = (const float*)d_in[10];
  const float* in_proj_b  = (const float*)d_in[11];
  const float* out_proj_w = (const float*)d_in[12];
  const float* out_proj_b = (const float*)d_in[13];
  const float* ff1_w   = (const float*)d_in[14];
  const float* ff1_b   = (const float*)d_in[15];
  const float* ff2_w   = (const float*)d_in[16];
  const float* ff2_b   = (const float*)d_in[17];
  const float* tln1_g  = (const float*)d_in[18];
  const float* tln1_b  = (const float*)d_in[19];
  const float* tln2_g  = (const float*)d_in[20];
  const float* tln2_b  = (const float*)d_in[21];
  const int* node_idx = hidx;
  const int* edge_idx = hidx + NNZC;

  char* ws = (char*)d_ws;
  size_t off = 0;
  auto alloc = [&](size_t bytes) -> void* {
    void* p = ws + off;
    off = (off + bytes + 63) & ~(size_t)63;
    return p;
  };
  float* s_node   = (float*)alloc(sizeof(float)*NN);
  float* s_edge   = (float*)alloc(sizeof(float)*MM);
  float* a_buf    = (float*)alloc(sizeof(float)*NNZC);
  float* amax     = (float*)alloc(sizeof(float)*NN);
  float* den      = (float*)alloc(sizeof(float)*NN);
  int*   DnCnt    = (int*)alloc(sizeof(int)*NN);
  int*   BnCnt    = (int*)alloc(sizeof(int)*MM);
  int*   node_off = (int*)alloc(sizeof(int)*(NN+1));
  int*   edge_off = (int*)alloc(sizeof(int)*(MM+1));
  int*   node_cur = (int*)alloc(sizeof(int)*NN);
  int*   edge_cur = (int*)alloc(sizeof(int)*MM);
  int*   node_list= (int*)alloc(sizeof(int)*NNZC);
  int*   edge_list= (int*)alloc(sizeof(int)*NNZC);
  float* conv     = (float*)alloc(sizeof(float)*NN*DD);
  float* x1       = (float*)alloc(sizeof(float)*NN*DD);
  float* x2       = (float*)alloc(sizeof(float)*NN*DD);
  unsigned short* xlb   = (unsigned short*)alloc(sizeof(unsigned short)*NN*DD);
  unsigned short* elb   = (unsigned short*)alloc(sizeof(unsigned short)*MM*DD);
  unsigned short* efb   = (unsigned short*)alloc(sizeof(unsigned short)*MM*DD);
  unsigned short* qkvbb = (unsigned short*)alloc(sizeof(unsigned short)*NN*3*DD);
  unsigned short* Vtb   = (unsigned short*)alloc(sizeof(unsigned short)*NN*DD);
  unsigned short* xb    = (unsigned short*)alloc(sizeof(unsigned short)*NN*DD);
  unsigned short* hattrb= (unsigned short*)alloc(sizeof(unsigned short)*MM*DD);
  unsigned short* Whb   = (unsigned short*)alloc(sizeof(unsigned short)*DD*DD);
  unsigned short* ipwb  = (unsigned short*)alloc(sizeof(unsigned short)*3*DD*DD);
  unsigned short* opwb  = (unsigned short*)alloc(sizeof(unsigned short)*DD*DD);
  unsigned short* ff1wb = (unsigned short*)alloc(sizeof(unsigned short)*DFFC*DD);
  unsigned short* ff2wb = (unsigned short*)alloc(sizeof(unsigned short)*DD*DFFC);
  unsigned short* x1b   = (unsigned short*)alloc(sizeof(unsigned short)*NN*DD);
  unsigned short* x2b   = (unsigned short*)alloc(sizeof(unsigned short)*NN*DD);
  unsigned short* ctxb  = (unsigned short*)alloc(sizeof(unsigned short)*NN*DD);
  unsigned short* attn_outb = (unsigned short*)alloc(sizeof(unsigned short)*NN*DD);
  // "late" region: attention partials alias FFN-phase buffers (dead before ff1).
  char* late = (char*)alloc(33u*1024*1024);
  float*          Opart = (float*)late;                                  // 32 MB (attn phase)
  float*          mlb   = (float*)(late + 32u*1024*1024);                // 1 MB (attn phase)
  unsigned short* ffhb  = (unsigned short*)late;                         // 16 MB (FFN phase)
  unsigned short* ffob  = (unsigned short*)(late + 16u*1024*1024);       // 4 MB (FFN phase)
  float*          x3    = (float*)(late + 24u*1024*1024);                // 8 MB (FFN phase)
  (void)ws_size; (void)in_sizes; (void)n_in; (void)out_size;

  dim3 b256(256);
  auto f2bL = [&](const float* src, unsigned short* dst, int n) {
    f2b_kernel<<<(n/8 + 255)/256, b256, 0, stream>>>(src, dst, n/8);
  };
  // one-time bf16 conversions
  f2bL(x, xb, NN*DD);
  f2bL(hattr, hattrb, MM*DD);
  f2bL(Wh, Whb, DD*DD);
  f2bL(in_proj_w, ipwb, 3*DD*DD);
  f2bL(out_proj_w, opwb, DD*DD);
  f2bL(ff1_w, ff1wb, DFFC*DD);
  f2bL(ff2_w, ff2wb, DD*DFFC);

  // xl = x @ Wh^T ; el = hattr @ Wh^T  (bf16 MFMA, bf16 out)
  gemm_bt_bf16<<<dim3(NN/128, DD/128), b256, 0, stream>>>(xb, Whb, nullptr, nullptr, xlb, DD, DD, 0);
  gemm_bt_bf16<<<dim3(MM/128, DD/128), b256, 0, stream>>>(hattrb, Whb, nullptr, nullptr, elb, DD, DD, 0);
  // sparse hypergraph conv
  rowdot_b16<<<NN/4, b256, 0, stream>>>(xlb, att,      s_node, NN);
  rowdot_b16<<<MM/4, b256, 0, stream>>>(elb, att + DD, s_edge, MM);
  init_kernel<<<NN/256, b256, 0, stream>>>(amax, den, DnCnt, BnCnt, node_cur, edge_cur);
  incidence_pass1<<<NNZC/256, b256, 0, stream>>>(node_idx, edge_idx, s_node, s_edge,
                                                 a_buf, amax, DnCnt, BnCnt);
  exscan_kernel<<<1, 1024, 0, stream>>>(DnCnt, node_off, NN);
  exscan_kernel<<<1, 1024, 0, stream>>>(BnCnt, edge_off, MM);
  incidence_pass2<<<NNZC/256, b256, 0, stream>>>(node_idx, edge_idx, a_buf, amax, den,
                                                 node_off, edge_off, node_cur, edge_cur,
                                                 node_list, edge_list);
  gather_edge<<<MM, b256, 0, stream>>>(edge_off, edge_list, node_idx, a_buf, den, xlb, efb);
  gather_node<<<NN, b256, 0, stream>>>(node_off, node_list, edge_idx, a_buf, den, efb, bias_h, conv);
  // x1 = LN(x + conv) (+ bf16 copy)
  ln_residual<<<NN, b256, 0, stream>>>(x, conv, nullptr, ln1_g, ln1_b, x1, x1b);
  // qkv (bf16 out only; attention reads Q/K straight from it)
  gemm_bt_bf16<<<dim3(NN/128, (3*DD)/128), b256, 0, stream>>>(x1b, ipwb, in_proj_b, nullptr, qkvbb, 3*DD, DD, 0);
  // attention (bf16 MFMA, split-K x4 + combine)
  conv_vt<<<dim3(NN/64, HH), b256, 0, stream>>>(qkvbb, Vtb);
  attn_mfma_part<<<dim3(NN/64, HH, NSPLIT), b256, 0, stream>>>(qkvbb, Vtb, Opart, mlb);
  attn_combine<<<NN*HH/4, b256, 0, stream>>>(Opart, mlb, ctxb);
  // out_proj (bf16 out)
  gemm_bt_bf16<<<dim3(NN/128, DD/128), b256, 0, stream>>>(ctxb, opwb, out_proj_b, nullptr, attn_outb, DD, DD, 0);
  // x2 = LN(x1 + attn_out) (+ bf16)
  ln_residual<<<NN, b256, 0, stream>>>(x1, nullptr, attn_outb, tln1_g, tln1_b, x2, x2b);
  // ffn: ff1 (bf16 out w/ relu), ff2 (bf16 out)
  gemm_bt_bf16<<<dim3(NN/128, DFFC/128), b256, 0, stream>>>(x2b, ff1wb, ff1_b, nullptr, ffhb, DFFC, DD, 1);
  gemm_bt_bf16<<<dim3(NN/128, DD/128),   b256, 0, stream>>>(ffhb, ff2wb, ff2_b, nullptr, ffob, DD, DFFC, 0);
  // x3 = LN(x2 + ff)
  ln_residual<<<NN, b256, 0, stream>>>(x2, nullptr, ffob, tln2_g, tln2_b, x3, nullptr);
  // out = LN(x1 + x3)
  ln_residual<<<NN, b256, 0, stream>>>(x1, x3, nullptr, ln2_g, ln2_b, (float*)d_out, nullptr);
}

// Round 10
// 309.955 us; speedup vs baseline: 6.3952x; 1.0545x over previous
//
#include <hip/hip_runtime.h>
#include <math.h>

#define NN   4096
#define MM   1024
#define NNZC 65536
#define DD   512
#define HH   8
#define DHH  64
#define DFFC 2048
#define NSPLIT 4

typedef short bf16x8 __attribute__((ext_vector_type(8)));
typedef float f32x4  __attribute__((ext_vector_type(4)));

static __device__ inline unsigned short f2bf(float f) {
  union { float f; unsigned int u; } v; v.f = f;
  unsigned int r = v.u + 0x7fff + ((v.u >> 16) & 1);   // RNE
  return (unsigned short)(r >> 16);
}
static __device__ inline float bf2f(unsigned short u) {
  return __uint_as_float((unsigned int)u << 16);
}

__device__ inline void gload16(const void* g, void* l) {
  __builtin_amdgcn_global_load_lds(
      (const __attribute__((address_space(1))) void*)g,
      (__attribute__((address_space(3))) void*)l, 16, 0, 0);
}

// ---------------- utility ----------------
__device__ inline void atomicMaxF(float* addr, float val) {
  if (val >= 0.f) atomicMax((int*)addr, __float_as_int(val));
  else            atomicMin((unsigned int*)addr, __float_as_uint(val));
}

// ---------------- init ----------------
__global__ void init_kernel(float* amax, float* den, int* DnCnt, int* BnCnt,
                            int* node_cur, int* edge_cur) {
  int i = blockIdx.x * 256 + threadIdx.x;
  if (i < NN) { amax[i] = -INFINITY; den[i] = 0.f; DnCnt[i] = 0; node_cur[i] = 0; }
  if (i < MM) { BnCnt[i] = 0; edge_cur[i] = 0; }
}

// ---------------- batched fp32 -> bf16 convert (7 segments, 1 launch) ----------------
__global__ __launch_bounds__(256) void f2b_multi(
    const float* s0, unsigned short* d0, int n0,
    const float* s1, unsigned short* d1, int n1,
    const float* s2, unsigned short* d2, int n2,
    const float* s3, unsigned short* d3, int n3,
    const float* s4, unsigned short* d4, int n4,
    const float* s5, unsigned short* d5, int n5,
    const float* s6, unsigned short* d6, int n6) {
  const float* in; unsigned short* out; int n8;
  switch (blockIdx.y) {
    case 0: in=s0; out=d0; n8=n0; break;
    case 1: in=s1; out=d1; n8=n1; break;
    case 2: in=s2; out=d2; n8=n2; break;
    case 3: in=s3; out=d3; n8=n3; break;
    case 4: in=s4; out=d4; n8=n4; break;
    case 5: in=s5; out=d5; n8=n5; break;
    default: in=s6; out=d6; n8=n6; break;
  }
  for (int i = blockIdx.x*256 + threadIdx.x; i < n8; i += gridDim.x*256) {
    float4 v0 = *(const float4*)&in[(size_t)i*8];
    float4 v1 = *(const float4*)&in[(size_t)i*8 + 4];
    unsigned short w[8];
    w[0]=f2bf(v0.x); w[1]=f2bf(v0.y); w[2]=f2bf(v0.z); w[3]=f2bf(v0.w);
    w[4]=f2bf(v1.x); w[5]=f2bf(v1.y); w[6]=f2bf(v1.z); w[7]=f2bf(v1.w);
    *(ulonglong2*)&out[(size_t)i*8] = *(ulonglong2*)w;
  }
}

// ---------------- bf16 MFMA NT GEMM: C[M,N] = A[M,K] @ B[N,K]^T (+bias,+relu) ----------------
__global__ __launch_bounds__(256) void gemm_bt_bf16(
    const unsigned short* __restrict__ A, const unsigned short* __restrict__ B,
    const float* __restrict__ bias, float* __restrict__ Cf,
    unsigned short* __restrict__ Cb, int N, int K, int relu) {
  __shared__ __align__(16) unsigned short Al[128*64];
  __shared__ __align__(16) unsigned short Bl[128*64];
  const int t = threadIdx.x;
  const int w = t >> 6, l = t & 63;
  const int lg = l >> 4, lid = l & 15;
  const int wr = w >> 1, wc = w & 1;
  const int bm = blockIdx.x * 128, bn = blockIdx.y * 128;

  f32x4 acc[4][4];
  #pragma unroll
  for (int mi = 0; mi < 4; ++mi)
    #pragma unroll
    for (int ni = 0; ni < 4; ++ni) acc[mi][ni] = (f32x4)0.f;

  for (int k0 = 0; k0 < K; k0 += 64) {
    #pragma unroll
    for (int i = 0; i < 4; ++i) {
      int cid = i*256 + t;
      int row = cid >> 3, cp = cid & 7;
      int gc = cp ^ (row & 7);
      gload16(&A[(size_t)(bm + row)*K + k0 + gc*8], &Al[cid*8]);
      gload16(&B[(size_t)(bn + row)*K + k0 + gc*8], &Bl[cid*8]);
    }
    asm volatile("s_waitcnt vmcnt(0)" ::: "memory");
    __syncthreads();
    #pragma unroll
    for (int ks = 0; ks < 2; ++ks) {
      bf16x8 af[4], bfr[4];
      #pragma unroll
      for (int mi = 0; mi < 4; ++mi) {
        int r = wr*64 + mi*16 + lid;
        af[mi] = *(const bf16x8*)&Al[r*64 + ((ks*4 + lg) ^ (r & 7))*8];
      }
      #pragma unroll
      for (int ni = 0; ni < 4; ++ni) {
        int r = wc*64 + ni*16 + lid;
        bfr[ni] = *(const bf16x8*)&Bl[r*64 + ((ks*4 + lg) ^ (r & 7))*8];
      }
      __builtin_amdgcn_s_setprio(1);
      #pragma unroll
      for (int mi = 0; mi < 4; ++mi)
        #pragma unroll
        for (int ni = 0; ni < 4; ++ni)
          acc[mi][ni] = __builtin_amdgcn_mfma_f32_16x16x32_bf16(af[mi], bfr[ni], acc[mi][ni], 0, 0, 0);
      __builtin_amdgcn_s_setprio(0);
    }
    __syncthreads();
  }

  #pragma unroll
  for (int ni = 0; ni < 4; ++ni) {
    int col = bn + wc*64 + ni*16 + lid;
    float bv = bias ? bias[col] : 0.f;
    #pragma unroll
    for (int mi = 0; mi < 4; ++mi) {
      #pragma unroll
      for (int rg = 0; rg < 4; ++rg) {
        int row = bm + wr*64 + mi*16 + lg*4 + rg;
        float v = acc[mi][ni][rg] + bv;
        if (relu) v = fmaxf(v, 0.f);
        if (Cf) Cf[(size_t)row*N + col] = v;
        if (Cb) Cb[(size_t)row*N + col] = f2bf(v);
      }
    }
  }
}

// ---------------- per-row dot (bf16 input) ----------------
__global__ __launch_bounds__(256) void rowdot_b16(const unsigned short* __restrict__ X,
    const float* __restrict__ vec, float* __restrict__ out, int rows) {
  int w = (blockIdx.x * 256 + threadIdx.x) >> 6;
  int lane = threadIdx.x & 63;
  if (w >= rows) return;
  const unsigned short* xr = &X[(size_t)w * DD];
  float s = 0.f;
  #pragma unroll
  for (int j = 0; j < 8; ++j) s += bf2f(xr[lane + 64*j]) * vec[lane + 64*j];
  #pragma unroll
  for (int off = 1; off < 64; off <<= 1) s += __shfl_xor(s, off, 64);
  if (lane == 0) out[w] = s;
}

// ---------------- incidence pass 1 ----------------
__global__ void incidence_pass1(const int* __restrict__ node_idx, const int* __restrict__ edge_idx,
    const float* __restrict__ s_node, const float* __restrict__ s_edge,
    float* __restrict__ a_buf, float* amax, int* DnCnt, int* BnCnt) {
  int i = blockIdx.x * 256 + threadIdx.x;
  if (i >= NNZC) return;
  int n = node_idx[i], m = edge_idx[i];
  float a = s_node[n] + s_edge[m];
  a = (a >= 0.f) ? a : 0.2f * a;
  a_buf[i] = a;
  atomicMaxF(&amax[n], a);
  atomicAdd(&DnCnt[n], 1);
  atomicAdd(&BnCnt[m], 1);
}

// ---------------- single-block exclusive scan ----------------
__global__ __launch_bounds__(1024) void exscan_kernel(const int* __restrict__ in,
                                                      int* __restrict__ out, int n) {
  __shared__ int sums[1024];
  const int t = threadIdx.x;
  const int chunk = (n + 1023) >> 10;
  const int start = t * chunk;
  const int stop  = min(start + chunk, n);
  int local = 0;
  for (int i = start; i < stop; ++i) local += in[i];
  sums[t] = local;
  __syncthreads();
  for (int o = 1; o < 1024; o <<= 1) {
    int v = (t >= o) ? sums[t - o] : 0;
    __syncthreads();
    sums[t] += v;
    __syncthreads();
  }
  int run = (t == 0) ? 0 : sums[t - 1];
  for (int i = start; i < stop; ++i) { out[i] = run; run += in[i]; }
  if (t == 1023) out[n] = sums[1023];
}

// ---------------- incidence pass 2 ----------------
__global__ void incidence_pass2(const int* __restrict__ node_idx, const int* __restrict__ edge_idx,
    float* __restrict__ a_buf, const float* __restrict__ amax, float* den,
    const int* __restrict__ node_off, const int* __restrict__ edge_off,
    int* node_cur, int* edge_cur, int* node_list, int* edge_list) {
  int i = blockIdx.x * 256 + threadIdx.x;
  if (i >= NNZC) return;
  int n = node_idx[i], m = edge_idx[i];
  float e = __expf(a_buf[i] - amax[n]);
  a_buf[i] = e;
  atomicAdd(&den[n], e);
  int pn = atomicAdd(&node_cur[n], 1);
  node_list[node_off[n] + pn] = i;
  int pm = atomicAdd(&edge_cur[m], 1);
  edge_list[edge_off[m] + pm] = i;
}

// ---------------- edge gather (bf16 xl in, bf16 ef out) ----------------
__global__ __launch_bounds__(256) void gather_edge(const int* __restrict__ edge_off,
    const int* __restrict__ edge_list, const int* __restrict__ node_idx,
    const float* __restrict__ a_buf, const float* __restrict__ den,
    const unsigned short* __restrict__ xlb, unsigned short* __restrict__ efb) {
  int m = blockIdx.x;
  int t = threadIdx.x;
  int beg = edge_off[m], end = edge_off[m+1];
  int cnt = end - beg;
  float Binv = (cnt > 0) ? (1.0f / (float)cnt) : 0.f;
  __shared__ int   ln_[128];
  __shared__ float lw_[128];
  float acc0 = 0.f, acc1 = 0.f;
  for (int c = beg; c < end; c += 128) {
    int nchunk = min(128, end - c);
    if (t < nchunk) {
      int i = edge_list[c + t];
      int n = node_idx[i];
      ln_[t] = n;
      lw_[t] = a_buf[i] / (den[n] + 1e-16f) * Binv;
    }
    __syncthreads();
    float a0 = 0.f, a1 = 0.f, b0 = 0.f, b1 = 0.f;
    int j = 0;
    for (; j + 1 < nchunk; j += 2) {
      float w0 = lw_[j], w1 = lw_[j+1];
      const unsigned short* r0 = &xlb[(size_t)ln_[j]   * DD];
      const unsigned short* r1 = &xlb[(size_t)ln_[j+1] * DD];
      a0 += w0 * bf2f(r0[t]);       b0 += w0 * bf2f(r0[t + 256]);
      a1 += w1 * bf2f(r1[t]);       b1 += w1 * bf2f(r1[t + 256]);
    }
    if (j < nchunk) {
      float w0 = lw_[j];
      const unsigned short* r0 = &xlb[(size_t)ln_[j] * DD];
      a0 += w0 * bf2f(r0[t]);       b0 += w0 * bf2f(r0[t + 256]);
    }
    acc0 += a0 + a1;
    acc1 += b0 + b1;
    __syncthreads();
  }
  efb[(size_t)m * DD + t]       = f2bf(acc0);
  efb[(size_t)m * DD + t + 256] = f2bf(acc1);
}

// ---------------- node gather (bf16 ef in, fp32 conv out) ----------------
__global__ __launch_bounds__(256) void gather_node(const int* __restrict__ node_off,
    const int* __restrict__ node_list, const int* __restrict__ edge_idx,
    const float* __restrict__ a_buf, const float* __restrict__ den,
    const unsigned short* __restrict__ efb, const float* __restrict__ bias_h,
    float* __restrict__ conv) {
  int n = blockIdx.x;
  int t = threadIdx.x;
  int beg = node_off[n], end = node_off[n+1];
  int cnt = end - beg;
  float Dinv = (cnt > 0) ? (1.0f / (float)cnt) : 0.f;
  float wscale = Dinv / (den[n] + 1e-16f);
  __shared__ int   le_[128];
  __shared__ float lw_[128];
  float acc0 = 0.f, acc1 = 0.f;
  for (int c = beg; c < end; c += 128) {
    int nchunk = min(128, end - c);
    if (t < nchunk) {
      int i = node_list[c + t];
      le_[t] = edge_idx[i];
      lw_[t] = a_buf[i] * wscale;
    }
    __syncthreads();
    float a0 = 0.f, a1 = 0.f, b0 = 0.f, b1 = 0.f;
    int j = 0;
    for (; j + 1 < nchunk; j += 2) {
      float w0 = lw_[j], w1 = lw_[j+1];
      const unsigned short* r0 = &efb[(size_t)le_[j]   * DD];
      const unsigned short* r1 = &efb[(size_t)le_[j+1] * DD];
      a0 += w0 * bf2f(r0[t]);       b0 += w0 * bf2f(r0[t + 256]);
      a1 += w1 * bf2f(r1[t]);       b1 += w1 * bf2f(r1[t + 256]);
    }
    if (j < nchunk) {
      float w0 = lw_[j];
      const unsigned short* r0 = &efb[(size_t)le_[j] * DD];
      a0 += w0 * bf2f(r0[t]);       b0 += w0 * bf2f(r0[t + 256]);
    }
    acc0 += a0 + a1;
    acc1 += b0 + b1;
    __syncthreads();
  }
  conv[(size_t)n * DD + t]       = acc0 + bias_h[t];
  conv[(size_t)n * DD + t + 256] = acc1 + bias_h[t + 256];
}

// ---------------- LayerNorm(a + b), b fp32 or bf16; optional bf16 copy ----------------
__global__ __launch_bounds__(256) void ln_residual(const float* __restrict__ a,
    const float* __restrict__ b, const unsigned short* __restrict__ bB,
    const float* __restrict__ g, const float* __restrict__ be,
    float* __restrict__ out, unsigned short* __restrict__ outb) {
  int r = blockIdx.x;
  int t = threadIdx.x;
  float b0 = b ? b[(size_t)r*DD + t]       : bf2f(bB[(size_t)r*DD + t]);
  float b1 = b ? b[(size_t)r*DD + t + 256] : bf2f(bB[(size_t)r*DD + t + 256]);
  float v0 = a[(size_t)r*DD + t]       + b0;
  float v1 = a[(size_t)r*DD + t + 256] + b1;
  __shared__ float red[4];
  __shared__ float mu_s, rstd_s;
  float s = v0 + v1;
  #pragma unroll
  for (int off = 1; off < 64; off <<= 1) s += __shfl_xor(s, off, 64);
  int wid = t >> 6;
  if ((t & 63) == 0) red[wid] = s;
  __syncthreads();
  if (t == 0) mu_s = (red[0] + red[1] + red[2] + red[3]) / 512.f;
  __syncthreads();
  float mu = mu_s;
  float d0 = v0 - mu, d1 = v1 - mu;
  float vs = d0*d0 + d1*d1;
  #pragma unroll
  for (int off = 1; off < 64; off <<= 1) vs += __shfl_xor(vs, off, 64);
  if ((t & 63) == 0) red[wid] = vs;
  __syncthreads();
  if (t == 0) rstd_s = rsqrtf((red[0] + red[1] + red[2] + red[3]) / 512.f + 1e-5f);
  __syncthreads();
  float rs = rstd_s;
  float o0 = d0 * rs * g[t]       + be[t];
  float o1 = d1 * rs * g[t + 256] + be[t + 256];
  out[(size_t)r*DD + t]       = o0;
  out[(size_t)r*DD + t + 256] = o1;
  if (outb) {
    outb[(size_t)r*DD + t]       = f2bf(o0);
    outb[(size_t)r*DD + t + 256] = f2bf(o1);
  }
}

// ---------------- fused final 2 LayerNorms: x3=LN(x2+ffo); out=LN(x1+x3) ----------------
__global__ __launch_bounds__(256) void ln_final2(const float* __restrict__ x2,
    const unsigned short* __restrict__ ffob, const float* __restrict__ x1,
    const float* __restrict__ g1, const float* __restrict__ b1,
    const float* __restrict__ g2, const float* __restrict__ b2,
    float* __restrict__ out) {
  int r = blockIdx.x;
  int t = threadIdx.x;
  __shared__ float red[4];
  __shared__ float sh0, sh1;
  int wid = t >> 6;
  // --- LN pass 1: x3 = LN(x2 + ffo) ---
  float v0 = x2[(size_t)r*DD + t]       + bf2f(ffob[(size_t)r*DD + t]);
  float v1 = x2[(size_t)r*DD + t + 256] + bf2f(ffob[(size_t)r*DD + t + 256]);
  float s = v0 + v1;
  #pragma unroll
  for (int off = 1; off < 64; off <<= 1) s += __shfl_xor(s, off, 64);
  if ((t & 63) == 0) red[wid] = s;
  __syncthreads();
  if (t == 0) sh0 = (red[0] + red[1] + red[2] + red[3]) / 512.f;
  __syncthreads();
  float mu = sh0;
  float d0 = v0 - mu, d1 = v1 - mu;
  float vs = d0*d0 + d1*d1;
  #pragma unroll
  for (int off = 1; off < 64; off <<= 1) vs += __shfl_xor(vs, off, 64);
  if ((t & 63) == 0) red[wid] = vs;
  __syncthreads();
  if (t == 0) sh1 = rsqrtf((red[0] + red[1] + red[2] + red[3]) / 512.f + 1e-5f);
  __syncthreads();
  float rs = sh1;
  float x30 = d0 * rs * g1[t]       + b1[t];
  float x31 = d1 * rs * g1[t + 256] + b1[t + 256];
  __syncthreads();   // red[] reuse
  // --- LN pass 2: out = LN(x1 + x3) ---
  float u0 = x1[(size_t)r*DD + t]       + x30;
  float u1 = x1[(size_t)r*DD + t + 256] + x31;
  s = u0 + u1;
  #pragma unroll
  for (int off = 1; off < 64; off <<= 1) s += __shfl_xor(s, off, 64);
  if ((t & 63) == 0) red[wid] = s;
  __syncthreads();
  if (t == 0) sh0 = (red[0] + red[1] + red[2] + red[3]) / 512.f;
  __syncthreads();
  mu = sh0;
  d0 = u0 - mu; d1 = u1 - mu;
  vs = d0*d0 + d1*d1;
  #pragma unroll
  for (int off = 1; off < 64; off <<= 1) vs += __shfl_xor(vs, off, 64);
  if ((t & 63) == 0) red[wid] = vs;
  __syncthreads();
  if (t == 0) sh1 = rsqrtf((red[0] + red[1] + red[2] + red[3]) / 512.f + 1e-5f);
  __syncthreads();
  rs = sh1;
  out[(size_t)r*DD + t]       = d0 * rs * g2[t]       + b2[t];
  out[(size_t)r*DD + t + 256] = d1 * rs * g2[t + 256] + b2[t + 256];
}

// ---------------- V-plane bf16 qkv -> transposed : Vtb[h][d][tok] ----------------
__global__ __launch_bounds__(256) void conv_vt(const unsigned short* __restrict__ qkvbb,
                                               unsigned short* __restrict__ Vtb) {
  __shared__ unsigned short Tl[64][76];
  const int h = blockIdx.y;
  const int tt = blockIdx.x * 64;
  const int t = threadIdx.x;
  {
    int row = t >> 2;
    int cbase = (t & 3) * 16;
    const unsigned short* src = &qkvbb[(size_t)(tt + row)*1536 + 1024 + h*64];
    #pragma unroll
    for (int jj = 0; jj < 4; ++jj)
      *(ushort4*)&Tl[row][cbase + jj*4] = *(const ushort4*)&src[cbase + jj*4];
  }
  __syncthreads();
  #pragma unroll
  for (int it = 0; it < 4; ++it) {
    int d = it*16 + (t >> 4);
    int tk = (t & 15) * 4;
    ushort4 w4;
    w4.x = Tl[tk+0][d]; w4.y = Tl[tk+1][d]; w4.z = Tl[tk+2][d]; w4.w = Tl[tk+3][d];
    *(ushort4*)&Vtb[(size_t)h*64*NN + (size_t)d*NN + tt + tk] = w4;
  }
}

// ---------------- MFMA flash attention partial (split-K): swapped-QK^T, in-reg softmax,
// LDS double-buffer + global_load_lds staging (K-perm & XOR-swizzle folded into global src).
__global__ __launch_bounds__(256) void attn_mfma_part(const unsigned short* __restrict__ qkvbb,
                                                      const unsigned short* __restrict__ Vtb,
                                                      unsigned short* __restrict__ Opartb,
                                                      float* __restrict__ ml) {
  const int head = blockIdx.y;
  const int z = blockIdx.z;
  const int q0 = blockIdx.x * 64;
  const int t = threadIdx.x;
  const int w = t >> 6;
  const int l = t & 63;
  const int lg = l >> 4;
  const int lid = l & 15;
  const float sc = 0.125f * 1.44269504f;    // 1/sqrt(64) * log2(e)
  const float THRraw = 44.36f;              // 8 / sc

  __shared__ __align__(16) unsigned short Kl[2][64*64];
  __shared__ __align__(16) unsigned short Vl[2][64*64];

  // Q fragment: raw bf16, scale folded into exp
  bf16x8 qa[2];
  {
    const int qrow = q0 + w*16 + lid;
    const unsigned short* qp = &qkvbb[(size_t)qrow*1536 + head*64];
    qa[0] = *(const bf16x8*)&qp[lg*8];
    qa[1] = *(const bf16x8*)&qp[32 + lg*8];
  }

  float m = -1e30f, msc = -1e30f, lsum = 0.f;
  f32x4 o[4];
  #pragma unroll
  for (int dt = 0; dt < 4; ++dt) o[dt] = (f32x4)0.f;

  const unsigned short* Kh = qkvbb + 512 + head*64;          // row stride 1536
  const unsigned short* Vh = Vtb + (size_t)head*64*NN;
  const int kt0 = z * (NN / NSPLIT);
  const int kt1 = kt0 + (NN / NSPLIT);

  // staging: this thread stages chunks c0 = t, c1 = 256+t (16B each).
  // chunk c -> LDS row = c>>3 (linear); content chunk p = (c&7) ^ (row&7) (XOR swizzle),
  // K rows additionally permuted: LDS row r holds K token kperm(r).
  const int c0 = t, c1 = 256 + t;
  const int row0 = c0 >> 3, p0 = (c0 & 7) ^ (row0 & 7);
  const int row1 = c1 >> 3, p1 = (c1 & 7) ^ (row1 & 7);
  const int kp0 = 8*((row0>>2)&3) + 4*((row0>>4)&1) + (row0&3) + 32*(row0>>5);
  const int kp1 = 8*((row1>>2)&3) + 4*((row1>>4)&1) + (row1&3) + 32*(row1>>5);

#define ISSUE(buf, ktv) do { \
    gload16(&Kh[(size_t)((ktv) + kp0)*1536 + p0*8], &Kl[buf][c0*8]); \
    gload16(&Kh[(size_t)((ktv) + kp1)*1536 + p1*8], &Kl[buf][c1*8]); \
    gload16(&Vh[(size_t)row0*NN + (ktv) + p0*8],    &Vl[buf][c0*8]); \
    gload16(&Vh[(size_t)row1*NN + (ktv) + p1*8],    &Vl[buf][c1*8]); \
  } while (0)

  ISSUE(0, kt0);
  asm volatile("s_waitcnt vmcnt(0)" ::: "memory");
  __syncthreads();

  int cur = 0;
  for (int kt = kt0; kt < kt1; kt += 64) {
    const bool hn = (kt + 64) < kt1;
    if (hn) ISSUE(cur ^ 1, kt + 64);   // async; lands during compute

    // ---- S^T = K Q^T (swapped operands) ----
    f32x4 s[4];
    #pragma unroll
    for (int n = 0; n < 4; ++n) s[n] = (f32x4)0.f;
    __builtin_amdgcn_s_setprio(1);
    #pragma unroll
    for (int n = 0; n < 4; ++n) {
      int tok = n*16 + lid;
      #pragma unroll
      for (int hf = 0; hf < 2; ++hf) {
        int didx = (tok*64 + hf*32 + lg*8) ^ ((tok & 7) << 3);
        bf16x8 kb = *(const bf16x8*)&Kl[cur][didx];
        s[n] = __builtin_amdgcn_mfma_f32_16x16x32_bf16(kb, qa[hf], s[n], 0, 0, 0);
      }
    }
    __builtin_amdgcn_s_setprio(0);

    // ---- in-register online softmax, raw units (q = lid per lane) ----
    float a0 = fmaxf(fmaxf(s[0][0], s[0][1]), s[0][2]);
    float a1 = fmaxf(fmaxf(s[0][3], s[1][0]), s[1][1]);
    float a2 = fmaxf(fmaxf(s[1][2], s[1][3]), s[2][0]);
    float a3 = fmaxf(fmaxf(s[2][1], s[2][2]), s[2][3]);
    float a4 = fmaxf(fmaxf(s[3][0], s[3][1]), s[3][2]);
    float mx = fmaxf(fmaxf(fmaxf(a0, a1), a2), fmaxf(fmaxf(a3, a4), s[3][3]));
    mx = fmaxf(mx, __shfl_xor(mx, 16, 64));
    mx = fmaxf(mx, __shfl_xor(mx, 32, 64));
    if (!__all(mx <= m + THRraw)) {
      float mn = fmaxf(m, mx);
      float c = exp2f((m - mn) * sc);
      m = mn;
      msc = m * sc;
      lsum *= c;
      #pragma unroll
      for (int r = 0; r < 4; ++r) {
        float cr = __shfl(c, lg*4 + r, 64);
        #pragma unroll
        for (int dt = 0; dt < 4; ++dt) o[dt][r] *= cr;
      }
    }
    float ps = 0.f;
    #pragma unroll
    for (int n = 0; n < 4; ++n)
      #pragma unroll
      for (int r = 0; r < 4; ++r) {
        float p = exp2f(fmaf(s[n][r], sc, -msc));
        s[n][r] = p;
        ps += p;
      }
    ps += __shfl_xor(ps, 16, 64);
    ps += __shfl_xor(ps, 32, 64);
    lsum += ps;

    // ---- P repack: fully in-lane (thanks to K row permutation) ----
    union { bf16x8 v; unsigned int u[4]; } pa[2];
    #pragma unroll
    for (int hf = 0; hf < 2; ++hf) {
      asm("v_cvt_pk_bf16_f32 %0, %1, %2" : "=v"(pa[hf].u[0]) : "v"(s[2*hf][0]),   "v"(s[2*hf][1]));
      asm("v_cvt_pk_bf16_f32 %0, %1, %2" : "=v"(pa[hf].u[1]) : "v"(s[2*hf][2]),   "v"(s[2*hf][3]));
      asm("v_cvt_pk_bf16_f32 %0, %1, %2" : "=v"(pa[hf].u[2]) : "v"(s[2*hf+1][0]), "v"(s[2*hf+1][1]));
      asm("v_cvt_pk_bf16_f32 %0, %1, %2" : "=v"(pa[hf].u[3]) : "v"(s[2*hf+1][2]), "v"(s[2*hf+1][3]));
    }

    // ---- O += P V ----
    __builtin_amdgcn_s_setprio(1);
    #pragma unroll
    for (int dt = 0; dt < 4; ++dt) {
      int drow = dt*16 + lid;
      #pragma unroll
      for (int hf = 0; hf < 2; ++hf) {
        int didx = (drow*64 + hf*32 + lg*8) ^ ((drow & 7) << 3);
        bf16x8 vb = *(const bf16x8*)&Vl[cur][didx];
        o[dt] = __builtin_amdgcn_mfma_f32_16x16x32_bf16(pa[hf].v, vb, o[dt], 0, 0, 0);
      }
    }
    __builtin_amdgcn_s_setprio(0);

    asm volatile("s_waitcnt vmcnt(0)" ::: "memory");   // next-tile loads landed
    __syncthreads();                                   // all waves done with cur
    cur ^= 1;
  }
#undef ISSUE

  // ---- epilogue: bf16 partial O (rows q=lg*4+r) + per-lane (msc, l) for q=lid ----
  #pragma unroll
  for (int r = 0; r < 4; ++r) {
    int q = q0 + w*16 + lg*4 + r;
    size_t base = ((size_t)(z*HH + head)*NN + q)*64;
    #pragma unroll
    for (int dt = 0; dt < 4; ++dt)
      Opartb[base + dt*16 + lid] = f2bf(o[dt][r]);
  }
  if (l < 16) {
    int q = q0 + w*16 + l;
    size_t mb = ((size_t)(z*HH + head)*NN + q)*2;
    ml[mb]     = msc;
    ml[mb + 1] = lsum;
  }
}

// ---------------- combine split-K partials -> ctx bf16 ----------------
__global__ __launch_bounds__(256) void attn_combine(const unsigned short* __restrict__ Opartb,
                                                    const float* __restrict__ ml,
                                                    unsigned short* __restrict__ ctxb) {
  const int w = threadIdx.x >> 6, lane = threadIdx.x & 63;
  const int row = blockIdx.x * 4 + w;     // 0 .. NN*HH-1
  const int q = row >> 3, head = row & 7;
  float ms[NSPLIT], ls[NSPLIT];
  float mglob = -1e30f;
  #pragma unroll
  for (int s = 0; s < NSPLIT; ++s) {
    size_t mb = ((size_t)(s*HH + head)*NN + q)*2;
    ms[s] = ml[mb]; ls[s] = ml[mb + 1];
    mglob = fmaxf(mglob, ms[s]);
  }
  float lt = 0.f, ov = 0.f;
  #pragma unroll
  for (int s = 0; s < NSPLIT; ++s) {
    float wgt = exp2f(ms[s] - mglob);
    lt += ls[s] * wgt;
    ov += bf2f(Opartb[((size_t)(s*HH + head)*NN + q)*64 + lane]) * wgt;
  }
  ctxb[(size_t)q*DD + head*64 + lane] = f2bf(ov / lt);
}

// ---------------- host ----------------
extern "C" void kernel_launch(void* const* d_in, const int* in_sizes, int n_in,
                              void* d_out, int out_size, void* d_ws, size_t ws_size,
                              hipStream_t stream) {
  const float* x       = (const float*)d_in[0];
  const int*   hidx    = (const int*)d_in[1];
  const float* hattr   = (const float*)d_in[2];
  const float* Wh      = (const float*)d_in[3];
  const float* att     = (const float*)d_in[4];
  const float* bias_h  = (const float*)d_in[5];
  const float* ln1_g   = (const float*)d_in[6];
  const float* ln1_b   = (const float*)d_in[7];
  const float* ln2_g   = (const float*)d_in[8];
  const float* ln2_b   = (const float*)d_in[9];
  const float* in_proj_w  = (const float*)d_in[10];
  const float* in_proj_b  = (const float*)d_in[11];
  const float* out_proj_w = (const float*)d_in[12];
  const float* out_proj_b = (const float*)d_in[13];
  const float* ff1_w   = (const float*)d_in[14];
  const float* ff1_b   = (const float*)d_in[15];
  const float* ff2_w   = (const float*)d_in[16];
  const float* ff2_b   = (const float*)d_in[17];
  const float* tln1_g  = (const float*)d_in[18];
  const float* tln1_b  = (const float*)d_in[19];
  const float* tln2_g  = (const float*)d_in[20];
  const float* tln2_b  = (const float*)d_in[21];
  const int* node_idx = hidx;
  const int* edge_idx = hidx + NNZC;

  char* ws = (char*)d_ws;
  size_t off = 0;
  auto alloc = [&](size_t bytes) -> void* {
    void* p = ws + off;
    off = (off + bytes + 63) & ~(size_t)63;
    return p;
  };
  float* s_node   = (float*)alloc(sizeof(float)*NN);
  float* s_edge   = (float*)alloc(sizeof(float)*MM);
  float* a_buf    = (float*)alloc(sizeof(float)*NNZC);
  float* amax     = (float*)alloc(sizeof(float)*NN);
  float* den      = (float*)alloc(sizeof(float)*NN);
  int*   DnCnt    = (int*)alloc(sizeof(int)*NN);
  int*   BnCnt    = (int*)alloc(sizeof(int)*MM);
  int*   node_off = (int*)alloc(sizeof(int)*(NN+1));
  int*   edge_off = (int*)alloc(sizeof(int)*(MM+1));
  int*   node_cur = (int*)alloc(sizeof(int)*NN);
  int*   edge_cur = (int*)alloc(sizeof(int)*MM);
  int*   node_list= (int*)alloc(sizeof(int)*NNZC);
  int*   edge_list= (int*)alloc(sizeof(int)*NNZC);
  float* conv     = (float*)alloc(sizeof(float)*NN*DD);
  float* x1       = (float*)alloc(sizeof(float)*NN*DD);
  float* x2       = (float*)alloc(sizeof(float)*NN*DD);
  unsigned short* xlb   = (unsigned short*)alloc(sizeof(unsigned short)*NN*DD);
  unsigned short* elb   = (unsigned short*)alloc(sizeof(unsigned short)*MM*DD);
  unsigned short* efb   = (unsigned short*)alloc(sizeof(unsigned short)*MM*DD);
  unsigned short* qkvbb = (unsigned short*)alloc(sizeof(unsigned short)*NN*3*DD);
  unsigned short* Vtb   = (unsigned short*)alloc(sizeof(unsigned short)*NN*DD);
  unsigned short* xb    = (unsigned short*)alloc(sizeof(unsigned short)*NN*DD);
  unsigned short* hattrb= (unsigned short*)alloc(sizeof(unsigned short)*MM*DD);
  unsigned short* Whb   = (unsigned short*)alloc(sizeof(unsigned short)*DD*DD);
  unsigned short* ipwb  = (unsigned short*)alloc(sizeof(unsigned short)*3*DD*DD);
  unsigned short* opwb  = (unsigned short*)alloc(sizeof(unsigned short)*DD*DD);
  unsigned short* ff1wb = (unsigned short*)alloc(sizeof(unsigned short)*DFFC*DD);
  unsigned short* ff2wb = (unsigned short*)alloc(sizeof(unsigned short)*DD*DFFC);
  unsigned short* x1b   = (unsigned short*)alloc(sizeof(unsigned short)*NN*DD);
  unsigned short* x2b   = (unsigned short*)alloc(sizeof(unsigned short)*NN*DD);
  unsigned short* ctxb  = (unsigned short*)alloc(sizeof(unsigned short)*NN*DD);
  unsigned short* attn_outb = (unsigned short*)alloc(sizeof(unsigned short)*NN*DD);
  // "late" region: attention partials alias FFN-phase buffers (dead before ff1).
  char* late = (char*)alloc(20u*1024*1024);
  unsigned short* Opartb = (unsigned short*)late;                        // 16 MB (attn phase)
  float*          mlb    = (float*)(late + 16u*1024*1024);               // 1 MB (attn phase)
  unsigned short* ffhb   = (unsigned short*)late;                        // 16 MB (FFN phase)
  unsigned short* ffob   = (unsigned short*)(late + 16u*1024*1024);      // 4 MB (FFN phase)
  (void)ws_size; (void)in_sizes; (void)n_in; (void)out_size;

  dim3 b256(256);
  // one-time bf16 conversions (single batched launch)
  f2b_multi<<<dim3(256, 7), b256, 0, stream>>>(
      x, xb, NN*DD/8,  hattr, hattrb, MM*DD/8,  Wh, Whb, DD*DD/8,
      in_proj_w, ipwb, 3*DD*DD/8,  out_proj_w, opwb, DD*DD/8,
      ff1_w, ff1wb, DFFC*DD/8,  ff2_w, ff2wb, DD*DFFC/8);

  // xl = x @ Wh^T ; el = hattr @ Wh^T  (bf16 MFMA, bf16 out)
  gemm_bt_bf16<<<dim3(NN/128, DD/128), b256, 0, stream>>>(xb, Whb, nullptr, nullptr, xlb, DD, DD, 0);
  gemm_bt_bf16<<<dim3(MM/128, DD/128), b256, 0, stream>>>(hattrb, Whb, nullptr, nullptr, elb, DD, DD, 0);
  // sparse hypergraph conv
  rowdot_b16<<<NN/4, b256, 0, stream>>>(xlb, att,      s_node, NN);
  rowdot_b16<<<MM/4, b256, 0, stream>>>(elb, att + DD, s_edge, MM);
  init_kernel<<<NN/256, b256, 0, stream>>>(amax, den, DnCnt, BnCnt, node_cur, edge_cur);
  incidence_pass1<<<NNZC/256, b256, 0, stream>>>(node_idx, edge_idx, s_node, s_edge,
                                                 a_buf, amax, DnCnt, BnCnt);
  exscan_kernel<<<1, 1024, 0, stream>>>(DnCnt, node_off, NN);
  exscan_kernel<<<1, 1024, 0, stream>>>(BnCnt, edge_off, MM);
  incidence_pass2<<<NNZC/256, b256, 0, stream>>>(node_idx, edge_idx, a_buf, amax, den,
                                                 node_off, edge_off, node_cur, edge_cur,
                                                 node_list, edge_list);
  gather_edge<<<MM, b256, 0, stream>>>(edge_off, edge_list, node_idx, a_buf, den, xlb, efb);
  gather_node<<<NN, b256, 0, stream>>>(node_off, node_list, edge_idx, a_buf, den, efb, bias_h, conv);
  // x1 = LN(x + conv) (+ bf16 copy)
  ln_residual<<<NN, b256, 0, stream>>>(x, conv, nullptr, ln1_g, ln1_b, x1, x1b);
  // qkv (bf16 out only; attention reads Q/K straight from it)
  gemm_bt_bf16<<<dim3(NN/128, (3*DD)/128), b256, 0, stream>>>(x1b, ipwb, in_proj_b, nullptr, qkvbb, 3*DD, DD, 0);
  // attention (bf16 MFMA, split-K x4 + combine)
  conv_vt<<<dim3(NN/64, HH), b256, 0, stream>>>(qkvbb, Vtb);
  attn_mfma_part<<<dim3(NN/64, HH, NSPLIT), b256, 0, stream>>>(qkvbb, Vtb, Opartb, mlb);
  attn_combine<<<NN*HH/4, b256, 0, stream>>>(Opartb, mlb, ctxb);
  // out_proj (bf16 out)
  gemm_bt_bf16<<<dim3(NN/128, DD/128), b256, 0, stream>>>(ctxb, opwb, out_proj_b, nullptr, attn_outb, DD, DD, 0);
  // x2 = LN(x1 + attn_out) (+ bf16)
  ln_residual<<<NN, b256, 0, stream>>>(x1, nullptr, attn_outb, tln1_g, tln1_b, x2, x2b);
  // ffn: ff1 (bf16 out w/ relu), ff2 (bf16 out)
  gemm_bt_bf16<<<dim3(NN/128, DFFC/128), b256, 0, stream>>>(x2b, ff1wb, ff1_b, nullptr, ffhb, DFFC, DD, 1);
  gemm_bt_bf16<<<dim3(NN/128, DD/128),   b256, 0, stream>>>(ffhb, ff2wb, ff2_b, nullptr, ffob, DD, DFFC, 0);
  // x3 = LN(x2 + ff); out = LN(x1 + x3)  (fused)
  ln_final2<<<NN, b256, 0, stream>>>(x2, ffob, x1, tln2_g, tln2_b, ln2_g, ln2_b, (float*)d_out);
}

// Round 11
// 278.573 us; speedup vs baseline: 7.1157x; 1.1127x over previous
//
#include <hip/hip_runtime.h>
#include <math.h>

#define NN   4096
#define MM   1024
#define NNZC 65536
#define DD   512
#define HH   8
#define DHH  64
#define DFFC 2048
#define NSPLIT 4

typedef short bf16x8 __attribute__((ext_vector_type(8)));
typedef float f32x4  __attribute__((ext_vector_type(4)));

static __device__ inline unsigned short f2bf(float f) {
  union { float f; unsigned int u; } v; v.f = f;
  unsigned int r = v.u + 0x7fff + ((v.u >> 16) & 1);   // RNE
  return (unsigned short)(r >> 16);
}
static __device__ inline float bf2f(unsigned short u) {
  return __uint_as_float((unsigned int)u << 16);
}

__device__ inline void gload16(const void* g, void* l) {
  __builtin_amdgcn_global_load_lds(
      (const __attribute__((address_space(1))) void*)g,
      (__attribute__((address_space(3))) void*)l, 16, 0, 0);
}

// ---------------- utility ----------------
__device__ inline void atomicMaxF(float* addr, float val) {
  if (val >= 0.f) atomicMax((int*)addr, __float_as_int(val));
  else            atomicMin((unsigned int*)addr, __float_as_uint(val));
}

// ---------------- init ----------------
__global__ void init_kernel(float* amax, float* den, int* DnCnt, int* BnCnt,
                            int* node_cur, int* edge_cur) {
  int i = blockIdx.x * 256 + threadIdx.x;
  if (i < NN) { amax[i] = -INFINITY; den[i] = 0.f; DnCnt[i] = 0; node_cur[i] = 0; }
  if (i < MM) { BnCnt[i] = 0; edge_cur[i] = 0; }
}

// ---------------- batched fp32 -> bf16 convert (7 segments, 1 launch) ----------------
__global__ __launch_bounds__(256) void f2b_multi(
    const float* s0, unsigned short* d0, int n0,
    const float* s1, unsigned short* d1, int n1,
    const float* s2, unsigned short* d2, int n2,
    const float* s3, unsigned short* d3, int n3,
    const float* s4, unsigned short* d4, int n4,
    const float* s5, unsigned short* d5, int n5,
    const float* s6, unsigned short* d6, int n6) {
  const float* in; unsigned short* out; int n8;
  switch (blockIdx.y) {
    case 0: in=s0; out=d0; n8=n0; break;
    case 1: in=s1; out=d1; n8=n1; break;
    case 2: in=s2; out=d2; n8=n2; break;
    case 3: in=s3; out=d3; n8=n3; break;
    case 4: in=s4; out=d4; n8=n4; break;
    case 5: in=s5; out=d5; n8=n5; break;
    default: in=s6; out=d6; n8=n6; break;
  }
  for (int i = blockIdx.x*256 + threadIdx.x; i < n8; i += gridDim.x*256) {
    float4 v0 = *(const float4*)&in[(size_t)i*8];
    float4 v1 = *(const float4*)&in[(size_t)i*8 + 4];
    unsigned short w[8];
    w[0]=f2bf(v0.x); w[1]=f2bf(v0.y); w[2]=f2bf(v0.z); w[3]=f2bf(v0.w);
    w[4]=f2bf(v1.x); w[5]=f2bf(v1.y); w[6]=f2bf(v1.z); w[7]=f2bf(v1.w);
    *(ulonglong2*)&out[(size_t)i*8] = *(ulonglong2*)w;
  }
}

// ---------------- bf16 MFMA NT GEMM, 128x128 tile (ff1) ----------------
__global__ __launch_bounds__(256) void gemm_bt_bf16(
    const unsigned short* __restrict__ A, const unsigned short* __restrict__ B,
    const float* __restrict__ bias, float* __restrict__ Cf,
    unsigned short* __restrict__ Cb, int N, int K, int relu) {
  __shared__ __align__(16) unsigned short Al[128*64];
  __shared__ __align__(16) unsigned short Bl[128*64];
  const int t = threadIdx.x;
  const int w = t >> 6, l = t & 63;
  const int lg = l >> 4, lid = l & 15;
  const int wr = w >> 1, wc = w & 1;
  const int bm = blockIdx.x * 128, bn = blockIdx.y * 128;

  f32x4 acc[4][4];
  #pragma unroll
  for (int mi = 0; mi < 4; ++mi)
    #pragma unroll
    for (int ni = 0; ni < 4; ++ni) acc[mi][ni] = (f32x4)0.f;

  for (int k0 = 0; k0 < K; k0 += 64) {
    #pragma unroll
    for (int i = 0; i < 4; ++i) {
      int cid = i*256 + t;
      int row = cid >> 3, cp = cid & 7;
      int gc = cp ^ (row & 7);
      gload16(&A[(size_t)(bm + row)*K + k0 + gc*8], &Al[cid*8]);
      gload16(&B[(size_t)(bn + row)*K + k0 + gc*8], &Bl[cid*8]);
    }
    asm volatile("s_waitcnt vmcnt(0)" ::: "memory");
    __syncthreads();
    #pragma unroll
    for (int ks = 0; ks < 2; ++ks) {
      bf16x8 af[4], bfr[4];
      #pragma unroll
      for (int mi = 0; mi < 4; ++mi) {
        int r = wr*64 + mi*16 + lid;
        af[mi] = *(const bf16x8*)&Al[r*64 + ((ks*4 + lg) ^ (r & 7))*8];
      }
      #pragma unroll
      for (int ni = 0; ni < 4; ++ni) {
        int r = wc*64 + ni*16 + lid;
        bfr[ni] = *(const bf16x8*)&Bl[r*64 + ((ks*4 + lg) ^ (r & 7))*8];
      }
      __builtin_amdgcn_s_setprio(1);
      #pragma unroll
      for (int mi = 0; mi < 4; ++mi)
        #pragma unroll
        for (int ni = 0; ni < 4; ++ni)
          acc[mi][ni] = __builtin_amdgcn_mfma_f32_16x16x32_bf16(af[mi], bfr[ni], acc[mi][ni], 0, 0, 0);
      __builtin_amdgcn_s_setprio(0);
    }
    __syncthreads();
  }

  #pragma unroll
  for (int ni = 0; ni < 4; ++ni) {
    int col = bn + wc*64 + ni*16 + lid;
    float bv = bias ? bias[col] : 0.f;
    #pragma unroll
    for (int mi = 0; mi < 4; ++mi) {
      #pragma unroll
      for (int rg = 0; rg < 4; ++rg) {
        int row = bm + wr*64 + mi*16 + lg*4 + rg;
        float v = acc[mi][ni][rg] + bv;
        if (relu) v = fmaxf(v, 0.f);
        if (Cf) Cf[(size_t)row*N + col] = v;
        if (Cb) Cb[(size_t)row*N + col] = f2bf(v);
      }
    }
  }
}

// ---------------- bf16 MFMA NT GEMM, 128x64 tile (small-N GEMMs: 2x the grid) ----------------
__global__ __launch_bounds__(256) void gemm_bt_bf16_n64(
    const unsigned short* __restrict__ A, const unsigned short* __restrict__ B,
    const float* __restrict__ bias, unsigned short* __restrict__ Cb, int N, int K) {
  __shared__ __align__(16) unsigned short Al[128*64];
  __shared__ __align__(16) unsigned short Bl[64*64];
  const int t = threadIdx.x;
  const int w = t >> 6, l = t & 63;
  const int lg = l >> 4, lid = l & 15;
  const int wr = w >> 1, wc = w & 1;      // wave tile: rows wr*64, cols wc*32
  const int bm = blockIdx.x * 128, bn = blockIdx.y * 64;

  f32x4 acc[4][2];
  #pragma unroll
  for (int mi = 0; mi < 4; ++mi)
    #pragma unroll
    for (int ni = 0; ni < 2; ++ni) acc[mi][ni] = (f32x4)0.f;

  for (int k0 = 0; k0 < K; k0 += 64) {
    #pragma unroll
    for (int i = 0; i < 4; ++i) {        // A: 1024 chunks
      int cid = i*256 + t;
      int row = cid >> 3, cp = cid & 7;
      int gc = cp ^ (row & 7);
      gload16(&A[(size_t)(bm + row)*K + k0 + gc*8], &Al[cid*8]);
    }
    #pragma unroll
    for (int i = 0; i < 2; ++i) {        // B: 512 chunks
      int cid = i*256 + t;
      int row = cid >> 3, cp = cid & 7;
      int gc = cp ^ (row & 7);
      gload16(&B[(size_t)(bn + row)*K + k0 + gc*8], &Bl[cid*8]);
    }
    asm volatile("s_waitcnt vmcnt(0)" ::: "memory");
    __syncthreads();
    #pragma unroll
    for (int ks = 0; ks < 2; ++ks) {
      bf16x8 af[4], bfr[2];
      #pragma unroll
      for (int mi = 0; mi < 4; ++mi) {
        int r = wr*64 + mi*16 + lid;
        af[mi] = *(const bf16x8*)&Al[r*64 + ((ks*4 + lg) ^ (r & 7))*8];
      }
      #pragma unroll
      for (int ni = 0; ni < 2; ++ni) {
        int r = wc*32 + ni*16 + lid;
        bfr[ni] = *(const bf16x8*)&Bl[r*64 + ((ks*4 + lg) ^ (r & 7))*8];
      }
      __builtin_amdgcn_s_setprio(1);
      #pragma unroll
      for (int mi = 0; mi < 4; ++mi)
        #pragma unroll
        for (int ni = 0; ni < 2; ++ni)
          acc[mi][ni] = __builtin_amdgcn_mfma_f32_16x16x32_bf16(af[mi], bfr[ni], acc[mi][ni], 0, 0, 0);
      __builtin_amdgcn_s_setprio(0);
    }
    __syncthreads();
  }

  #pragma unroll
  for (int ni = 0; ni < 2; ++ni) {
    int col = bn + wc*32 + ni*16 + lid;
    float bv = bias ? bias[col] : 0.f;
    #pragma unroll
    for (int mi = 0; mi < 4; ++mi) {
      #pragma unroll
      for (int rg = 0; rg < 4; ++rg) {
        int row = bm + wr*64 + mi*16 + lg*4 + rg;
        Cb[(size_t)row*N + col] = f2bf(acc[mi][ni][rg] + bv);
      }
    }
  }
}

// ---------------- per-row dot (bf16 input) ----------------
__global__ __launch_bounds__(256) void rowdot_b16(const unsigned short* __restrict__ X,
    const float* __restrict__ vec, float* __restrict__ out, int rows) {
  int w = (blockIdx.x * 256 + threadIdx.x) >> 6;
  int lane = threadIdx.x & 63;
  if (w >= rows) return;
  const unsigned short* xr = &X[(size_t)w * DD];
  float s = 0.f;
  #pragma unroll
  for (int j = 0; j < 8; ++j) s += bf2f(xr[lane + 64*j]) * vec[lane + 64*j];
  #pragma unroll
  for (int off = 1; off < 64; off <<= 1) s += __shfl_xor(s, off, 64);
  if (lane == 0) out[w] = s;
}

// ---------------- incidence pass 1 ----------------
__global__ void incidence_pass1(const int* __restrict__ node_idx, const int* __restrict__ edge_idx,
    const float* __restrict__ s_node, const float* __restrict__ s_edge,
    float* __restrict__ a_buf, float* amax, int* DnCnt, int* BnCnt) {
  int i = blockIdx.x * 256 + threadIdx.x;
  if (i >= NNZC) return;
  int n = node_idx[i], m = edge_idx[i];
  float a = s_node[n] + s_edge[m];
  a = (a >= 0.f) ? a : 0.2f * a;
  a_buf[i] = a;
  atomicMaxF(&amax[n], a);
  atomicAdd(&DnCnt[n], 1);
  atomicAdd(&BnCnt[m], 1);
}

// ---------------- single-block exclusive scan ----------------
__global__ __launch_bounds__(1024) void exscan_kernel(const int* __restrict__ in,
                                                      int* __restrict__ out, int n) {
  __shared__ int sums[1024];
  const int t = threadIdx.x;
  const int chunk = (n + 1023) >> 10;
  const int start = t * chunk;
  const int stop  = min(start + chunk, n);
  int local = 0;
  for (int i = start; i < stop; ++i) local += in[i];
  sums[t] = local;
  __syncthreads();
  for (int o = 1; o < 1024; o <<= 1) {
    int v = (t >= o) ? sums[t - o] : 0;
    __syncthreads();
    sums[t] += v;
    __syncthreads();
  }
  int run = (t == 0) ? 0 : sums[t - 1];
  for (int i = start; i < stop; ++i) { out[i] = run; run += in[i]; }
  if (t == 1023) out[n] = sums[1023];
}

// ---------------- incidence pass 2 ----------------
__global__ void incidence_pass2(const int* __restrict__ node_idx, const int* __restrict__ edge_idx,
    float* __restrict__ a_buf, const float* __restrict__ amax, float* den,
    const int* __restrict__ node_off, const int* __restrict__ edge_off,
    int* node_cur, int* edge_cur, int* node_list, int* edge_list) {
  int i = blockIdx.x * 256 + threadIdx.x;
  if (i >= NNZC) return;
  int n = node_idx[i], m = edge_idx[i];
  float e = __expf(a_buf[i] - amax[n]);
  a_buf[i] = e;
  atomicAdd(&den[n], e);
  int pn = atomicAdd(&node_cur[n], 1);
  node_list[node_off[n] + pn] = i;
  int pm = atomicAdd(&edge_cur[m], 1);
  edge_list[edge_off[m] + pm] = i;
}

// ---------------- edge gather (bf16 xl in, bf16 ef out) ----------------
__global__ __launch_bounds__(256) void gather_edge(const int* __restrict__ edge_off,
    const int* __restrict__ edge_list, const int* __restrict__ node_idx,
    const float* __restrict__ a_buf, const float* __restrict__ den,
    const unsigned short* __restrict__ xlb, unsigned short* __restrict__ efb) {
  int m = blockIdx.x;
  int t = threadIdx.x;
  int beg = edge_off[m], end = edge_off[m+1];
  int cnt = end - beg;
  float Binv = (cnt > 0) ? (1.0f / (float)cnt) : 0.f;
  __shared__ int   ln_[128];
  __shared__ float lw_[128];
  float acc0 = 0.f, acc1 = 0.f;
  for (int c = beg; c < end; c += 128) {
    int nchunk = min(128, end - c);
    if (t < nchunk) {
      int i = edge_list[c + t];
      int n = node_idx[i];
      ln_[t] = n;
      lw_[t] = a_buf[i] / (den[n] + 1e-16f) * Binv;
    }
    __syncthreads();
    float a0 = 0.f, a1 = 0.f, b0 = 0.f, b1 = 0.f;
    int j = 0;
    for (; j + 1 < nchunk; j += 2) {
      float w0 = lw_[j], w1 = lw_[j+1];
      const unsigned short* r0 = &xlb[(size_t)ln_[j]   * DD];
      const unsigned short* r1 = &xlb[(size_t)ln_[j+1] * DD];
      a0 += w0 * bf2f(r0[t]);       b0 += w0 * bf2f(r0[t + 256]);
      a1 += w1 * bf2f(r1[t]);       b1 += w1 * bf2f(r1[t + 256]);
    }
    if (j < nchunk) {
      float w0 = lw_[j];
      const unsigned short* r0 = &xlb[(size_t)ln_[j] * DD];
      a0 += w0 * bf2f(r0[t]);       b0 += w0 * bf2f(r0[t + 256]);
    }
    acc0 += a0 + a1;
    acc1 += b0 + b1;
    __syncthreads();
  }
  efb[(size_t)m * DD + t]       = f2bf(acc0);
  efb[(size_t)m * DD + t + 256] = f2bf(acc1);
}

// ---------------- node gather (bf16 ef in, fp32 conv out) ----------------
__global__ __launch_bounds__(256) void gather_node(const int* __restrict__ node_off,
    const int* __restrict__ node_list, const int* __restrict__ edge_idx,
    const float* __restrict__ a_buf, const float* __restrict__ den,
    const unsigned short* __restrict__ efb, const float* __restrict__ bias_h,
    float* __restrict__ conv) {
  int n = blockIdx.x;
  int t = threadIdx.x;
  int beg = node_off[n], end = node_off[n+1];
  int cnt = end - beg;
  float Dinv = (cnt > 0) ? (1.0f / (float)cnt) : 0.f;
  float wscale = Dinv / (den[n] + 1e-16f);
  __shared__ int   le_[128];
  __shared__ float lw_[128];
  float acc0 = 0.f, acc1 = 0.f;
  for (int c = beg; c < end; c += 128) {
    int nchunk = min(128, end - c);
    if (t < nchunk) {
      int i = node_list[c + t];
      le_[t] = edge_idx[i];
      lw_[t] = a_buf[i] * wscale;
    }
    __syncthreads();
    float a0 = 0.f, a1 = 0.f, b0 = 0.f, b1 = 0.f;
    int j = 0;
    for (; j + 1 < nchunk; j += 2) {
      float w0 = lw_[j], w1 = lw_[j+1];
      const unsigned short* r0 = &efb[(size_t)le_[j]   * DD];
      const unsigned short* r1 = &efb[(size_t)le_[j+1] * DD];
      a0 += w0 * bf2f(r0[t]);       b0 += w0 * bf2f(r0[t + 256]);
      a1 += w1 * bf2f(r1[t]);       b1 += w1 * bf2f(r1[t + 256]);
    }
    if (j < nchunk) {
      float w0 = lw_[j];
      const unsigned short* r0 = &efb[(size_t)le_[j] * DD];
      a0 += w0 * bf2f(r0[t]);       b0 += w0 * bf2f(r0[t + 256]);
    }
    acc0 += a0 + a1;
    acc1 += b0 + b1;
    __syncthreads();
  }
  conv[(size_t)n * DD + t]       = acc0 + bias_h[t];
  conv[(size_t)n * DD + t + 256] = acc1 + bias_h[t + 256];
}

// ---------------- LayerNorm(a + b), b fp32 or bf16; optional bf16 copy ----------------
__global__ __launch_bounds__(256) void ln_residual(const float* __restrict__ a,
    const float* __restrict__ b, const unsigned short* __restrict__ bB,
    const float* __restrict__ g, const float* __restrict__ be,
    float* __restrict__ out, unsigned short* __restrict__ outb) {
  int r = blockIdx.x;
  int t = threadIdx.x;
  float b0 = b ? b[(size_t)r*DD + t]       : bf2f(bB[(size_t)r*DD + t]);
  float b1 = b ? b[(size_t)r*DD + t + 256] : bf2f(bB[(size_t)r*DD + t + 256]);
  float v0 = a[(size_t)r*DD + t]       + b0;
  float v1 = a[(size_t)r*DD + t + 256] + b1;
  __shared__ float red[4];
  __shared__ float mu_s, rstd_s;
  float s = v0 + v1;
  #pragma unroll
  for (int off = 1; off < 64; off <<= 1) s += __shfl_xor(s, off, 64);
  int wid = t >> 6;
  if ((t & 63) == 0) red[wid] = s;
  __syncthreads();
  if (t == 0) mu_s = (red[0] + red[1] + red[2] + red[3]) / 512.f;
  __syncthreads();
  float mu = mu_s;
  float d0 = v0 - mu, d1 = v1 - mu;
  float vs = d0*d0 + d1*d1;
  #pragma unroll
  for (int off = 1; off < 64; off <<= 1) vs += __shfl_xor(vs, off, 64);
  if ((t & 63) == 0) red[wid] = vs;
  __syncthreads();
  if (t == 0) rstd_s = rsqrtf((red[0] + red[1] + red[2] + red[3]) / 512.f + 1e-5f);
  __syncthreads();
  float rs = rstd_s;
  float o0 = d0 * rs * g[t]       + be[t];
  float o1 = d1 * rs * g[t + 256] + be[t + 256];
  out[(size_t)r*DD + t]       = o0;
  out[(size_t)r*DD + t + 256] = o1;
  if (outb) {
    outb[(size_t)r*DD + t]       = f2bf(o0);
    outb[(size_t)r*DD + t + 256] = f2bf(o1);
  }
}

// ---------------- fused final 2 LayerNorms: x3=LN(x2+ffo); out=LN(x1+x3) ----------------
__global__ __launch_bounds__(256) void ln_final2(const float* __restrict__ x2,
    const unsigned short* __restrict__ ffob, const float* __restrict__ x1,
    const float* __restrict__ g1, const float* __restrict__ b1,
    const float* __restrict__ g2, const float* __restrict__ b2,
    float* __restrict__ out) {
  int r = blockIdx.x;
  int t = threadIdx.x;
  __shared__ float red[4];
  __shared__ float sh0, sh1;
  int wid = t >> 6;
  float v0 = x2[(size_t)r*DD + t]       + bf2f(ffob[(size_t)r*DD + t]);
  float v1 = x2[(size_t)r*DD + t + 256] + bf2f(ffob[(size_t)r*DD + t + 256]);
  float s = v0 + v1;
  #pragma unroll
  for (int off = 1; off < 64; off <<= 1) s += __shfl_xor(s, off, 64);
  if ((t & 63) == 0) red[wid] = s;
  __syncthreads();
  if (t == 0) sh0 = (red[0] + red[1] + red[2] + red[3]) / 512.f;
  __syncthreads();
  float mu = sh0;
  float d0 = v0 - mu, d1 = v1 - mu;
  float vs = d0*d0 + d1*d1;
  #pragma unroll
  for (int off = 1; off < 64; off <<= 1) vs += __shfl_xor(vs, off, 64);
  if ((t & 63) == 0) red[wid] = vs;
  __syncthreads();
  if (t == 0) sh1 = rsqrtf((red[0] + red[1] + red[2] + red[3]) / 512.f + 1e-5f);
  __syncthreads();
  float rs = sh1;
  float x30 = d0 * rs * g1[t]       + b1[t];
  float x31 = d1 * rs * g1[t + 256] + b1[t + 256];
  __syncthreads();
  float u0 = x1[(size_t)r*DD + t]       + x30;
  float u1 = x1[(size_t)r*DD + t + 256] + x31;
  s = u0 + u1;
  #pragma unroll
  for (int off = 1; off < 64; off <<= 1) s += __shfl_xor(s, off, 64);
  if ((t & 63) == 0) red[wid] = s;
  __syncthreads();
  if (t == 0) sh0 = (red[0] + red[1] + red[2] + red[3]) / 512.f;
  __syncthreads();
  mu = sh0;
  d0 = u0 - mu; d1 = u1 - mu;
  vs = d0*d0 + d1*d1;
  #pragma unroll
  for (int off = 1; off < 64; off <<= 1) vs += __shfl_xor(vs, off, 64);
  if ((t & 63) == 0) red[wid] = vs;
  __syncthreads();
  if (t == 0) sh1 = rsqrtf((red[0] + red[1] + red[2] + red[3]) / 512.f + 1e-5f);
  __syncthreads();
  rs = sh1;
  out[(size_t)r*DD + t]       = d0 * rs * g2[t]       + b2[t];
  out[(size_t)r*DD + t + 256] = d1 * rs * g2[t + 256] + b2[t + 256];
}

// ---------------- V-plane bf16 qkv -> transposed : Vtb[h][d][tok] ----------------
__global__ __launch_bounds__(256) void conv_vt(const unsigned short* __restrict__ qkvbb,
                                               unsigned short* __restrict__ Vtb) {
  __shared__ unsigned short Tl[64][76];
  const int h = blockIdx.y;
  const int tt = blockIdx.x * 64;
  const int t = threadIdx.x;
  {
    int row = t >> 2;
    int cbase = (t & 3) * 16;
    const unsigned short* src = &qkvbb[(size_t)(tt + row)*1536 + 1024 + h*64];
    #pragma unroll
    for (int jj = 0; jj < 4; ++jj)
      *(ushort4*)&Tl[row][cbase + jj*4] = *(const ushort4*)&src[cbase + jj*4];
  }
  __syncthreads();
  #pragma unroll
  for (int it = 0; it < 4; ++it) {
    int d = it*16 + (t >> 4);
    int tk = (t & 15) * 4;
    ushort4 w4;
    w4.x = Tl[tk+0][d]; w4.y = Tl[tk+1][d]; w4.z = Tl[tk+2][d]; w4.w = Tl[tk+3][d];
    *(ushort4*)&Vtb[(size_t)h*64*NN + (size_t)d*NN + tt + tk] = w4;
  }
}

// ---------------- MFMA flash attention partial (split-K), swapped-QK^T in-register softmax ----
// Reg-staged single LDS buffer (round-9 structure, best measured) + bf16 partials.
__global__ __launch_bounds__(256) void attn_mfma_part(const unsigned short* __restrict__ qkvbb,
                                                      const unsigned short* __restrict__ Vtb,
                                                      unsigned short* __restrict__ Opartb,
                                                      float* __restrict__ ml) {
  const int head = blockIdx.y;
  const int z = blockIdx.z;
  const int q0 = blockIdx.x * 64;
  const int t = threadIdx.x;
  const int w = t >> 6;
  const int l = t & 63;
  const int lg = l >> 4;
  const int lid = l & 15;
  const float sc = 0.125f * 1.44269504f;    // 1/sqrt(64) * log2(e)
  const float THRraw = 44.36f;              // 8 / sc

  __shared__ __align__(16) unsigned short Kl[64*64];
  __shared__ __align__(16) unsigned short Vl[64*64];

  bf16x8 qa[2];
  {
    const int qrow = q0 + w*16 + lid;
    const unsigned short* qp = &qkvbb[(size_t)qrow*1536 + head*64];
    qa[0] = *(const bf16x8*)&qp[lg*8];
    qa[1] = *(const bf16x8*)&qp[32 + lg*8];
  }

  float m = -1e30f, msc = -1e30f, lsum = 0.f;
  f32x4 o[4];
  #pragma unroll
  for (int dt = 0; dt < 4; ++dt) o[dt] = (f32x4)0.f;

  const unsigned short* Kh = qkvbb + 512 + head*64;          // row stride 1536
  const unsigned short* Vh = Vtb + (size_t)head*64*NN;
  const int kt0 = z * (NN / NSPLIT);
  const int kt1 = kt0 + (NN / NSPLIT);

  const int srow0 = t >> 3,        scc = (t & 7) * 8;
  const int srow1 = 32 + (t >> 3);
  const int sdst0 = (srow0*64 + scc) ^ ((srow0 & 7) << 3);
  const int sdst1 = (srow1*64 + scc) ^ ((srow1 & 7) << 3);
  const int kperm0 = 8*((srow0>>2)&3) + 4*((srow0>>4)&1) + (srow0&3) + 32*(srow0>>5);
  const int kperm1 = 8*((srow1>>2)&3) + 4*((srow1>>4)&1) + (srow1&3) + 32*(srow1>>5);
  ulonglong2 kreg0, kreg1, vreg0, vreg1;

#define LOADKV(ktv) do { \
    kreg0 = *(const ulonglong2*)&Kh[(size_t)((ktv) + kperm0)*1536 + scc]; \
    vreg0 = *(const ulonglong2*)&Vh[(size_t)srow0*NN + (ktv) + scc]; \
    kreg1 = *(const ulonglong2*)&Kh[(size_t)((ktv) + kperm1)*1536 + scc]; \
    vreg1 = *(const ulonglong2*)&Vh[(size_t)srow1*NN + (ktv) + scc]; \
  } while (0)
#define STORKV() do { \
    *(ulonglong2*)&Kl[sdst0] = kreg0; *(ulonglong2*)&Vl[sdst0] = vreg0; \
    *(ulonglong2*)&Kl[sdst1] = kreg1; *(ulonglong2*)&Vl[sdst1] = vreg1; \
  } while (0)

  LOADKV(kt0);
  STORKV();
  __syncthreads();

  for (int kt = kt0; kt < kt1; kt += 64) {
    const bool hn = (kt + 64) < kt1;
    if (hn) LOADKV(kt + 64);   // issue early; lands during compute (T14)

    // ---- S^T = K Q^T (swapped operands) ----
    f32x4 s[4];
    #pragma unroll
    for (int n = 0; n < 4; ++n) s[n] = (f32x4)0.f;
    __builtin_amdgcn_s_setprio(1);
    #pragma unroll
    for (int n = 0; n < 4; ++n) {
      int tok = n*16 + lid;
      #pragma unroll
      for (int hf = 0; hf < 2; ++hf) {
        int didx = (tok*64 + hf*32 + lg*8) ^ ((tok & 7) << 3);
        bf16x8 kb = *(const bf16x8*)&Kl[didx];
        s[n] = __builtin_amdgcn_mfma_f32_16x16x32_bf16(kb, qa[hf], s[n], 0, 0, 0);
      }
    }
    __builtin_amdgcn_s_setprio(0);

    // ---- in-register online softmax, raw units (q = lid per lane) ----
    float a0 = fmaxf(fmaxf(s[0][0], s[0][1]), s[0][2]);
    float a1 = fmaxf(fmaxf(s[0][3], s[1][0]), s[1][1]);
    float a2 = fmaxf(fmaxf(s[1][2], s[1][3]), s[2][0]);
    float a3 = fmaxf(fmaxf(s[2][1], s[2][2]), s[2][3]);
    float a4 = fmaxf(fmaxf(s[3][0], s[3][1]), s[3][2]);
    float mx = fmaxf(fmaxf(fmaxf(a0, a1), a2), fmaxf(fmaxf(a3, a4), s[3][3]));
    mx = fmaxf(mx, __shfl_xor(mx, 16, 64));
    mx = fmaxf(mx, __shfl_xor(mx, 32, 64));
    if (!__all(mx <= m + THRraw)) {
      float mn = fmaxf(m, mx);
      float c = exp2f((m - mn) * sc);
      m = mn;
      msc = m * sc;
      lsum *= c;
      #pragma unroll
      for (int r = 0; r < 4; ++r) {
        float cr = __shfl(c, lg*4 + r, 64);
        #pragma unroll
        for (int dt = 0; dt < 4; ++dt) o[dt][r] *= cr;
      }
    }
    float ps = 0.f;
    #pragma unroll
    for (int n = 0; n < 4; ++n)
      #pragma unroll
      for (int r = 0; r < 4; ++r) {
        float p = exp2f(fmaf(s[n][r], sc, -msc));
        s[n][r] = p;
        ps += p;
      }
    ps += __shfl_xor(ps, 16, 64);
    ps += __shfl_xor(ps, 32, 64);
    lsum += ps;

    // ---- P repack: fully in-lane (thanks to K row permutation) ----
    union { bf16x8 v; unsigned int u[4]; } pa[2];
    #pragma unroll
    for (int hf = 0; hf < 2; ++hf) {
      asm("v_cvt_pk_bf16_f32 %0, %1, %2" : "=v"(pa[hf].u[0]) : "v"(s[2*hf][0]),   "v"(s[2*hf][1]));
      asm("v_cvt_pk_bf16_f32 %0, %1, %2" : "=v"(pa[hf].u[1]) : "v"(s[2*hf][2]),   "v"(s[2*hf][3]));
      asm("v_cvt_pk_bf16_f32 %0, %1, %2" : "=v"(pa[hf].u[2]) : "v"(s[2*hf+1][0]), "v"(s[2*hf+1][1]));
      asm("v_cvt_pk_bf16_f32 %0, %1, %2" : "=v"(pa[hf].u[3]) : "v"(s[2*hf+1][2]), "v"(s[2*hf+1][3]));
    }

    // ---- O += P V ----
    __builtin_amdgcn_s_setprio(1);
    #pragma unroll
    for (int dt = 0; dt < 4; ++dt) {
      int drow = dt*16 + lid;
      #pragma unroll
      for (int hf = 0; hf < 2; ++hf) {
        int didx = (drow*64 + hf*32 + lg*8) ^ ((drow & 7) << 3);
        bf16x8 vb = *(const bf16x8*)&Vl[didx];
        o[dt] = __builtin_amdgcn_mfma_f32_16x16x32_bf16(pa[hf].v, vb, o[dt], 0, 0, 0);
      }
    }
    __builtin_amdgcn_s_setprio(0);

    __syncthreads();           // all waves done reading Kl/Vl
    if (hn) {
      STORKV();                // write prefetched tile
      __syncthreads();
    }
  }
#undef LOADKV
#undef STORKV

  // ---- epilogue: bf16 partial O (rows q=lg*4+r) + per-lane (msc, l) for q=lid ----
  #pragma unroll
  for (int r = 0; r < 4; ++r) {
    int q = q0 + w*16 + lg*4 + r;
    size_t base = ((size_t)(z*HH + head)*NN + q)*64;
    #pragma unroll
    for (int dt = 0; dt < 4; ++dt)
      Opartb[base + dt*16 + lid] = f2bf(o[dt][r]);
  }
  if (l < 16) {
    int q = q0 + w*16 + l;
    size_t mb = ((size_t)(z*HH + head)*NN + q)*2;
    ml[mb]     = msc;
    ml[mb + 1] = lsum;
  }
}

// ---------------- combine split-K partials -> ctx bf16 ----------------
__global__ __launch_bounds__(256) void attn_combine(const unsigned short* __restrict__ Opartb,
                                                    const float* __restrict__ ml,
                                                    unsigned short* __restrict__ ctxb) {
  const int w = threadIdx.x >> 6, lane = threadIdx.x & 63;
  const int row = blockIdx.x * 4 + w;     // 0 .. NN*HH-1
  const int q = row >> 3, head = row & 7;
  float ms[NSPLIT], ls[NSPLIT];
  float mglob = -1e30f;
  #pragma unroll
  for (int s = 0; s < NSPLIT; ++s) {
    size_t mb = ((size_t)(s*HH + head)*NN + q)*2;
    ms[s] = ml[mb]; ls[s] = ml[mb + 1];
    mglob = fmaxf(mglob, ms[s]);
  }
  float lt = 0.f, ov = 0.f;
  #pragma unroll
  for (int s = 0; s < NSPLIT; ++s) {
    float wgt = exp2f(ms[s] - mglob);
    lt += ls[s] * wgt;
    ov += bf2f(Opartb[((size_t)(s*HH + head)*NN + q)*64 + lane]) * wgt;
  }
  ctxb[(size_t)q*DD + head*64 + lane] = f2bf(ov / lt);
}

// ---------------- host ----------------
extern "C" void kernel_launch(void* const* d_in, const int* in_sizes, int n_in,
                              void* d_out, int out_size, void* d_ws, size_t ws_size,
                              hipStream_t stream) {
  const float* x       = (const float*)d_in[0];
  const int*   hidx    = (const int*)d_in[1];
  const float* hattr   = (const float*)d_in[2];
  const float* Wh      = (const float*)d_in[3];
  const float* att     = (const float*)d_in[4];
  const float* bias_h  = (const float*)d_in[5];
  const float* ln1_g   = (const float*)d_in[6];
  const float* ln1_b   = (const float*)d_in[7];
  const float* ln2_g   = (const float*)d_in[8];
  const float* ln2_b   = (const float*)d_in[9];
  const float* in_proj_w  = (const float*)d_in[10];
  const float* in_proj_b  = (const float*)d_in[11];
  const float* out_proj_w = (const float*)d_in[12];
  const float* out_proj_b = (const float*)d_in[13];
  const float* ff1_w   = (const float*)d_in[14];
  const float* ff1_b   = (const float*)d_in[15];
  const float* ff2_w   = (const float*)d_in[16];
  const float* ff2_b   = (const float*)d_in[17];
  const float* tln1_g  = (const float*)d_in[18];
  const float* tln1_b  = (const float*)d_in[19];
  const float* tln2_g  = (const float*)d_in[20];
  const float* tln2_b  = (const float*)d_in[21];
  const int* node_idx = hidx;
  const int* edge_idx = hidx + NNZC;

  char* ws = (char*)d_ws;
  size_t off = 0;
  auto alloc = [&](size_t bytes) -> void* {
    void* p = ws + off;
    off = (off + bytes + 63) & ~(size_t)63;
    return p;
  };
  float* s_node   = (float*)alloc(sizeof(float)*NN);
  float* s_edge   = (float*)alloc(sizeof(float)*MM);
  float* a_buf    = (float*)alloc(sizeof(float)*NNZC);
  float* amax     = (float*)alloc(sizeof(float)*NN);
  float* den      = (float*)alloc(sizeof(float)*NN);
  int*   DnCnt    = (int*)alloc(sizeof(int)*NN);
  int*   BnCnt    = (int*)alloc(sizeof(int)*MM);
  int*   node_off = (int*)alloc(sizeof(int)*(NN+1));
  int*   edge_off = (int*)alloc(sizeof(int)*(MM+1));
  int*   node_cur = (int*)alloc(sizeof(int)*NN);
  int*   edge_cur = (int*)alloc(sizeof(int)*MM);
  int*   node_list= (int*)alloc(sizeof(int)*NNZC);
  int*   edge_list= (int*)alloc(sizeof(int)*NNZC);
  float* conv     = (float*)alloc(sizeof(float)*NN*DD);
  float* x1       = (float*)alloc(sizeof(float)*NN*DD);
  float* x2       = (float*)alloc(sizeof(float)*NN*DD);
  unsigned short* xhb   = (unsigned short*)alloc(sizeof(unsigned short)*(NN+MM)*DD);  // [x; hattr]
  unsigned short* xelb  = (unsigned short*)alloc(sizeof(unsigned short)*(NN+MM)*DD);  // [xl; el]
  unsigned short* efb   = (unsigned short*)alloc(sizeof(unsigned short)*MM*DD);
  unsigned short* qkvbb = (unsigned short*)alloc(sizeof(unsigned short)*NN*3*DD);
  unsigned short* Vtb   = (unsigned short*)alloc(sizeof(unsigned short)*NN*DD);
  unsigned short* Whb   = (unsigned short*)alloc(sizeof(unsigned short)*DD*DD);
  unsigned short* ipwb  = (unsigned short*)alloc(sizeof(unsigned short)*3*DD*DD);
  unsigned short* opwb  = (unsigned short*)alloc(sizeof(unsigned short)*DD*DD);
  unsigned short* ff1wb = (unsigned short*)alloc(sizeof(unsigned short)*DFFC*DD);
  unsigned short* ff2wb = (unsigned short*)alloc(sizeof(unsigned short)*DD*DFFC);
  unsigned short* x1b   = (unsigned short*)alloc(sizeof(unsigned short)*NN*DD);
  unsigned short* x2b   = (unsigned short*)alloc(sizeof(unsigned short)*NN*DD);
  unsigned short* ctxb  = (unsigned short*)alloc(sizeof(unsigned short)*NN*DD);
  unsigned short* attn_outb = (unsigned short*)alloc(sizeof(unsigned short)*NN*DD);
  // "late" region: attention partials alias FFN-phase buffers (dead before ff1).
  char* late = (char*)alloc(20u*1024*1024);
  unsigned short* Opartb = (unsigned short*)late;                        // 16 MB (attn phase)
  float*          mlb    = (float*)(late + 16u*1024*1024);               // 1 MB (attn phase)
  unsigned short* ffhb   = (unsigned short*)late;                        // 16 MB (FFN phase)
  unsigned short* ffob   = (unsigned short*)(late + 16u*1024*1024);      // 4 MB (FFN phase)
  unsigned short* xlb = xelb;
  unsigned short* elb = xelb + (size_t)NN*DD;
  (void)ws_size; (void)in_sizes; (void)n_in; (void)out_size;

  dim3 b256(256);
  // one-time bf16 conversions (single batched launch); x and hattr land adjacent in xhb
  f2b_multi<<<dim3(256, 7), b256, 0, stream>>>(
      x, xhb, NN*DD/8,  hattr, xhb + (size_t)NN*DD, MM*DD/8,  Wh, Whb, DD*DD/8,
      in_proj_w, ipwb, 3*DD*DD/8,  out_proj_w, opwb, DD*DD/8,
      ff1_w, ff1wb, DFFC*DD/8,  ff2_w, ff2wb, DD*DFFC/8);

  // [xl; el] = [x; hattr] @ Wh^T  (merged, BN=64: grid 40x8 = 320 blocks)
  gemm_bt_bf16_n64<<<dim3((NN+MM)/128, DD/64), b256, 0, stream>>>(xhb, Whb, nullptr, xelb, DD, DD);
  // sparse hypergraph conv
  rowdot_b16<<<NN/4, b256, 0, stream>>>(xlb, att,      s_node, NN);
  rowdot_b16<<<MM/4, b256, 0, stream>>>(elb, att + DD, s_edge, MM);
  init_kernel<<<NN/256, b256, 0, stream>>>(amax, den, DnCnt, BnCnt, node_cur, edge_cur);
  incidence_pass1<<<NNZC/256, b256, 0, stream>>>(node_idx, edge_idx, s_node, s_edge,
                                                 a_buf, amax, DnCnt, BnCnt);
  exscan_kernel<<<1, 1024, 0, stream>>>(DnCnt, node_off, NN);
  exscan_kernel<<<1, 1024, 0, stream>>>(BnCnt, edge_off, MM);
  incidence_pass2<<<NNZC/256, b256, 0, stream>>>(node_idx, edge_idx, a_buf, amax, den,
                                                 node_off, edge_off, node_cur, edge_cur,
                                                 node_list, edge_list);
  gather_edge<<<MM, b256, 0, stream>>>(edge_off, edge_list, node_idx, a_buf, den, xlb, efb);
  gather_node<<<NN, b256, 0, stream>>>(node_off, node_list, edge_idx, a_buf, den, efb, bias_h, conv);
  // x1 = LN(x + conv) (+ bf16 copy)
  ln_residual<<<NN, b256, 0, stream>>>(x, conv, nullptr, ln1_g, ln1_b, x1, x1b);
  // qkv (BN=64: grid 32x24 = 768 blocks; bf16 out, attention reads Q/K straight from it)
  gemm_bt_bf16_n64<<<dim3(NN/128, (3*DD)/64), b256, 0, stream>>>(x1b, ipwb, in_proj_b, qkvbb, 3*DD, DD);
  // attention (bf16 MFMA, split-K x4 + combine)
  conv_vt<<<dim3(NN/64, HH), b256, 0, stream>>>(qkvbb, Vtb);
  attn_mfma_part<<<dim3(NN/64, HH, NSPLIT), b256, 0, stream>>>(qkvbb, Vtb, Opartb, mlb);
  attn_combine<<<NN*HH/4, b256, 0, stream>>>(Opartb, mlb, ctxb);
  // out_proj (BN=64: grid 32x8 = 256 blocks)
  gemm_bt_bf16_n64<<<dim3(NN/128, DD/64), b256, 0, stream>>>(ctxb, opwb, out_proj_b, attn_outb, DD, DD);
  // x2 = LN(x1 + attn_out) (+ bf16)
  ln_residual<<<NN, b256, 0, stream>>>(x1, nullptr, attn_outb, tln1_g, tln1_b, x2, x2b);
  // ffn: ff1 (128x128 tile, grid 512; relu, bf16 out), ff2 (BN=64: grid 32x8 = 256, K=2048)
  gemm_bt_bf16<<<dim3(NN/128, DFFC/128), b256, 0, stream>>>(x2b, ff1wb, ff1_b, nullptr, ffhb, DFFC, DD, 1);
  gemm_bt_bf16_n64<<<dim3(NN/128, DD/64), b256, 0, stream>>>(ffhb, ff2wb, ff2_b, ffob, DD, DFFC);
  // x3 = LN(x2 + ff); out = LN(x1 + x3)  (fused)
  ln_final2<<<NN, b256, 0, stream>>>(x2, ffob, x1, tln2_g, tln2_b, ln2_g, ln2_b, (float*)d_out);
}